// Round 4
// baseline (1883.749 us; speedup 1.0000x reference)
//
#include <hip/hip_runtime.h>
#include <math.h>

#define N_NODES 1024
#define K_NB    32
#define H_DIM   256
#define DE_DIM  128
#define N_EXP   8
#define NTOPK   2
#define FFH     512

typedef __attribute__((ext_vector_type(8))) short s8v;   // 8 bf16 = 4 VGPR
typedef __attribute__((ext_vector_type(4))) float f4v;   // MFMA acc

// ---- ws layout (elements) ----
#define NH_ELEMS   (N_EXP * N_NODES * H_DIM)   // 2097152 bf16
// per-expert fragment-pool offsets (bf16 elems)
#define OFF_WN   0
#define OFF_WM   65536
#define OFF_WE   196608
#define OFF_WQ   229376
#define OFF_WO   425984
#define OFF_W1E  491520
#define OFF_W2E  622592
#define EXP_STRIDE 753664

// ---------------------------------------------------------------- helpers
__device__ __forceinline__ unsigned short f2bf(float x) {
  unsigned u = __float_as_uint(x);
  unsigned r = u + 0x7FFFu + ((u >> 16) & 1u);   // RNE
  return (unsigned short)(r >> 16);
}
__device__ __forceinline__ float bf2f(unsigned short h) {
  return __uint_as_float((unsigned)h << 16);
}
__device__ __forceinline__ float gelu_f(float x) {
  float u = 0.7978845608028654f * (x + 0.044715f * x * x * x);
  float ex = __expf(2.f * u);
  float th = 1.f - 2.f / (ex + 1.f);
  return 0.5f * x * (1.f + th);
}

// A-fragment read from row-major bf16 LDS tile with XOR swizzle.
__device__ __forceinline__ s8v lda(const char* base, int SBv, int rt, int kt, int l) {
  int r = rt * 16 + (l & 15);
  int byte = r * SBv + kt * 64 + ((l >> 4) << 4);
  return *(const s8v*)(base + (byte ^ ((r & 7) << 4)));
}
__device__ __forceinline__ void stb16(char* base, int SBv, int r, int c, float v) {
  *(unsigned short*)(base + ((r * SBv + c * 2) ^ ((r & 7) << 4))) = f2bf(v);
}

// K-loop: NA output tiles (ct = ctb + 8*m), NKT k-steps; B frags from global pool.
template<int NA, int NKT>
__device__ __forceinline__ void kloop(f4v acc[NA], const char* Ab, int ASB, int rt,
                                      const unsigned short* __restrict__ fb, int NCT,
                                      int ktb0, int ctb, int l) {
  __builtin_amdgcn_s_setprio(1);
  for (int kt = 0; kt < NKT; ++kt) {
    s8v av = lda(Ab, ASB, rt, kt, l);
#pragma unroll
    for (int m = 0; m < NA; ++m) {
      s8v bv = *(const s8v*)(fb + (((size_t)(ktb0 + kt) * NCT + (ctb + 8 * m)) * 64 + l) * 8);
      acc[m] = __builtin_amdgcn_mfma_f32_16x16x32_bf16(av, bv, acc[m], 0, 0, 0);
    }
  }
  __builtin_amdgcn_s_setprio(0);
}

// ---------------------------------------------------------------- gating
__global__ __launch_bounds__(64)
void gate_kernel(const float* __restrict__ nf, const float* __restrict__ wg,
                 int* __restrict__ sel_ne, float* __restrict__ sel_g) {
  int n = blockIdx.x, t = threadIdx.x;
  float p[8] = {0, 0, 0, 0, 0, 0, 0, 0};
  for (int j = 0; j < 4; ++j) {
    float x = nf[n * H_DIM + t + 64 * j];
#pragma unroll
    for (int e = 0; e < 8; ++e) p[e] += x * wg[(t + 64 * j) * 8 + e];
  }
#pragma unroll
  for (int e = 0; e < 8; ++e)
    for (int m = 32; m >= 1; m >>= 1) p[e] += __shfl_xor(p[e], m, 64);
  if (t == 0) {
    int i0 = 0; float v0 = p[0];
    for (int e = 1; e < 8; ++e) if (p[e] > v0) { v0 = p[e]; i0 = e; }
    int i1 = -1; float v1 = -3.4e38f;
    for (int e = 0; e < 8; ++e) if (e != i0 && p[e] > v1) { v1 = p[e]; i1 = e; }
    float g1 = __expf(v1 - v0);
    float inv = 1.f / (1.f + g1);
    sel_ne[n * 2 + 0] = (n << 3) | i0; sel_g[n * 2 + 0] = inv;
    sel_ne[n * 2 + 1] = (n << 3) | i1; sel_g[n * 2 + 1] = g1 * inv;
  }
}

__global__ __launch_bounds__(256)
void sort_kernel(const int* __restrict__ sel_ne, const float* __restrict__ sel_g,
                 int* __restrict__ work_ne, float* __restrict__ work_g) {
  __shared__ int cnt[8], off[8], cur[8];
  int t = threadIdx.x;
  if (t < 8) { cnt[t] = 0; cur[t] = 0; }
  __syncthreads();
  for (int i = t; i < N_NODES * NTOPK; i += 256) atomicAdd(&cnt[sel_ne[i] & 7], 1);
  __syncthreads();
  if (t == 0) { int s = 0; for (int e = 0; e < 8; ++e) { off[e] = s; s += cnt[e]; } }
  __syncthreads();
  for (int i = t; i < N_NODES * NTOPK; i += 256) {
    int pe = sel_ne[i]; int e = pe & 7;
    int pos = off[e] + atomicAdd(&cur[e], 1);
    work_ne[pos] = pe; work_g[pos] = sel_g[i];
  }
}

// per-expert LayerNorm of all nodes -> bf16
__global__ __launch_bounds__(256)
void nh_kernel(const float* __restrict__ nf, const float* __restrict__ lag,
               const float* __restrict__ lab, unsigned short* __restrict__ nh16) {
  __shared__ float red[8];
  int n = blockIdx.x, e = blockIdx.y, t = threadIdx.x;
  float x = nf[n * H_DIM + t];
  float sv = x, sq = x * x;
  for (int m = 32; m >= 1; m >>= 1) { sv += __shfl_xor(sv, m, 64); sq += __shfl_xor(sq, m, 64); }
  if ((t & 63) == 0) { red[t >> 6] = sv; red[4 + (t >> 6)] = sq; }
  __syncthreads();
  float sum = red[0] + red[1] + red[2] + red[3];
  float ssum = red[4] + red[5] + red[6] + red[7];
  float mu = sum * (1.f / 256.f);
  float var = ssum * (1.f / 256.f) - mu * mu;
  float rstd = rsqrtf(var + 1e-5f);
  nh16[((size_t)e * N_NODES + n) * H_DIM + t] =
      f2bf((x - mu) * rstd * lag[e * H_DIM + t] + lab[e * H_DIM + t]);
}

// ------------------------------------------------ weight -> bf16 fragments
__global__ __launch_bounds__(64)
void wconv(const float* __restrict__ W_node, const float* __restrict__ W_msg,
           const float* __restrict__ W_edge, const float* __restrict__ W_qkv,
           const float* __restrict__ W_out, const float* __restrict__ W1e,
           const float* __restrict__ W2e, unsigned short* __restrict__ fb) {
  int f = blockIdx.x, e = blockIdx.y, l = threadIdx.x;
  const float* src; int C, nct, fl; size_t off;
  if (f < 128)       { src = W_node + (size_t)e * 131072; C = 256; nct = 16; fl = f;        off = OFF_WN;  }
  else if (f < 384)  { src = W_msg  + (size_t)e * 131072; C = 256; nct = 16; fl = f - 128;  off = OFF_WM;  }
  else if (f < 448)  { src = W_edge + (size_t)e * 32768;  C = 256; nct = 16; fl = f - 384;  off = OFF_WE;  }
  else if (f < 832)  { src = W_qkv  + (size_t)e * 196608; C = 768; nct = 48; fl = f - 448;  off = OFF_WQ;  }
  else if (f < 960)  { src = W_out  + (size_t)e * 65536;  C = 256; nct = 16; fl = f - 832;  off = OFF_WO;  }
  else if (f < 1216) { src = W1e    + (size_t)e * 131072; C = 512; nct = 32; fl = f - 960;  off = OFF_W1E; }
  else               { src = W2e    + (size_t)e * 131072; C = 256; nct = 16; fl = f - 1216; off = OFF_W2E; }
  int kt = fl / nct, ct = fl - kt * nct;
  int k0 = kt * 32 + ((l >> 4) << 3), c = ct * 16 + (l & 15);
  unsigned pk[4];
#pragma unroll
  for (int jj = 0; jj < 4; ++jj) {
    unsigned short a = f2bf(src[(size_t)(k0 + 2 * jj) * C + c]);
    unsigned short b = f2bf(src[(size_t)(k0 + 2 * jj + 1) * C + c]);
    pk[jj] = (unsigned)a | ((unsigned)b << 16);
  }
  unsigned short* dst = fb + (size_t)e * EXP_STRIDE + off + ((size_t)fl * 64 + l) * 8;
  *(uint4*)dst = make_uint4(pk[0], pk[1], pk[2], pk[3]);
}

// ---------------------------------------------------------------- main
// LDS budget 81408 B -> 2 blocks/CU (160 KiB LDS). Regions (byte offsets):
//  SA   0..16K   : sender -> msg -> ctx -> eh2            (bf16, SB=512, swz)
//  SB  16K..32K  : nodeh -> k                              (bf16)
//  SC  32K..48K  : eh -> v                                 (bf16)
//  EF  16K..48K  : ef f32 [32][256]  (overlays SB+SC after attention)
//  SD  48K..56K  : edge_raw bf16 [32][256B]
//  SQ  56K..72K  : q bf16 [32][512B] -> h1e half [32][512B]
//  MF  72K..     : misc f32 (1896 floats)
__global__ __launch_bounds__(1024, 8)
void moe_main(const float* __restrict__ node_features,
              const float* __restrict__ edge_features,
              const float* __restrict__ edge_raw,
              const int* __restrict__ neighbor_list,
              const float* __restrict__ neighbor_mask,
              const float* __restrict__ W_node_f32, const float* __restrict__ bn,
              const float* __restrict__ be, const float* __restrict__ bm,
              const float* __restrict__ bq, const float* __restrict__ bo,
              const float* __restrict__ ln_ffn_g, const float* __restrict__ ln_ffn_b,
              const float* __restrict__ W1n, const float* __restrict__ b1n,
              const float* __restrict__ W2n, const float* __restrict__ b2n,
              const float* __restrict__ b1e, const float* __restrict__ b2e,
              const unsigned short* __restrict__ nh16,
              const unsigned short* __restrict__ fb,
              const int* __restrict__ work_ne, const float* __restrict__ work_g,
              float* __restrict__ out_node, float* __restrict__ out_edge) {
  extern __shared__ char sm[];
  char* SAp = sm;
  char* SBp = sm + 16384;
  char* SCp = sm + 32768;
  float* EF = (float*)(sm + 16384);    // 32K f32 [32][256]
  char* SDp = sm + 49152;              // 8K
  char* SQp = sm + 57344;              // 16K
  float* MF = (float*)(sm + 73728);
  float* Mrecv = MF;            // 256
  float* Mrv2  = MF + 256;      // 512
  float* Mnp   = MF + 768;      // 256
  float* Mnh2  = MF + 1024;     // 256
  float* Mh1   = MF + 1280;     // 512
  float* Mred  = MF + 1792;     // 8
  float* Mmask = MF + 1800;     // 32
  float* Mmu   = MF + 1832;     // 32
  float* Mrstd = MF + 1864;     // 32

  const int t = threadIdx.x;
  const int pe = work_ne[blockIdx.x];
  const int n = pe >> 3, e = pe & 7;
  const float gate = work_g[blockIdx.x];

  const unsigned short* fbE   = fb + (size_t)e * EXP_STRIDE;
  const unsigned short* fbWn  = fbE + OFF_WN;
  const unsigned short* fbWm  = fbE + OFF_WM;
  const unsigned short* fbWe  = fbE + OFF_WE;
  const unsigned short* fbWq  = fbE + OFF_WQ;
  const unsigned short* fbWo  = fbE + OFF_WO;
  const unsigned short* fbW1e = fbE + OFF_W1E;
  const unsigned short* fbW2e = fbE + OFF_W2E;

  const float* Wn2  = W_node_f32 + (size_t)e * 131072;
  const float* bnE  = bn + e * H_DIM;
  const float* beE  = be + e * H_DIM;
  const float* bmE  = bm + e * H_DIM;
  const float* bqE  = bq + e * 3 * H_DIM;
  const float* boE  = bo + e * H_DIM;
  const float* lfg  = ln_ffn_g + e * H_DIM;
  const float* lfb  = ln_ffn_b + e * H_DIM;
  const float* w1n  = W1n + (size_t)e * H_DIM * FFH;
  const float* c1n  = b1n + e * FFH;
  const float* w2n  = W2n + (size_t)e * FFH * H_DIM;
  const float* c2n  = b2n + e * H_DIM;
  const float* c1e  = b1e + e * FFH;
  const float* c2e  = b2e + e * H_DIM;

  const int w = t >> 6, l = t & 63;
  const int rt = w & 1, ctb = w >> 1;

  // ---- stage ----
  const unsigned short* nh_e = nh16 + (size_t)e * N_NODES * H_DIM;
  {
    int r = t >> 5, j = t & 31;
    int nbr = neighbor_list[n * K_NB + r];
    uint4 val = ((const uint4*)(nh_e + (size_t)nbr * H_DIM))[j];
    *(uint4*)(SAp + ((r * 512 + j * 16) ^ ((r & 7) << 4))) = val;
  }
  if (t < 256) Mrecv[t] = bf2f(nh_e[(size_t)n * H_DIM + t]);
  {
    int r = t >> 5, c = (t & 31) * 4;
    float4 v = *(const float4*)(edge_raw + ((size_t)n * K_NB + r) * DE_DIM + c);
    unsigned p0 = (unsigned)f2bf(v.x) | ((unsigned)f2bf(v.y) << 16);
    unsigned p1 = (unsigned)f2bf(v.z) | ((unsigned)f2bf(v.w) << 16);
    *(uint2*)(SDp + ((r * 256 + c * 2) ^ ((r & 7) << 4))) = make_uint2(p0, p1);
  }
  if (t < 32) Mmask[t] = neighbor_mask[n * K_NB + t];
  if (t < 256) Mnp[t] = 0.f;
  __syncthreads();

  // ---- recv rank-1: Mrv[c] = sum_i recv[i]*Wn[256+i][c] + bn[c] (fp32) ----
  if (t < 512) {
    int c = t & 255, part = t >> 8;
    float s = 0.f;
    for (int i = 0; i < 128; ++i)
      s += Mrecv[part * 128 + i] * Wn2[(size_t)(256 + part * 128 + i) * 256 + c];
    Mrv2[part * 256 + c] = s;
  }
  __syncthreads();
  if (t < 256) Mrecv[t] = Mrv2[t] + Mrv2[256 + t] + bnE[t];
  __syncthreads();

  // ---- phase 1: nodeh = gelu(sender@Wn1 + Mrv) -> SB ----
  {
    f4v acc[2];
#pragma unroll
    for (int m = 0; m < 2; ++m) {
      float iv = Mrecv[(ctb + 8 * m) * 16 + (l & 15)];
      acc[m][0] = iv; acc[m][1] = iv; acc[m][2] = iv; acc[m][3] = iv;
    }
    kloop<2, 8>(acc, SAp, 512, rt, fbWn, 16, 0, ctb, l);
#pragma unroll
    for (int m = 0; m < 2; ++m) {
      int c = (ctb + 8 * m) * 16 + (l & 15);
#pragma unroll
      for (int ri = 0; ri < 4; ++ri)
        stb16(SBp, 512, rt * 16 + ((l >> 4) << 2) + ri, c, gelu_f(acc[m][ri]));
    }
  }
  // ---- phase 3: eh = gelu(edge_raw@We + be) -> SC ----
  {
    f4v acc[2];
#pragma unroll
    for (int m = 0; m < 2; ++m) {
      float iv = beE[(ctb + 8 * m) * 16 + (l & 15)];
      acc[m][0] = iv; acc[m][1] = iv; acc[m][2] = iv; acc[m][3] = iv;
    }
    kloop<2, 4>(acc, SDp, 256, rt, fbWe, 16, 0, ctb, l);
#pragma unroll
    for (int m = 0; m < 2; ++m) {
      int c = (ctb + 8 * m) * 16 + (l & 15);
#pragma unroll
      for (int ri = 0; ri < 4; ++ri)
        stb16(SCp, 512, rt * 16 + ((l >> 4) << 2) + ri, c, gelu_f(acc[m][ri]));
    }
  }
  __syncthreads();

  // ---- phase 2+4: msg = gelu([eh|nodeh]@Wm + bm) -> SA ----
  {
    f4v acc[2];
#pragma unroll
    for (int m = 0; m < 2; ++m) {
      float iv = bmE[(ctb + 8 * m) * 16 + (l & 15)];
      acc[m][0] = iv; acc[m][1] = iv; acc[m][2] = iv; acc[m][3] = iv;
    }
    kloop<2, 8>(acc, SCp, 512, rt, fbWm, 16, 0, ctb, l);   // eh    (Wm rows 0..255)
    kloop<2, 8>(acc, SBp, 512, rt, fbWm, 16, 8, ctb, l);   // nodeh (Wm rows 256..511)
#pragma unroll
    for (int m = 0; m < 2; ++m) {
      int c = (ctb + 8 * m) * 16 + (l & 15);
#pragma unroll
      for (int ri = 0; ri < 4; ++ri)
        stb16(SAp, 512, rt * 16 + ((l >> 4) << 2) + ri, c, gelu_f(acc[m][ri]));
    }
  }
  __syncthreads();

  // ---- phase 5: qkv = msg@Wq + bq; q->SQ bf16, k->SB bf16, v->SC bf16 ----
  {
    f4v acc[6];
#pragma unroll
    for (int m = 0; m < 6; ++m) {
      float iv = bqE[(ctb + 8 * m) * 16 + (l & 15)];
      acc[m][0] = iv; acc[m][1] = iv; acc[m][2] = iv; acc[m][3] = iv;
    }
    kloop<6, 8>(acc, SAp, 512, rt, fbWq, 48, 0, ctb, l);
#pragma unroll
    for (int m = 0; m < 6; ++m) {
      int cg = (ctb + 8 * m) * 16 + (l & 15);
      int rbase = rt * 16 + ((l >> 4) << 2);
      char* dst = (cg < 256) ? SQp : ((cg < 512) ? SBp : SCp);
      int cl = cg & 255;
#pragma unroll
      for (int ri = 0; ri < 4; ++ri) stb16(dst, 512, rbase + ri, cl, acc[m][ri]);
    }
  }
  __syncthreads();

  // ---- phase 6: attention, all 1024 threads: (h = t>>7, q = (t>>2)&31, part = t&3) ----
  {
    const int hh = t >> 7, qq = (t >> 2) & 31, part = t & 3;
    const int cb = hh * 64;  // byte offset of this head's 32 dims
    float qf[32];
#pragma unroll
    for (int d4 = 0; d4 < 8; ++d4) {
      uint2 qb = *(const uint2*)(SQp + ((qq * 512 + cb + d4 * 8) ^ ((qq & 7) << 4)));
      qf[d4 * 4 + 0] = bf2f(qb.x & 0xffff); qf[d4 * 4 + 1] = bf2f(qb.x >> 16);
      qf[d4 * 4 + 2] = bf2f(qb.y & 0xffff); qf[d4 * 4 + 3] = bf2f(qb.y >> 16);
    }
    float s[8];
    const float scale = 0.17677669529663687f;  // 1/sqrt(32)
#pragma unroll
    for (int j = 0; j < 8; ++j) {
      int kk = part + 4 * j;
      float a = 0.f;
#pragma unroll
      for (int d4 = 0; d4 < 8; ++d4) {
        uint2 kb = *(const uint2*)(SBp + ((kk * 512 + cb + d4 * 8) ^ ((kk & 7) << 4)));
        a += qf[d4 * 4 + 0] * bf2f(kb.x & 0xffff) + qf[d4 * 4 + 1] * bf2f(kb.x >> 16) +
             qf[d4 * 4 + 2] * bf2f(kb.y & 0xffff) + qf[d4 * 4 + 3] * bf2f(kb.y >> 16);
      }
      float mv = (Mmask[kk] > 0.f) ? 0.f : -1e9f;
      s[j] = a * scale + mv;
    }
    float m = s[0];
#pragma unroll
    for (int j = 1; j < 8; ++j) m = fmaxf(m, s[j]);
    m = fmaxf(m, __shfl_xor(m, 1, 64));
    m = fmaxf(m, __shfl_xor(m, 2, 64));
    float sum = 0.f;
#pragma unroll
    for (int j = 0; j < 8; ++j) { s[j] = __expf(s[j] - m); sum += s[j]; }
    sum += __shfl_xor(sum, 1, 64);
    sum += __shfl_xor(sum, 2, 64);
    float inv = 1.f / sum;
#pragma unroll
    for (int j = 0; j < 8; ++j) s[j] *= inv;
    float cx[32];
#pragma unroll
    for (int d = 0; d < 32; ++d) cx[d] = 0.f;
#pragma unroll
    for (int j = 0; j < 8; ++j) {
      int kk = part + 4 * j;
#pragma unroll
      for (int d4 = 0; d4 < 8; ++d4) {
        uint2 vb = *(const uint2*)(SCp + ((kk * 512 + cb + d4 * 8) ^ ((kk & 7) << 4)));
        cx[d4 * 4 + 0] += s[j] * bf2f(vb.x & 0xffff);
        cx[d4 * 4 + 1] += s[j] * bf2f(vb.x >> 16);
        cx[d4 * 4 + 2] += s[j] * bf2f(vb.y & 0xffff);
        cx[d4 * 4 + 3] += s[j] * bf2f(vb.y >> 16);
      }
    }
#pragma unroll
    for (int d = 0; d < 32; ++d) {
      cx[d] += __shfl_xor(cx[d], 1, 64);
      cx[d] += __shfl_xor(cx[d], 2, 64);
    }
    __syncthreads();  // all q/k/v reads done; SA(msg) fully read in phase 5
    if (part == 0) {
#pragma unroll
      for (int jj = 0; jj < 16; ++jj) {
        unsigned pkv = (unsigned)f2bf(cx[2 * jj]) | ((unsigned)f2bf(cx[2 * jj + 1]) << 16);
        *(unsigned*)(SAp + ((qq * 512 + cb + jj * 4) ^ ((qq & 7) << 4))) = pkv;
      }
    }
  }
  __syncthreads();

  // ---- phase 7: edge_out = ctx@Wo + bo; np partials; ef -> EF (over k/v) ----
  {
    f4v acc[2];
#pragma unroll
    for (int m = 0; m < 2; ++m) {
      float iv = boE[(ctb + 8 * m) * 16 + (l & 15)];
      acc[m][0] = iv; acc[m][1] = iv; acc[m][2] = iv; acc[m][3] = iv;
    }
    kloop<2, 8>(acc, SAp, 512, rt, fbWo, 16, 0, ctb, l);
#pragma unroll
    for (int m = 0; m < 2; ++m) {
      int c = (ctb + 8 * m) * 16 + (l & 15);
      int rbase = rt * 16 + ((l >> 4) << 2);
      float np = 0.f;
#pragma unroll
      for (int ri = 0; ri < 4; ++ri) {
        int r = rbase + ri;
        float eo = acc[m][ri];
        np += eo * Mmask[r];
        EF[r * 256 + c] = eo + edge_features[((size_t)n * K_NB + r) * H_DIM + c];
      }
      atomicAdd(&Mnp[c], np);
    }
  }
  __syncthreads();

  // ---- phase 9a: LN stats of ef; 8a: nfv + node-LN partials ----
  {
    int rr = t >> 5, j = t & 31;
    float s1 = 0.f, s2 = 0.f;
#pragma unroll
    for (int m2 = 0; m2 < 8; ++m2) {
      float xv = EF[rr * 256 + j + 32 * m2];
      s1 += xv; s2 += xv * xv;
    }
    s1 += __shfl_xor(s1, 16, 32); s2 += __shfl_xor(s2, 16, 32);
    s1 += __shfl_xor(s1, 8, 32);  s2 += __shfl_xor(s2, 8, 32);
    s1 += __shfl_xor(s1, 4, 32);  s2 += __shfl_xor(s2, 4, 32);
    s1 += __shfl_xor(s1, 2, 32);  s2 += __shfl_xor(s2, 2, 32);
    s1 += __shfl_xor(s1, 1, 32);  s2 += __shfl_xor(s2, 1, 32);
    if (j == 0) {
      float mu2 = s1 * (1.f / 256.f);
      float v2 = s2 * (1.f / 256.f) - mu2 * mu2;
      Mmu[rr] = mu2; Mrstd[rr] = rsqrtf(v2 + 1e-5f);
    }
  }
  float cntv = 1e-5f;
#pragma unroll
  for (int kk = 0; kk < 32; ++kk) cntv += Mmask[kk];
  float nfv = 0.f;
  if (t < 256) {
    nfv = Mnp[t] / cntv + node_features[n * H_DIM + t];
    float sv = nfv, sq = nfv * nfv;
    for (int m = 32; m >= 1; m >>= 1) { sv += __shfl_xor(sv, m, 64); sq += __shfl_xor(sq, m, 64); }
    if ((t & 63) == 0) { Mred[t >> 6] = sv; Mred[4 + (t >> 6)] = sq; }
  }
  __syncthreads();

  // ---- 9c: node LN -> Mnh2 ; 9d: eh2 = LN(ef) -> SA bf16 ----
  if (t < 256) {
    float sum = Mred[0] + Mred[1] + Mred[2] + Mred[3];
    float ssum = Mred[4] + Mred[5] + Mred[6] + Mred[7];
    float mu = sum * (1.f / 256.f);
    float var = ssum * (1.f / 256.f) - mu * mu;
    float rstd = rsqrtf(var + 1e-5f);
    Mnh2[t] = (nfv - mu) * rstd * lfg[t] + lfb[t];
  }
  {
    int col = t & 255, rgp = t >> 8;
    float g2 = lfg[col], b2v = lfb[col];
#pragma unroll
    for (int r8 = 0; r8 < 8; ++r8) {
      int row = rgp * 8 + r8;
      float xv = (EF[row * 256 + col] - Mmu[row]) * Mrstd[row] * g2 + b2v;
      stb16(SAp, 512, row, col, xv);
    }
  }
  __syncthreads();

  // ---- phases 10+11 (k-split halves, h1e half-buffer in SQ) + node FFN ----
  f4v acc2[2];
#pragma unroll
  for (int m = 0; m < 2; ++m) {
    float iv = c2e[(ctb + 8 * m) * 16 + (l & 15)];
    acc2[m][0] = iv; acc2[m][1] = iv; acc2[m][2] = iv; acc2[m][3] = iv;
  }
#pragma unroll
  for (int half = 0; half < 2; ++half) {
    // phase 10 half: h1e[:, half*256 : half*256+256] = gelu(eh2 @ w1e_half + c1e_half)
    {
      f4v acc[2];
#pragma unroll
      for (int m = 0; m < 2; ++m) {
        float iv = c1e[(half * 16 + ctb + 8 * m) * 16 + (l & 15)];
        acc[m][0] = iv; acc[m][1] = iv; acc[m][2] = iv; acc[m][3] = iv;
      }
      kloop<2, 8>(acc, SAp, 512, rt, fbW1e, 32, 0, half * 16 + ctb, l);
#pragma unroll
      for (int m = 0; m < 2; ++m) {
        int c = (ctb + 8 * m) * 16 + (l & 15);
#pragma unroll
        for (int ri = 0; ri < 4; ++ri)
          stb16(SQp, 512, rt * 16 + ((l >> 4) << 2) + ri, c, gelu_f(acc[m][ri]));
      }
    }
    if (half == 0 && t < FFH) {     // 8b: node FFN hidden (fp32), overlapped
      float a = c1n[t];
      for (int i = 0; i < H_DIM; ++i) a += Mnh2[i] * w1n[(size_t)i * FFH + t];
      Mh1[t] = gelu_f(a);
    }
    __syncthreads();
    // phase 11 half: acc2 += h1e_half @ w2e[half*256 : , :]
    kloop<2, 8>(acc2, SQp, 512, rt, fbW2e, 16, half * 8, ctb, l);
    __syncthreads();  // SQ reused next half
  }

  // ---- epilogues ----
#pragma unroll
  for (int m = 0; m < 2; ++m) {
    int c = (ctb + 8 * m) * 16 + (l & 15);
    int rbase = rt * 16 + ((l >> 4) << 2);
#pragma unroll
    for (int ri = 0; ri < 4; ++ri) {
      int r = rbase + ri;
      float o = acc2[m][ri] + EF[r * 256 + c];
      atomicAdd(&out_edge[((size_t)n * K_NB + r) * H_DIM + c], gate * o);
    }
  }
  if (t < 256) {   // 8c: node FFN out (fp32)
    float o = nfv + c2n[t];
    for (int i = 0; i < FFH; ++i) o += Mh1[i] * w2n[(size_t)i * H_DIM + t];
    atomicAdd(&out_node[n * H_DIM + t], gate * o);
  }
}

// ---------------------------------------------------------------- launch
extern "C" void kernel_launch(void* const* d_in, const int* in_sizes, int n_in,
                              void* d_out, int out_size, void* d_ws, size_t ws_size,
                              hipStream_t stream) {
  const float* node_features = (const float*)d_in[0];
  const float* edge_features = (const float*)d_in[1];
  const float* edge_raw      = (const float*)d_in[2];
  const int*   neighbor_list = (const int*)d_in[3];
  const float* neighbor_mask = (const float*)d_in[4];
  const float* w_gate        = (const float*)d_in[6];
  const float* W_edge = (const float*)d_in[7];
  const float* b_edge = (const float*)d_in[8];
  const float* W_node = (const float*)d_in[9];
  const float* b_node = (const float*)d_in[10];
  const float* W_msg  = (const float*)d_in[11];
  const float* b_msg  = (const float*)d_in[12];
  const float* W_qkv  = (const float*)d_in[13];
  const float* b_qkv  = (const float*)d_in[14];
  const float* W_out  = (const float*)d_in[15];
  const float* b_out  = (const float*)d_in[16];
  const float* ln_attn_g = (const float*)d_in[17];
  const float* ln_attn_b = (const float*)d_in[18];
  const float* ln_ffn_g  = (const float*)d_in[19];
  const float* ln_ffn_b  = (const float*)d_in[20];
  const float* W1n = (const float*)d_in[21];
  const float* b1n = (const float*)d_in[22];
  const float* W2n = (const float*)d_in[23];
  const float* b2n = (const float*)d_in[24];
  const float* W1e = (const float*)d_in[25];
  const float* b1e = (const float*)d_in[26];
  const float* W2e = (const float*)d_in[27];
  const float* b2e = (const float*)d_in[28];

  unsigned short* nh16 = (unsigned short*)d_ws;           // 2097152 bf16
  unsigned short* fbp  = nh16 + NH_ELEMS;                 // 6029312 bf16
  int*   sel_ne  = (int*)(fbp + (size_t)N_EXP * EXP_STRIDE);
  float* sel_g   = (float*)(sel_ne + 2048);
  int*   work_ne = (int*)(sel_g + 2048);
  float* work_g  = (float*)(work_ne + 2048);

  float* out_node = (float*)d_out;
  float* out_edge = out_node + N_NODES * H_DIM;

  hipMemsetAsync(d_out, 0, (size_t)out_size * sizeof(float), stream);

  gate_kernel<<<N_NODES, 64, 0, stream>>>(node_features, w_gate, sel_ne, sel_g);
  sort_kernel<<<1, 256, 0, stream>>>(sel_ne, sel_g, work_ne, work_g);
  nh_kernel<<<dim3(N_NODES, N_EXP), 256, 0, stream>>>(node_features, ln_attn_g, ln_attn_b, nh16);
  wconv<<<dim3(1472, N_EXP), 64, 0, stream>>>(W_node, W_msg, W_edge, W_qkv, W_out, W1e, W2e, fbp);

  size_t smem = 81408;   // <= 81920 -> 2 blocks/CU
  hipFuncSetAttribute((const void*)moe_main, hipFuncAttributeMaxDynamicSharedMemorySize, (int)smem);
  moe_main<<<N_NODES * NTOPK, 1024, smem, stream>>>(
      node_features, edge_features, edge_raw, neighbor_list, neighbor_mask,
      W_node, b_node, b_edge, b_msg, b_qkv, b_out,
      ln_ffn_g, ln_ffn_b, W1n, b1n, W2n, b2n, b1e, b2e,
      nh16, fbp, work_ne, work_g, out_node, out_edge);
}

// Round 5
// 1112.028 us; speedup vs baseline: 1.6940x; 1.6940x over previous
//
#include <hip/hip_runtime.h>
#include <math.h>

#define N_NODES 1024
#define K_NB    32
#define H_DIM   256
#define DE_DIM  128
#define N_EXP   8
#define NTOPK   2
#define FFH     512

typedef __attribute__((ext_vector_type(8))) short s8v;   // 8 bf16 = 4 VGPR
typedef __attribute__((ext_vector_type(4))) float f4v;   // MFMA acc

// ---- ws layout (elements) ----
#define NH_ELEMS   (N_EXP * N_NODES * H_DIM)   // 2097152 bf16
// per-expert fragment-pool offsets (bf16 elems)
#define OFF_WN   0
#define OFF_WM   65536
#define OFF_WE   196608
#define OFF_WQ   229376
#define OFF_WO   425984
#define OFF_W1E  491520
#define OFF_W2E  622592
#define EXP_STRIDE 753664

// ---------------------------------------------------------------- helpers
__device__ __forceinline__ unsigned short f2bf(float x) {
  unsigned u = __float_as_uint(x);
  unsigned r = u + 0x7FFFu + ((u >> 16) & 1u);   // RNE
  return (unsigned short)(r >> 16);
}
__device__ __forceinline__ float bf2f(unsigned short h) {
  return __uint_as_float((unsigned)h << 16);
}
__device__ __forceinline__ float gelu_f(float x) {
  float u = 0.7978845608028654f * (x + 0.044715f * x * x * x);
  float ex = __expf(2.f * u);
  float th = 1.f - 2.f / (ex + 1.f);
  return 0.5f * x * (1.f + th);
}

// A-fragment read from row-major bf16 LDS tile with XOR swizzle.
__device__ __forceinline__ s8v lda(const char* base, int SBv, int rt, int kt, int l) {
  int r = rt * 16 + (l & 15);
  int byte = r * SBv + kt * 64 + ((l >> 4) << 4);
  return *(const s8v*)(base + (byte ^ ((r & 7) << 4)));
}
__device__ __forceinline__ void stb16(char* base, int SBv, int r, int c, float v) {
  *(unsigned short*)(base + ((r * SBv + c * 2) ^ ((r & 7) << 4))) = f2bf(v);
}

// K-loop: NA output tiles (ct = ctb + 8*m), NKT k-steps; B frags from global pool.
template<int NA, int NKT>
__device__ __forceinline__ void kloop(f4v acc[NA], const char* Ab, int ASB, int rt,
                                      const unsigned short* __restrict__ fb, int NCT,
                                      int ktb0, int ctb, int l) {
  __builtin_amdgcn_s_setprio(1);
  for (int kt = 0; kt < NKT; ++kt) {
    s8v av = lda(Ab, ASB, rt, kt, l);
#pragma unroll
    for (int m = 0; m < NA; ++m) {
      s8v bv = *(const s8v*)(fb + (((size_t)(ktb0 + kt) * NCT + (ctb + 8 * m)) * 64 + l) * 8);
      acc[m] = __builtin_amdgcn_mfma_f32_16x16x32_bf16(av, bv, acc[m], 0, 0, 0);
    }
  }
  __builtin_amdgcn_s_setprio(0);
}

// ---------------------------------------------------------------- gating
__global__ __launch_bounds__(64)
void gate_kernel(const float* __restrict__ nf, const float* __restrict__ wg,
                 int* __restrict__ sel_ne, float* __restrict__ sel_g) {
  int n = blockIdx.x, t = threadIdx.x;
  float p[8] = {0, 0, 0, 0, 0, 0, 0, 0};
  for (int j = 0; j < 4; ++j) {
    float x = nf[n * H_DIM + t + 64 * j];
#pragma unroll
    for (int e = 0; e < 8; ++e) p[e] += x * wg[(t + 64 * j) * 8 + e];
  }
#pragma unroll
  for (int e = 0; e < 8; ++e)
    for (int m = 32; m >= 1; m >>= 1) p[e] += __shfl_xor(p[e], m, 64);
  if (t == 0) {
    int i0 = 0; float v0 = p[0];
    for (int e = 1; e < 8; ++e) if (p[e] > v0) { v0 = p[e]; i0 = e; }
    int i1 = -1; float v1 = -3.4e38f;
    for (int e = 0; e < 8; ++e) if (e != i0 && p[e] > v1) { v1 = p[e]; i1 = e; }
    float g1 = __expf(v1 - v0);
    float inv = 1.f / (1.f + g1);
    sel_ne[n * 2 + 0] = (n << 3) | i0; sel_g[n * 2 + 0] = inv;
    sel_ne[n * 2 + 1] = (n << 3) | i1; sel_g[n * 2 + 1] = g1 * inv;
  }
}

__global__ __launch_bounds__(256)
void sort_kernel(const int* __restrict__ sel_ne, const float* __restrict__ sel_g,
                 int* __restrict__ work_ne, float* __restrict__ work_g) {
  __shared__ int cnt[8], off[8], cur[8];
  int t = threadIdx.x;
  if (t < 8) { cnt[t] = 0; cur[t] = 0; }
  __syncthreads();
  for (int i = t; i < N_NODES * NTOPK; i += 256) atomicAdd(&cnt[sel_ne[i] & 7], 1);
  __syncthreads();
  if (t == 0) { int s = 0; for (int e = 0; e < 8; ++e) { off[e] = s; s += cnt[e]; } }
  __syncthreads();
  for (int i = t; i < N_NODES * NTOPK; i += 256) {
    int pe = sel_ne[i]; int e = pe & 7;
    int pos = off[e] + atomicAdd(&cur[e], 1);
    work_ne[pos] = pe; work_g[pos] = sel_g[i];
  }
}

// per-expert LayerNorm of all nodes -> bf16
__global__ __launch_bounds__(256)
void nh_kernel(const float* __restrict__ nf, const float* __restrict__ lag,
               const float* __restrict__ lab, unsigned short* __restrict__ nh16) {
  __shared__ float red[8];
  int n = blockIdx.x, e = blockIdx.y, t = threadIdx.x;
  float x = nf[n * H_DIM + t];
  float sv = x, sq = x * x;
  for (int m = 32; m >= 1; m >>= 1) { sv += __shfl_xor(sv, m, 64); sq += __shfl_xor(sq, m, 64); }
  if ((t & 63) == 0) { red[t >> 6] = sv; red[4 + (t >> 6)] = sq; }
  __syncthreads();
  float sum = red[0] + red[1] + red[2] + red[3];
  float ssum = red[4] + red[5] + red[6] + red[7];
  float mu = sum * (1.f / 256.f);
  float var = ssum * (1.f / 256.f) - mu * mu;
  float rstd = rsqrtf(var + 1e-5f);
  nh16[((size_t)e * N_NODES + n) * H_DIM + t] =
      f2bf((x - mu) * rstd * lag[e * H_DIM + t] + lab[e * H_DIM + t]);
}

// ------------------------------------------------ weight -> bf16 fragments
__global__ __launch_bounds__(64)
void wconv(const float* __restrict__ W_node, const float* __restrict__ W_msg,
           const float* __restrict__ W_edge, const float* __restrict__ W_qkv,
           const float* __restrict__ W_out, const float* __restrict__ W1e,
           const float* __restrict__ W2e, unsigned short* __restrict__ fb) {
  int f = blockIdx.x, e = blockIdx.y, l = threadIdx.x;
  const float* src; int C, nct, fl; size_t off;
  if (f < 128)       { src = W_node + (size_t)e * 131072; C = 256; nct = 16; fl = f;        off = OFF_WN;  }
  else if (f < 384)  { src = W_msg  + (size_t)e * 131072; C = 256; nct = 16; fl = f - 128;  off = OFF_WM;  }
  else if (f < 448)  { src = W_edge + (size_t)e * 32768;  C = 256; nct = 16; fl = f - 384;  off = OFF_WE;  }
  else if (f < 832)  { src = W_qkv  + (size_t)e * 196608; C = 768; nct = 48; fl = f - 448;  off = OFF_WQ;  }
  else if (f < 960)  { src = W_out  + (size_t)e * 65536;  C = 256; nct = 16; fl = f - 832;  off = OFF_WO;  }
  else if (f < 1216) { src = W1e    + (size_t)e * 131072; C = 512; nct = 32; fl = f - 960;  off = OFF_W1E; }
  else               { src = W2e    + (size_t)e * 131072; C = 256; nct = 16; fl = f - 1216; off = OFF_W2E; }
  int kt = fl / nct, ct = fl - kt * nct;
  int k0 = kt * 32 + ((l >> 4) << 3), c = ct * 16 + (l & 15);
  unsigned pk[4];
#pragma unroll
  for (int jj = 0; jj < 4; ++jj) {
    unsigned short a = f2bf(src[(size_t)(k0 + 2 * jj) * C + c]);
    unsigned short b = f2bf(src[(size_t)(k0 + 2 * jj + 1) * C + c]);
    pk[jj] = (unsigned)a | ((unsigned)b << 16);
  }
  unsigned short* dst = fb + (size_t)e * EXP_STRIDE + off + ((size_t)fl * 64 + l) * 8;
  *(uint4*)dst = make_uint4(pk[0], pk[1], pk[2], pk[3]);
}

// ---------------------------------------------------------------- main
// LDS 81408 B -> 2 blocks/CU. Regions as R4. Attention is register-lean:
// stage A ~20 live VGPRs, stage B ~20 (8 dims/thread + prob shfl) so the
// (1024,8) 64-total-reg budget (32 VGPR + 32 AGPR split) never spills.
__global__ __launch_bounds__(1024, 8)
void moe_main(const float* __restrict__ node_features,
              const float* __restrict__ edge_features,
              const float* __restrict__ edge_raw,
              const int* __restrict__ neighbor_list,
              const float* __restrict__ neighbor_mask,
              const float* __restrict__ W_node_f32, const float* __restrict__ bn,
              const float* __restrict__ be, const float* __restrict__ bm,
              const float* __restrict__ bq, const float* __restrict__ bo,
              const float* __restrict__ ln_ffn_g, const float* __restrict__ ln_ffn_b,
              const float* __restrict__ W1n, const float* __restrict__ b1n,
              const float* __restrict__ W2n, const float* __restrict__ b2n,
              const float* __restrict__ b1e, const float* __restrict__ b2e,
              const unsigned short* __restrict__ nh16,
              const unsigned short* __restrict__ fb,
              const int* __restrict__ work_ne, const float* __restrict__ work_g,
              float* __restrict__ out_node, float* __restrict__ out_edge) {
  extern __shared__ char sm[];
  char* SAp = sm;
  char* SBp = sm + 16384;
  char* SCp = sm + 32768;
  float* EF = (float*)(sm + 16384);    // 32K f32 [32][256]
  char* SDp = sm + 49152;              // 8K
  char* SQp = sm + 57344;              // 16K
  float* MF = (float*)(sm + 73728);
  float* Mrecv = MF;            // 256
  float* Mrv2  = MF + 256;      // 512
  float* Mnp   = MF + 768;      // 256
  float* Mnh2  = MF + 1024;     // 256
  float* Mh1   = MF + 1280;     // 512
  float* Mred  = MF + 1792;     // 8
  float* Mmask = MF + 1800;     // 32
  float* Mmu   = MF + 1832;     // 32
  float* Mrstd = MF + 1864;     // 32

  const int t = threadIdx.x;
  const int pe = work_ne[blockIdx.x];
  const int n = pe >> 3, e = pe & 7;
  const float gate = work_g[blockIdx.x];

  const unsigned short* fbE   = fb + (size_t)e * EXP_STRIDE;
  const unsigned short* fbWn  = fbE + OFF_WN;
  const unsigned short* fbWm  = fbE + OFF_WM;
  const unsigned short* fbWe  = fbE + OFF_WE;
  const unsigned short* fbWq  = fbE + OFF_WQ;
  const unsigned short* fbWo  = fbE + OFF_WO;
  const unsigned short* fbW1e = fbE + OFF_W1E;
  const unsigned short* fbW2e = fbE + OFF_W2E;

  const float* Wn2  = W_node_f32 + (size_t)e * 131072;
  const float* bnE  = bn + e * H_DIM;
  const float* beE  = be + e * H_DIM;
  const float* bmE  = bm + e * H_DIM;
  const float* bqE  = bq + e * 3 * H_DIM;
  const float* boE  = bo + e * H_DIM;
  const float* lfg  = ln_ffn_g + e * H_DIM;
  const float* lfb  = ln_ffn_b + e * H_DIM;
  const float* w1n  = W1n + (size_t)e * H_DIM * FFH;
  const float* c1n  = b1n + e * FFH;
  const float* w2n  = W2n + (size_t)e * FFH * H_DIM;
  const float* c2n  = b2n + e * H_DIM;
  const float* c1e  = b1e + e * FFH;
  const float* c2e  = b2e + e * H_DIM;

  const int w = t >> 6, l = t & 63;
  const int rt = w & 1, ctb = w >> 1;

  // ---- stage ----
  const unsigned short* nh_e = nh16 + (size_t)e * N_NODES * H_DIM;
  {
    int r = t >> 5, j = t & 31;
    int nbr = neighbor_list[n * K_NB + r];
    uint4 val = ((const uint4*)(nh_e + (size_t)nbr * H_DIM))[j];
    *(uint4*)(SAp + ((r * 512 + j * 16) ^ ((r & 7) << 4))) = val;
  }
  if (t < 256) Mrecv[t] = bf2f(nh_e[(size_t)n * H_DIM + t]);
  {
    int r = t >> 5, c = (t & 31) * 4;
    float4 v = *(const float4*)(edge_raw + ((size_t)n * K_NB + r) * DE_DIM + c);
    unsigned p0 = (unsigned)f2bf(v.x) | ((unsigned)f2bf(v.y) << 16);
    unsigned p1 = (unsigned)f2bf(v.z) | ((unsigned)f2bf(v.w) << 16);
    *(uint2*)(SDp + ((r * 256 + c * 2) ^ ((r & 7) << 4))) = make_uint2(p0, p1);
  }
  if (t < 32) Mmask[t] = neighbor_mask[n * K_NB + t];
  if (t < 256) Mnp[t] = 0.f;
  __syncthreads();

  // ---- recv rank-1: Mrv[c] = sum_i recv[i]*Wn[256+i][c] + bn[c] (fp32) ----
  if (t < 512) {
    int c = t & 255, part = t >> 8;
    float s = 0.f;
    for (int i = 0; i < 128; ++i)
      s += Mrecv[part * 128 + i] * Wn2[(size_t)(256 + part * 128 + i) * 256 + c];
    Mrv2[part * 256 + c] = s;
  }
  __syncthreads();
  if (t < 256) Mrecv[t] = Mrv2[t] + Mrv2[256 + t] + bnE[t];
  __syncthreads();

  // ---- phase 1: nodeh = gelu(sender@Wn1 + Mrv) -> SB ----
  {
    f4v acc[2];
#pragma unroll
    for (int m = 0; m < 2; ++m) {
      float iv = Mrecv[(ctb + 8 * m) * 16 + (l & 15)];
      acc[m][0] = iv; acc[m][1] = iv; acc[m][2] = iv; acc[m][3] = iv;
    }
    kloop<2, 8>(acc, SAp, 512, rt, fbWn, 16, 0, ctb, l);
#pragma unroll
    for (int m = 0; m < 2; ++m) {
      int c = (ctb + 8 * m) * 16 + (l & 15);
#pragma unroll
      for (int ri = 0; ri < 4; ++ri)
        stb16(SBp, 512, rt * 16 + ((l >> 4) << 2) + ri, c, gelu_f(acc[m][ri]));
    }
  }
  // ---- phase 3: eh = gelu(edge_raw@We + be) -> SC ----
  {
    f4v acc[2];
#pragma unroll
    for (int m = 0; m < 2; ++m) {
      float iv = beE[(ctb + 8 * m) * 16 + (l & 15)];
      acc[m][0] = iv; acc[m][1] = iv; acc[m][2] = iv; acc[m][3] = iv;
    }
    kloop<2, 4>(acc, SDp, 256, rt, fbWe, 16, 0, ctb, l);
#pragma unroll
    for (int m = 0; m < 2; ++m) {
      int c = (ctb + 8 * m) * 16 + (l & 15);
#pragma unroll
      for (int ri = 0; ri < 4; ++ri)
        stb16(SCp, 512, rt * 16 + ((l >> 4) << 2) + ri, c, gelu_f(acc[m][ri]));
    }
  }
  __syncthreads();

  // ---- phase 2+4: msg = gelu([eh|nodeh]@Wm + bm) -> SA ----
  {
    f4v acc[2];
#pragma unroll
    for (int m = 0; m < 2; ++m) {
      float iv = bmE[(ctb + 8 * m) * 16 + (l & 15)];
      acc[m][0] = iv; acc[m][1] = iv; acc[m][2] = iv; acc[m][3] = iv;
    }
    kloop<2, 8>(acc, SCp, 512, rt, fbWm, 16, 0, ctb, l);   // eh    (Wm rows 0..255)
    kloop<2, 8>(acc, SBp, 512, rt, fbWm, 16, 8, ctb, l);   // nodeh (Wm rows 256..511)
#pragma unroll
    for (int m = 0; m < 2; ++m) {
      int c = (ctb + 8 * m) * 16 + (l & 15);
#pragma unroll
      for (int ri = 0; ri < 4; ++ri)
        stb16(SAp, 512, rt * 16 + ((l >> 4) << 2) + ri, c, gelu_f(acc[m][ri]));
    }
  }
  __syncthreads();

  // ---- phase 5: qkv = msg@Wq + bq; q->SQ bf16, k->SB bf16, v->SC bf16 ----
  {
    f4v acc[6];
#pragma unroll
    for (int m = 0; m < 6; ++m) {
      float iv = bqE[(ctb + 8 * m) * 16 + (l & 15)];
      acc[m][0] = iv; acc[m][1] = iv; acc[m][2] = iv; acc[m][3] = iv;
    }
    kloop<6, 8>(acc, SAp, 512, rt, fbWq, 48, 0, ctb, l);
#pragma unroll
    for (int m = 0; m < 6; ++m) {
      int cg = (ctb + 8 * m) * 16 + (l & 15);
      int rbase = rt * 16 + ((l >> 4) << 2);
      char* dst = (cg < 256) ? SQp : ((cg < 512) ? SBp : SCp);
      int cl = cg & 255;
#pragma unroll
      for (int ri = 0; ri < 4; ++ri) stb16(dst, 512, rbase + ri, cl, acc[m][ri]);
    }
  }
  __syncthreads();

  // ---- phase 6: attention, all 1024 threads, register-lean two-stage ----
  // thread = (h = t>>7, q = (t>>2)&31, part = t&3)
  {
    const int hh = t >> 7, qq = (t >> 2) & 31, part = t & 3;
    const int cb = hh * 64;  // byte offset of this head's 32 dims (bf16)
    // stage A: scores for keys kk = part + 4j (q streamed, not preloaded)
    float s[8];
#pragma unroll
    for (int j = 0; j < 8; ++j) s[j] = 0.f;
#pragma unroll
    for (int d4 = 0; d4 < 8; ++d4) {
      uint2 qb = *(const uint2*)(SQp + ((qq * 512 + cb + d4 * 8) ^ ((qq & 7) << 4)));
      float q0 = bf2f(qb.x & 0xffff), q1 = bf2f(qb.x >> 16);
      float q2 = bf2f(qb.y & 0xffff), q3 = bf2f(qb.y >> 16);
#pragma unroll
      for (int j = 0; j < 8; ++j) {
        int kk = part + 4 * j;
        uint2 kb = *(const uint2*)(SBp + ((kk * 512 + cb + d4 * 8) ^ ((kk & 7) << 4)));
        s[j] += q0 * bf2f(kb.x & 0xffff) + q1 * bf2f(kb.x >> 16) +
                q2 * bf2f(kb.y & 0xffff) + q3 * bf2f(kb.y >> 16);
      }
    }
    const float scale = 0.17677669529663687f;  // 1/sqrt(32)
    float m = -3.4e38f;
#pragma unroll
    for (int j = 0; j < 8; ++j) {
      int kk = part + 4 * j;
      float mv = (Mmask[kk] > 0.f) ? 0.f : -1e9f;
      s[j] = s[j] * scale + mv;
      m = fmaxf(m, s[j]);
    }
    m = fmaxf(m, __shfl_xor(m, 1, 64));
    m = fmaxf(m, __shfl_xor(m, 2, 64));
    float sum = 0.f;
#pragma unroll
    for (int j = 0; j < 8; ++j) { s[j] = __expf(s[j] - m); sum += s[j]; }
    sum += __shfl_xor(sum, 1, 64);
    sum += __shfl_xor(sum, 2, 64);
    float inv = 1.f / sum;
#pragma unroll
    for (int j = 0; j < 8; ++j) s[j] *= inv;
    // stage B: this thread owns dims [part*8, part*8+8); probs come via shfl
    float cx[8];
#pragma unroll
    for (int d = 0; d < 8; ++d) cx[d] = 0.f;
#pragma unroll
    for (int x = 0; x < 4; ++x) {
      int ps = part ^ x;
#pragma unroll
      for (int j = 0; j < 8; ++j) {
        float p = __shfl_xor(s[j], x, 64);
        int kk = ps + 4 * j;
        uint4 vb = *(const uint4*)(SCp + ((kk * 512 + cb + part * 16) ^ ((kk & 7) << 4)));
        cx[0] += p * bf2f(vb.x & 0xffff); cx[1] += p * bf2f(vb.x >> 16);
        cx[2] += p * bf2f(vb.y & 0xffff); cx[3] += p * bf2f(vb.y >> 16);
        cx[4] += p * bf2f(vb.z & 0xffff); cx[5] += p * bf2f(vb.z >> 16);
        cx[6] += p * bf2f(vb.w & 0xffff); cx[7] += p * bf2f(vb.w >> 16);
      }
    }
    // write ctx dims [part*8 .. +8) of (hh,qq) to SA (disjoint uint4 per thread)
    unsigned o0 = (unsigned)f2bf(cx[0]) | ((unsigned)f2bf(cx[1]) << 16);
    unsigned o1 = (unsigned)f2bf(cx[2]) | ((unsigned)f2bf(cx[3]) << 16);
    unsigned o2 = (unsigned)f2bf(cx[4]) | ((unsigned)f2bf(cx[5]) << 16);
    unsigned o3 = (unsigned)f2bf(cx[6]) | ((unsigned)f2bf(cx[7]) << 16);
    *(uint4*)(SAp + ((qq * 512 + cb + part * 16) ^ ((qq & 7) << 4))) = make_uint4(o0, o1, o2, o3);
  }
  __syncthreads();

  // ---- phase 7: edge_out = ctx@Wo + bo; np partials; ef -> EF (over k/v) ----
  {
    f4v acc[2];
#pragma unroll
    for (int m = 0; m < 2; ++m) {
      float iv = boE[(ctb + 8 * m) * 16 + (l & 15)];
      acc[m][0] = iv; acc[m][1] = iv; acc[m][2] = iv; acc[m][3] = iv;
    }
    kloop<2, 8>(acc, SAp, 512, rt, fbWo, 16, 0, ctb, l);
#pragma unroll
    for (int m = 0; m < 2; ++m) {
      int c = (ctb + 8 * m) * 16 + (l & 15);
      int rbase = rt * 16 + ((l >> 4) << 2);
      float np = 0.f;
#pragma unroll
      for (int ri = 0; ri < 4; ++ri) {
        int r = rbase + ri;
        float eo = acc[m][ri];
        np += eo * Mmask[r];
        EF[r * 256 + c] = eo + edge_features[((size_t)n * K_NB + r) * H_DIM + c];
      }
      atomicAdd(&Mnp[c], np);
    }
  }
  __syncthreads();

  // ---- phase 9a: LN stats of ef; 8a: nfv + node-LN partials ----
  {
    int rr = t >> 5, j = t & 31;
    float s1 = 0.f, s2 = 0.f;
#pragma unroll
    for (int m2 = 0; m2 < 8; ++m2) {
      float xv = EF[rr * 256 + j + 32 * m2];
      s1 += xv; s2 += xv * xv;
    }
    s1 += __shfl_xor(s1, 16, 32); s2 += __shfl_xor(s2, 16, 32);
    s1 += __shfl_xor(s1, 8, 32);  s2 += __shfl_xor(s2, 8, 32);
    s1 += __shfl_xor(s1, 4, 32);  s2 += __shfl_xor(s2, 4, 32);
    s1 += __shfl_xor(s1, 2, 32);  s2 += __shfl_xor(s2, 2, 32);
    s1 += __shfl_xor(s1, 1, 32);  s2 += __shfl_xor(s2, 1, 32);
    if (j == 0) {
      float mu2 = s1 * (1.f / 256.f);
      float v2 = s2 * (1.f / 256.f) - mu2 * mu2;
      Mmu[rr] = mu2; Mrstd[rr] = rsqrtf(v2 + 1e-5f);
    }
  }
  float cntv = 1e-5f;
#pragma unroll
  for (int kk = 0; kk < 32; ++kk) cntv += Mmask[kk];
  float nfv = 0.f;
  if (t < 256) {
    nfv = Mnp[t] / cntv + node_features[n * H_DIM + t];
    float sv = nfv, sq = nfv * nfv;
    for (int m = 32; m >= 1; m >>= 1) { sv += __shfl_xor(sv, m, 64); sq += __shfl_xor(sq, m, 64); }
    if ((t & 63) == 0) { Mred[t >> 6] = sv; Mred[4 + (t >> 6)] = sq; }
  }
  __syncthreads();

  // ---- 9c: node LN -> Mnh2 ; 9d: eh2 = LN(ef) -> SA bf16 ----
  if (t < 256) {
    float sum = Mred[0] + Mred[1] + Mred[2] + Mred[3];
    float ssum = Mred[4] + Mred[5] + Mred[6] + Mred[7];
    float mu = sum * (1.f / 256.f);
    float var = ssum * (1.f / 256.f) - mu * mu;
    float rstd = rsqrtf(var + 1e-5f);
    Mnh2[t] = (nfv - mu) * rstd * lfg[t] + lfb[t];
  }
  {
    int col = t & 255, rgp = t >> 8;
    float g2 = lfg[col], b2v = lfb[col];
#pragma unroll
    for (int r8 = 0; r8 < 8; ++r8) {
      int row = rgp * 8 + r8;
      float xv = (EF[row * 256 + col] - Mmu[row]) * Mrstd[row] * g2 + b2v;
      stb16(SAp, 512, row, col, xv);
    }
  }
  __syncthreads();

  // ---- phases 10+11 (k-split halves, h1e half-buffer in SQ) + node FFN ----
  f4v acc2[2];
#pragma unroll
  for (int m = 0; m < 2; ++m) {
    float iv = c2e[(ctb + 8 * m) * 16 + (l & 15)];
    acc2[m][0] = iv; acc2[m][1] = iv; acc2[m][2] = iv; acc2[m][3] = iv;
  }
#pragma unroll
  for (int half = 0; half < 2; ++half) {
    // phase 10 half: h1e[:, half*256 : half*256+256] = gelu(eh2 @ w1e_half + c1e_half)
    {
      f4v acc[2];
#pragma unroll
      for (int m = 0; m < 2; ++m) {
        float iv = c1e[(half * 16 + ctb + 8 * m) * 16 + (l & 15)];
        acc[m][0] = iv; acc[m][1] = iv; acc[m][2] = iv; acc[m][3] = iv;
      }
      kloop<2, 8>(acc, SAp, 512, rt, fbW1e, 32, 0, half * 16 + ctb, l);
#pragma unroll
      for (int m = 0; m < 2; ++m) {
        int c = (ctb + 8 * m) * 16 + (l & 15);
#pragma unroll
        for (int ri = 0; ri < 4; ++ri)
          stb16(SQp, 512, rt * 16 + ((l >> 4) << 2) + ri, c, gelu_f(acc[m][ri]));
      }
    }
    if (half == 0 && t < FFH) {     // 8b: node FFN hidden (fp32), overlapped
      float a = c1n[t];
      for (int i = 0; i < H_DIM; ++i) a += Mnh2[i] * w1n[(size_t)i * FFH + t];
      Mh1[t] = gelu_f(a);
    }
    __syncthreads();
    // phase 11 half: acc2 += h1e_half @ w2e[half*256 : , :]
    kloop<2, 8>(acc2, SQp, 512, rt, fbW2e, 16, half * 8, ctb, l);
    __syncthreads();  // SQ reused next half
  }

  // ---- epilogues ----
#pragma unroll
  for (int m = 0; m < 2; ++m) {
    int c = (ctb + 8 * m) * 16 + (l & 15);
    int rbase = rt * 16 + ((l >> 4) << 2);
#pragma unroll
    for (int ri = 0; ri < 4; ++ri) {
      int r = rbase + ri;
      float o = acc2[m][ri] + EF[r * 256 + c];
      atomicAdd(&out_edge[((size_t)n * K_NB + r) * H_DIM + c], gate * o);
    }
  }
  if (t < 256) {   // 8c: node FFN out (fp32)
    float o = nfv + c2n[t];
    for (int i = 0; i < FFH; ++i) o += Mh1[i] * w2n[(size_t)i * H_DIM + t];
    atomicAdd(&out_node[n * H_DIM + t], gate * o);
  }
}

// ---------------------------------------------------------------- launch
extern "C" void kernel_launch(void* const* d_in, const int* in_sizes, int n_in,
                              void* d_out, int out_size, void* d_ws, size_t ws_size,
                              hipStream_t stream) {
  const float* node_features = (const float*)d_in[0];
  const float* edge_features = (const float*)d_in[1];
  const float* edge_raw      = (const float*)d_in[2];
  const int*   neighbor_list = (const int*)d_in[3];
  const float* neighbor_mask = (const float*)d_in[4];
  const float* w_gate        = (const float*)d_in[6];
  const float* W_edge = (const float*)d_in[7];
  const float* b_edge = (const float*)d_in[8];
  const float* W_node = (const float*)d_in[9];
  const float* b_node = (const float*)d_in[10];
  const float* W_msg  = (const float*)d_in[11];
  const float* b_msg  = (const float*)d_in[12];
  const float* W_qkv  = (const float*)d_in[13];
  const float* b_qkv  = (const float*)d_in[14];
  const float* W_out  = (const float*)d_in[15];
  const float* b_out  = (const float*)d_in[16];
  const float* ln_attn_g = (const float*)d_in[17];
  const float* ln_attn_b = (const float*)d_in[18];
  const float* ln_ffn_g  = (const float*)d_in[19];
  const float* ln_ffn_b  = (const float*)d_in[20];
  const float* W1n = (const float*)d_in[21];
  const float* b1n = (const float*)d_in[22];
  const float* W2n = (const float*)d_in[23];
  const float* b2n = (const float*)d_in[24];
  const float* W1e = (const float*)d_in[25];
  const float* b1e = (const float*)d_in[26];
  const float* W2e = (const float*)d_in[27];
  const float* b2e = (const float*)d_in[28];

  unsigned short* nh16 = (unsigned short*)d_ws;           // 2097152 bf16
  unsigned short* fbp  = nh16 + NH_ELEMS;                 // 6029312 bf16
  int*   sel_ne  = (int*)(fbp + (size_t)N_EXP * EXP_STRIDE);
  float* sel_g   = (float*)(sel_ne + 2048);
  int*   work_ne = (int*)(sel_g + 2048);
  float* work_g  = (float*)(work_ne + 2048);

  float* out_node = (float*)d_out;
  float* out_edge = out_node + N_NODES * H_DIM;

  hipMemsetAsync(d_out, 0, (size_t)out_size * sizeof(float), stream);

  gate_kernel<<<N_NODES, 64, 0, stream>>>(node_features, w_gate, sel_ne, sel_g);
  sort_kernel<<<1, 256, 0, stream>>>(sel_ne, sel_g, work_ne, work_g);
  nh_kernel<<<dim3(N_NODES, N_EXP), 256, 0, stream>>>(node_features, ln_attn_g, ln_attn_b, nh16);
  wconv<<<dim3(1472, N_EXP), 64, 0, stream>>>(W_node, W_msg, W_edge, W_qkv, W_out, W1e, W2e, fbp);

  size_t smem = 81408;   // <= 81920 -> 2 blocks/CU
  hipFuncSetAttribute((const void*)moe_main, hipFuncAttributeMaxDynamicSharedMemorySize, (int)smem);
  moe_main<<<N_NODES * NTOPK, 1024, smem, stream>>>(
      node_features, edge_features, edge_raw, neighbor_list, neighbor_mask,
      W_node, b_node, b_edge, b_msg, b_qkv, b_out,
      ln_ffn_g, ln_ffn_b, W1n, b1n, W2n, b2n, b1e, b2e,
      nh16, fbp, work_ne, work_g, out_node, out_edge);
}

// Round 6
// 766.317 us; speedup vs baseline: 2.4582x; 1.4511x over previous
//
#include <hip/hip_runtime.h>
#include <math.h>

#define N_NODES 1024
#define K_NB    32
#define H_DIM   256
#define DE_DIM  128
#define N_EXP   8
#define NTOPK   2
#define FFH     512

typedef __attribute__((ext_vector_type(8))) short s8v;   // 8 bf16 = 4 VGPR
typedef __attribute__((ext_vector_type(4))) float f4v;   // MFMA acc

// ---- ws layout (elements) ----
#define NH_ELEMS   (N_EXP * N_NODES * H_DIM)   // 2097152 bf16
// per-expert fragment-pool offsets (bf16 elems)
#define OFF_WN   0
#define OFF_WM   65536
#define OFF_WE   196608
#define OFF_WQ   229376
#define OFF_WO   425984
#define OFF_W1E  491520
#define OFF_W2E  622592
#define EXP_STRIDE 753664

// ---------------------------------------------------------------- helpers
__device__ __forceinline__ unsigned short f2bf(float x) {
  unsigned u = __float_as_uint(x);
  unsigned r = u + 0x7FFFu + ((u >> 16) & 1u);   // RNE
  return (unsigned short)(r >> 16);
}
__device__ __forceinline__ float bf2f(unsigned short h) {
  return __uint_as_float((unsigned)h << 16);
}
__device__ __forceinline__ float gelu_f(float x) {
  float u = 0.7978845608028654f * (x + 0.044715f * x * x * x);
  float ex = __expf(2.f * u);
  float th = 1.f - 2.f / (ex + 1.f);
  return 0.5f * x * (1.f + th);
}

// A-fragment read from row-major bf16 LDS tile with XOR swizzle.
__device__ __forceinline__ s8v lda(const char* base, int SBv, int rt, int kt, int l) {
  int r = rt * 16 + (l & 15);
  int byte = r * SBv + kt * 64 + ((l >> 4) << 4);
  return *(const s8v*)(base + (byte ^ ((r & 7) << 4)));
}
__device__ __forceinline__ void stb16(char* base, int SBv, int r, int c, float v) {
  *(unsigned short*)(base + ((r * SBv + c * 2) ^ ((r & 7) << 4))) = f2bf(v);
}

// K-loop: NA output tiles (ct = ctb0 + CSTR*m), NKT k-steps.
template<int NA, int NKT, int CSTR>
__device__ __forceinline__ void kloop(f4v acc[NA], const char* Ab, int ASB, int rt,
                                      const unsigned short* __restrict__ fb, int NCT,
                                      int ktb0, int ctb0, int l) {
  __builtin_amdgcn_s_setprio(1);
  for (int kt = 0; kt < NKT; ++kt) {
    s8v av = lda(Ab, ASB, rt, kt, l);
#pragma unroll
    for (int m = 0; m < NA; ++m) {
      s8v bv = *(const s8v*)(fb + (((size_t)(ktb0 + kt) * NCT + (ctb0 + CSTR * m)) * 64 + l) * 8);
      acc[m] = __builtin_amdgcn_mfma_f32_16x16x32_bf16(av, bv, acc[m], 0, 0, 0);
    }
  }
  __builtin_amdgcn_s_setprio(0);
}

// ---------------------------------------------------------------- gating
__global__ __launch_bounds__(64)
void gate_kernel(const float* __restrict__ nf, const float* __restrict__ wg,
                 int* __restrict__ sel_ne, float* __restrict__ sel_g) {
  int n = blockIdx.x, t = threadIdx.x;
  float p[8] = {0, 0, 0, 0, 0, 0, 0, 0};
  for (int j = 0; j < 4; ++j) {
    float x = nf[n * H_DIM + t + 64 * j];
#pragma unroll
    for (int e = 0; e < 8; ++e) p[e] += x * wg[(t + 64 * j) * 8 + e];
  }
#pragma unroll
  for (int e = 0; e < 8; ++e)
    for (int m = 32; m >= 1; m >>= 1) p[e] += __shfl_xor(p[e], m, 64);
  if (t == 0) {
    int i0 = 0; float v0 = p[0];
    for (int e = 1; e < 8; ++e) if (p[e] > v0) { v0 = p[e]; i0 = e; }
    int i1 = -1; float v1 = -3.4e38f;
    for (int e = 0; e < 8; ++e) if (e != i0 && p[e] > v1) { v1 = p[e]; i1 = e; }
    float g1 = __expf(v1 - v0);
    float inv = 1.f / (1.f + g1);
    sel_ne[n * 2 + 0] = (n << 3) | i0; sel_g[n * 2 + 0] = inv;
    sel_ne[n * 2 + 1] = (n << 3) | i1; sel_g[n * 2 + 1] = g1 * inv;
  }
}

__global__ __launch_bounds__(256)
void sort_kernel(const int* __restrict__ sel_ne, const float* __restrict__ sel_g,
                 int* __restrict__ work_ne, float* __restrict__ work_g) {
  __shared__ int cnt[8], off[8], cur[8];
  int t = threadIdx.x;
  if (t < 8) { cnt[t] = 0; cur[t] = 0; }
  __syncthreads();
  for (int i = t; i < N_NODES * NTOPK; i += 256) atomicAdd(&cnt[sel_ne[i] & 7], 1);
  __syncthreads();
  if (t == 0) { int s = 0; for (int e = 0; e < 8; ++e) { off[e] = s; s += cnt[e]; } }
  __syncthreads();
  for (int i = t; i < N_NODES * NTOPK; i += 256) {
    int pe = sel_ne[i]; int e = pe & 7;
    int pos = off[e] + atomicAdd(&cur[e], 1);
    work_ne[pos] = pe; work_g[pos] = sel_g[i];
  }
}

// per-expert LayerNorm of all nodes -> bf16
__global__ __launch_bounds__(256)
void nh_kernel(const float* __restrict__ nf, const float* __restrict__ lag,
               const float* __restrict__ lab, unsigned short* __restrict__ nh16) {
  __shared__ float red[8];
  int n = blockIdx.x, e = blockIdx.y, t = threadIdx.x;
  float x = nf[n * H_DIM + t];
  float sv = x, sq = x * x;
  for (int m = 32; m >= 1; m >>= 1) { sv += __shfl_xor(sv, m, 64); sq += __shfl_xor(sq, m, 64); }
  if ((t & 63) == 0) { red[t >> 6] = sv; red[4 + (t >> 6)] = sq; }
  __syncthreads();
  float sum = red[0] + red[1] + red[2] + red[3];
  float ssum = red[4] + red[5] + red[6] + red[7];
  float mu = sum * (1.f / 256.f);
  float var = ssum * (1.f / 256.f) - mu * mu;
  float rstd = rsqrtf(var + 1e-5f);
  nh16[((size_t)e * N_NODES + n) * H_DIM + t] =
      f2bf((x - mu) * rstd * lag[e * H_DIM + t] + lab[e * H_DIM + t]);
}

// ------------------------------------------------ weight -> bf16 fragments
__global__ __launch_bounds__(64)
void wconv(const float* __restrict__ W_node, const float* __restrict__ W_msg,
           const float* __restrict__ W_edge, const float* __restrict__ W_qkv,
           const float* __restrict__ W_out, const float* __restrict__ W1e,
           const float* __restrict__ W2e, unsigned short* __restrict__ fb) {
  int f = blockIdx.x, e = blockIdx.y, l = threadIdx.x;
  const float* src; int C, nct, fl; size_t off;
  if (f < 128)       { src = W_node + (size_t)e * 131072; C = 256; nct = 16; fl = f;        off = OFF_WN;  }
  else if (f < 384)  { src = W_msg  + (size_t)e * 131072; C = 256; nct = 16; fl = f - 128;  off = OFF_WM;  }
  else if (f < 448)  { src = W_edge + (size_t)e * 32768;  C = 256; nct = 16; fl = f - 384;  off = OFF_WE;  }
  else if (f < 832)  { src = W_qkv  + (size_t)e * 196608; C = 768; nct = 48; fl = f - 448;  off = OFF_WQ;  }
  else if (f < 960)  { src = W_out  + (size_t)e * 65536;  C = 256; nct = 16; fl = f - 832;  off = OFF_WO;  }
  else if (f < 1216) { src = W1e    + (size_t)e * 131072; C = 512; nct = 32; fl = f - 960;  off = OFF_W1E; }
  else               { src = W2e    + (size_t)e * 131072; C = 256; nct = 16; fl = f - 1216; off = OFF_W2E; }
  int kt = fl / nct, ct = fl - kt * nct;
  int k0 = kt * 32 + ((l >> 4) << 3), c = ct * 16 + (l & 15);
  unsigned pk[4];
#pragma unroll
  for (int jj = 0; jj < 4; ++jj) {
    unsigned short a = f2bf(src[(size_t)(k0 + 2 * jj) * C + c]);
    unsigned short b = f2bf(src[(size_t)(k0 + 2 * jj + 1) * C + c]);
    pk[jj] = (unsigned)a | ((unsigned)b << 16);
  }
  unsigned short* dst = fb + (size_t)e * EXP_STRIDE + off + ((size_t)fl * 64 + l) * 8;
  *(uint4*)dst = make_uint4(pk[0], pk[1], pk[2], pk[3]);
}

// ---------------------------------------------------------------- main
// 512 threads (8 waves), __launch_bounds__(512,4): 2 blocks/CU (LDS 2x81408
// <= 160K) AND 128 regs/thread -> no spills (the R5 failure mode).
// Wave tiling: rt = w&1, ctb = w>>1 in 0..3; col-tiles ct = ctb + 4m.
__global__ __launch_bounds__(512, 4)
void moe_main(const float* __restrict__ node_features,
              const float* __restrict__ edge_features,
              const float* __restrict__ edge_raw,
              const int* __restrict__ neighbor_list,
              const float* __restrict__ neighbor_mask,
              const float* __restrict__ W_node_f32, const float* __restrict__ bn,
              const float* __restrict__ be, const float* __restrict__ bm,
              const float* __restrict__ bq, const float* __restrict__ bo,
              const float* __restrict__ ln_ffn_g, const float* __restrict__ ln_ffn_b,
              const float* __restrict__ W1n, const float* __restrict__ b1n,
              const float* __restrict__ W2n, const float* __restrict__ b2n,
              const float* __restrict__ b1e, const float* __restrict__ b2e,
              const unsigned short* __restrict__ nh16,
              const unsigned short* __restrict__ fb,
              const int* __restrict__ work_ne, const float* __restrict__ work_g,
              float* __restrict__ out_node, float* __restrict__ out_edge) {
  extern __shared__ char sm[];
  char* SAp = sm;                      // 16K: sender -> msg -> ctx -> eh2
  char* SBp = sm + 16384;              // 16K: nodeh -> k
  char* SCp = sm + 32768;              // 16K: eh -> v
  float* EF = (float*)(sm + 16384);    // 32K f32 [32][256] (overlays SB+SC)
  char* SDp = sm + 49152;              // 8K : edge_raw bf16
  char* SQp = sm + 57344;              // 16K: q bf16 -> h1e half
  float* MF = (float*)(sm + 73728);
  float* Mrecv = MF;            // 256
  float* Mrv2  = MF + 256;      // 512
  float* Mnp   = MF + 768;      // 256
  float* Mnh2  = MF + 1024;     // 256
  float* Mh1   = MF + 1280;     // 512
  float* Mred  = MF + 1792;     // 8
  float* Mmask = MF + 1800;     // 32
  float* Mmu   = MF + 1832;     // 32
  float* Mrstd = MF + 1864;     // 32

  const int t = threadIdx.x;
  const int pe = work_ne[blockIdx.x];
  const int n = pe >> 3, e = pe & 7;
  const float gate = work_g[blockIdx.x];

  const unsigned short* fbE   = fb + (size_t)e * EXP_STRIDE;
  const unsigned short* fbWn  = fbE + OFF_WN;
  const unsigned short* fbWm  = fbE + OFF_WM;
  const unsigned short* fbWe  = fbE + OFF_WE;
  const unsigned short* fbWq  = fbE + OFF_WQ;
  const unsigned short* fbWo  = fbE + OFF_WO;
  const unsigned short* fbW1e = fbE + OFF_W1E;
  const unsigned short* fbW2e = fbE + OFF_W2E;

  const float* Wn2  = W_node_f32 + (size_t)e * 131072;
  const float* bnE  = bn + e * H_DIM;
  const float* beE  = be + e * H_DIM;
  const float* bmE  = bm + e * H_DIM;
  const float* bqE  = bq + e * 3 * H_DIM;
  const float* boE  = bo + e * H_DIM;
  const float* lfg  = ln_ffn_g + e * H_DIM;
  const float* lfb  = ln_ffn_b + e * H_DIM;
  const float* w1n  = W1n + (size_t)e * H_DIM * FFH;
  const float* c1n  = b1n + e * FFH;
  const float* w2n  = W2n + (size_t)e * FFH * H_DIM;
  const float* c2n  = b2n + e * H_DIM;
  const float* c1e  = b1e + e * FFH;
  const float* c2e  = b2e + e * H_DIM;

  const int w = t >> 6, l = t & 63;
  const int rt = w & 1, ctb = w >> 1;   // ctb in 0..3

  // ---- stage ----
  const unsigned short* nh_e = nh16 + (size_t)e * N_NODES * H_DIM;
#pragma unroll
  for (int rr2 = 0; rr2 < 2; ++rr2) {
    int r = (t >> 5) + 16 * rr2, j = t & 31;
    int nbr = neighbor_list[n * K_NB + r];
    uint4 val = ((const uint4*)(nh_e + (size_t)nbr * H_DIM))[j];
    *(uint4*)(SAp + ((r * 512 + j * 16) ^ ((r & 7) << 4))) = val;
  }
  if (t < 256) Mrecv[t] = bf2f(nh_e[(size_t)n * H_DIM + t]);
#pragma unroll
  for (int rr2 = 0; rr2 < 2; ++rr2) {
    int r = (t >> 5) + 16 * rr2, c = (t & 31) * 4;
    float4 v = *(const float4*)(edge_raw + ((size_t)n * K_NB + r) * DE_DIM + c);
    unsigned p0 = (unsigned)f2bf(v.x) | ((unsigned)f2bf(v.y) << 16);
    unsigned p1 = (unsigned)f2bf(v.z) | ((unsigned)f2bf(v.w) << 16);
    *(uint2*)(SDp + ((r * 256 + c * 2) ^ ((r & 7) << 4))) = make_uint2(p0, p1);
  }
  if (t < 32) Mmask[t] = neighbor_mask[n * K_NB + t];
  if (t < 256) Mnp[t] = 0.f;
  __syncthreads();

  // ---- recv rank-1: Mrv[c] = sum_i recv[i]*Wn[256+i][c] + bn[c] (fp32) ----
  {
    int c = t & 255, part = t >> 8;   // part in 0..1
    float s = 0.f;
    for (int i = 0; i < 128; ++i)
      s += Mrecv[part * 128 + i] * Wn2[(size_t)(256 + part * 128 + i) * 256 + c];
    Mrv2[part * 256 + c] = s;
  }
  __syncthreads();
  if (t < 256) Mrecv[t] = Mrv2[t] + Mrv2[256 + t] + bnE[t];
  __syncthreads();

  // ---- phase 1: nodeh = gelu(sender@Wn1 + Mrv) -> SB ----
  {
    f4v acc[4];
#pragma unroll
    for (int m = 0; m < 4; ++m) {
      float iv = Mrecv[(ctb + 4 * m) * 16 + (l & 15)];
      acc[m][0] = iv; acc[m][1] = iv; acc[m][2] = iv; acc[m][3] = iv;
    }
    kloop<4, 8, 4>(acc, SAp, 512, rt, fbWn, 16, 0, ctb, l);
#pragma unroll
    for (int m = 0; m < 4; ++m) {
      int c = (ctb + 4 * m) * 16 + (l & 15);
#pragma unroll
      for (int ri = 0; ri < 4; ++ri)
        stb16(SBp, 512, rt * 16 + ((l >> 4) << 2) + ri, c, gelu_f(acc[m][ri]));
    }
  }
  // ---- phase 3: eh = gelu(edge_raw@We + be) -> SC ----
  {
    f4v acc[4];
#pragma unroll
    for (int m = 0; m < 4; ++m) {
      float iv = beE[(ctb + 4 * m) * 16 + (l & 15)];
      acc[m][0] = iv; acc[m][1] = iv; acc[m][2] = iv; acc[m][3] = iv;
    }
    kloop<4, 4, 4>(acc, SDp, 256, rt, fbWe, 16, 0, ctb, l);
#pragma unroll
    for (int m = 0; m < 4; ++m) {
      int c = (ctb + 4 * m) * 16 + (l & 15);
#pragma unroll
      for (int ri = 0; ri < 4; ++ri)
        stb16(SCp, 512, rt * 16 + ((l >> 4) << 2) + ri, c, gelu_f(acc[m][ri]));
    }
  }
  __syncthreads();

  // ---- phase 2+4: msg = gelu([eh|nodeh]@Wm + bm) -> SA ----
  {
    f4v acc[4];
#pragma unroll
    for (int m = 0; m < 4; ++m) {
      float iv = bmE[(ctb + 4 * m) * 16 + (l & 15)];
      acc[m][0] = iv; acc[m][1] = iv; acc[m][2] = iv; acc[m][3] = iv;
    }
    kloop<4, 8, 4>(acc, SCp, 512, rt, fbWm, 16, 0, ctb, l);   // eh    (rows 0..255)
    kloop<4, 8, 4>(acc, SBp, 512, rt, fbWm, 16, 8, ctb, l);   // nodeh (rows 256..511)
#pragma unroll
    for (int m = 0; m < 4; ++m) {
      int c = (ctb + 4 * m) * 16 + (l & 15);
#pragma unroll
      for (int ri = 0; ri < 4; ++ri)
        stb16(SAp, 512, rt * 16 + ((l >> 4) << 2) + ri, c, gelu_f(acc[m][ri]));
    }
  }
  __syncthreads();

  // ---- phase 5: qkv = msg@Wq + bq (two NA=6 passes); q->SQ, k->SB, v->SC ----
#pragma unroll
  for (int p = 0; p < 2; ++p) {
    f4v acc[6];
#pragma unroll
    for (int m = 0; m < 6; ++m) {
      float iv = bqE[(ctb + 24 * p + 4 * m) * 16 + (l & 15)];
      acc[m][0] = iv; acc[m][1] = iv; acc[m][2] = iv; acc[m][3] = iv;
    }
    kloop<6, 8, 4>(acc, SAp, 512, rt, fbWq, 48, 0, ctb + 24 * p, l);
#pragma unroll
    for (int m = 0; m < 6; ++m) {
      int cg = (ctb + 24 * p + 4 * m) * 16 + (l & 15);
      int rbase = rt * 16 + ((l >> 4) << 2);
      char* dst = (cg < 256) ? SQp : ((cg < 512) ? SBp : SCp);
      int cl = cg & 255;
#pragma unroll
      for (int ri = 0; ri < 4; ++ri) stb16(dst, 512, rbase + ri, cl, acc[m][ri]);
    }
  }
  __syncthreads();

  // ---- phase 6: attention, 512 threads: (h = t>>6, q = (t>>1)&31, part = t&1) ----
  {
    const int hh = t >> 6, qq = (t >> 1) & 31, part = t & 1;
    const int cb = hh * 64;  // byte offset of this head's 32 dims (bf16)
    // stage A: scores for keys kk = part + 2j (q streamed)
    float s[16];
#pragma unroll
    for (int j = 0; j < 16; ++j) s[j] = 0.f;
#pragma unroll
    for (int d4 = 0; d4 < 8; ++d4) {
      uint2 qb = *(const uint2*)(SQp + ((qq * 512 + cb + d4 * 8) ^ ((qq & 7) << 4)));
      float q0 = bf2f(qb.x & 0xffff), q1 = bf2f(qb.x >> 16);
      float q2 = bf2f(qb.y & 0xffff), q3 = bf2f(qb.y >> 16);
#pragma unroll
      for (int j = 0; j < 16; ++j) {
        int kk = part + 2 * j;
        uint2 kb = *(const uint2*)(SBp + ((kk * 512 + cb + d4 * 8) ^ ((kk & 7) << 4)));
        s[j] += q0 * bf2f(kb.x & 0xffff) + q1 * bf2f(kb.x >> 16) +
                q2 * bf2f(kb.y & 0xffff) + q3 * bf2f(kb.y >> 16);
      }
    }
    const float scale = 0.17677669529663687f;  // 1/sqrt(32)
    float m = -3.4e38f;
#pragma unroll
    for (int j = 0; j < 16; ++j) {
      int kk = part + 2 * j;
      float mv = (Mmask[kk] > 0.f) ? 0.f : -1e9f;
      s[j] = s[j] * scale + mv;
      m = fmaxf(m, s[j]);
    }
    m = fmaxf(m, __shfl_xor(m, 1, 64));
    float sum = 0.f;
#pragma unroll
    for (int j = 0; j < 16; ++j) { s[j] = __expf(s[j] - m); sum += s[j]; }
    sum += __shfl_xor(sum, 1, 64);
    float inv = 1.f / sum;
#pragma unroll
    for (int j = 0; j < 16; ++j) s[j] *= inv;
    // stage B: this thread owns dims [part*16, part*16+16); probs via shfl
    float cx[16];
#pragma unroll
    for (int d = 0; d < 16; ++d) cx[d] = 0.f;
#pragma unroll
    for (int x = 0; x < 2; ++x) {
      int ps = part ^ x;
#pragma unroll
      for (int j = 0; j < 16; ++j) {
        float p = __shfl_xor(s[j], x, 64);
        int kk = ps + 2 * j;
        const char* vrow = SCp + ((kk * 512 + cb + part * 32) ^ ((kk & 7) << 4));
        uint4 v0 = *(const uint4*)vrow;
        uint4 v1 = *(const uint4*)(vrow + 16);
        cx[0]  += p * bf2f(v0.x & 0xffff); cx[1]  += p * bf2f(v0.x >> 16);
        cx[2]  += p * bf2f(v0.y & 0xffff); cx[3]  += p * bf2f(v0.y >> 16);
        cx[4]  += p * bf2f(v0.z & 0xffff); cx[5]  += p * bf2f(v0.z >> 16);
        cx[6]  += p * bf2f(v0.w & 0xffff); cx[7]  += p * bf2f(v0.w >> 16);
        cx[8]  += p * bf2f(v1.x & 0xffff); cx[9]  += p * bf2f(v1.x >> 16);
        cx[10] += p * bf2f(v1.y & 0xffff); cx[11] += p * bf2f(v1.y >> 16);
        cx[12] += p * bf2f(v1.z & 0xffff); cx[13] += p * bf2f(v1.z >> 16);
        cx[14] += p * bf2f(v1.w & 0xffff); cx[15] += p * bf2f(v1.w >> 16);
      }
    }
    // note: part*32 crosses a 16B swizzle unit only at part=1 with (kk&7)>=1;
    // the XOR applies to bits [4..6] of the byte addr and both 16B halves of
    // a 32B-aligned pair swizzle identically, so the two uint4 reads are the
    // correct contiguous dims. ctx write mirrors the same addressing.
    char* crow = SAp + ((qq * 512 + cb + part * 32) ^ ((qq & 7) << 4));
    unsigned o0 = (unsigned)f2bf(cx[0])  | ((unsigned)f2bf(cx[1])  << 16);
    unsigned o1 = (unsigned)f2bf(cx[2])  | ((unsigned)f2bf(cx[3])  << 16);
    unsigned o2 = (unsigned)f2bf(cx[4])  | ((unsigned)f2bf(cx[5])  << 16);
    unsigned o3 = (unsigned)f2bf(cx[6])  | ((unsigned)f2bf(cx[7])  << 16);
    *(uint4*)crow = make_uint4(o0, o1, o2, o3);
    unsigned o4 = (unsigned)f2bf(cx[8])  | ((unsigned)f2bf(cx[9])  << 16);
    unsigned o5 = (unsigned)f2bf(cx[10]) | ((unsigned)f2bf(cx[11]) << 16);
    unsigned o6 = (unsigned)f2bf(cx[12]) | ((unsigned)f2bf(cx[13]) << 16);
    unsigned o7 = (unsigned)f2bf(cx[14]) | ((unsigned)f2bf(cx[15]) << 16);
    *(uint4*)(crow + 16) = make_uint4(o4, o5, o6, o7);
  }
  __syncthreads();

  // ---- phase 7: edge_out = ctx@Wo + bo; np partials; ef -> EF (over k/v) ----
  {
    f4v acc[4];
#pragma unroll
    for (int m = 0; m < 4; ++m) {
      float iv = boE[(ctb + 4 * m) * 16 + (l & 15)];
      acc[m][0] = iv; acc[m][1] = iv; acc[m][2] = iv; acc[m][3] = iv;
    }
    kloop<4, 8, 4>(acc, SAp, 512, rt, fbWo, 16, 0, ctb, l);
#pragma unroll
    for (int m = 0; m < 4; ++m) {
      int c = (ctb + 4 * m) * 16 + (l & 15);
      int rbase = rt * 16 + ((l >> 4) << 2);
      float np = 0.f;
#pragma unroll
      for (int ri = 0; ri < 4; ++ri) {
        int r = rbase + ri;
        float eo = acc[m][ri];
        np += eo * Mmask[r];
        EF[r * 256 + c] = eo + edge_features[((size_t)n * K_NB + r) * H_DIM + c];
      }
      atomicAdd(&Mnp[c], np);
    }
  }
  __syncthreads();

  // ---- phase 9a: LN stats of ef; 8a: nfv + node-LN partials ----
  {
    int rr = t >> 4, j = t & 15;
    float s1 = 0.f, s2 = 0.f;
#pragma unroll
    for (int m2 = 0; m2 < 16; ++m2) {
      float xv = EF[rr * 256 + j + 16 * m2];
      s1 += xv; s2 += xv * xv;
    }
    s1 += __shfl_xor(s1, 8, 64); s2 += __shfl_xor(s2, 8, 64);
    s1 += __shfl_xor(s1, 4, 64); s2 += __shfl_xor(s2, 4, 64);
    s1 += __shfl_xor(s1, 2, 64); s2 += __shfl_xor(s2, 2, 64);
    s1 += __shfl_xor(s1, 1, 64); s2 += __shfl_xor(s2, 1, 64);
    if (j == 0) {
      float mu2 = s1 * (1.f / 256.f);
      float v2 = s2 * (1.f / 256.f) - mu2 * mu2;
      Mmu[rr] = mu2; Mrstd[rr] = rsqrtf(v2 + 1e-5f);
    }
  }
  float cntv = 1e-5f;
#pragma unroll
  for (int kk = 0; kk < 32; ++kk) cntv += Mmask[kk];
  float nfv = 0.f;
  if (t < 256) {
    nfv = Mnp[t] / cntv + node_features[n * H_DIM + t];
    float sv = nfv, sq = nfv * nfv;
    for (int m = 32; m >= 1; m >>= 1) { sv += __shfl_xor(sv, m, 64); sq += __shfl_xor(sq, m, 64); }
    if ((t & 63) == 0) { Mred[t >> 6] = sv; Mred[4 + (t >> 6)] = sq; }
  }
  __syncthreads();

  // ---- 9c: node LN -> Mnh2 ; 9d: eh2 = LN(ef) -> SA bf16 ----
  if (t < 256) {
    float sum = Mred[0] + Mred[1] + Mred[2] + Mred[3];
    float ssum = Mred[4] + Mred[5] + Mred[6] + Mred[7];
    float mu = sum * (1.f / 256.f);
    float var = ssum * (1.f / 256.f) - mu * mu;
    float rstd = rsqrtf(var + 1e-5f);
    Mnh2[t] = (nfv - mu) * rstd * lfg[t] + lfb[t];
  }
  {
    int col = t & 255, rgp = t >> 8;
    float g2 = lfg[col], b2v = lfb[col];
#pragma unroll
    for (int r8 = 0; r8 < 16; ++r8) {
      int row = rgp * 16 + r8;
      float xv = (EF[row * 256 + col] - Mmu[row]) * Mrstd[row] * g2 + b2v;
      stb16(SAp, 512, row, col, xv);
    }
  }
  __syncthreads();

  // ---- phases 10+11 (k-split halves, h1e half-buffer in SQ) + node FFN ----
  f4v acc2[4];
#pragma unroll
  for (int m = 0; m < 4; ++m) {
    float iv = c2e[(ctb + 4 * m) * 16 + (l & 15)];
    acc2[m][0] = iv; acc2[m][1] = iv; acc2[m][2] = iv; acc2[m][3] = iv;
  }
#pragma unroll
  for (int half = 0; half < 2; ++half) {
    // phase 10 half: h1e[:, half*256 : +256] = gelu(eh2 @ w1e_half + c1e_half)
    {
      f4v acc[4];
#pragma unroll
      for (int m = 0; m < 4; ++m) {
        float iv = c1e[(half * 16 + ctb + 4 * m) * 16 + (l & 15)];
        acc[m][0] = iv; acc[m][1] = iv; acc[m][2] = iv; acc[m][3] = iv;
      }
      kloop<4, 8, 4>(acc, SAp, 512, rt, fbW1e, 32, 0, half * 16 + ctb, l);
#pragma unroll
      for (int m = 0; m < 4; ++m) {
        int c = (ctb + 4 * m) * 16 + (l & 15);
#pragma unroll
        for (int ri = 0; ri < 4; ++ri)
          stb16(SQp, 512, rt * 16 + ((l >> 4) << 2) + ri, c, gelu_f(acc[m][ri]));
      }
    }
    if (half == 0) {     // 8b: node FFN hidden (fp32), all 512 threads
      float a = c1n[t];
      for (int i = 0; i < H_DIM; ++i) a += Mnh2[i] * w1n[(size_t)i * FFH + t];
      Mh1[t] = gelu_f(a);
    }
    __syncthreads();
    // phase 11 half: acc2 += h1e_half @ w2e[half*256 : , :]
    kloop<4, 8, 4>(acc2, SQp, 512, rt, fbW2e, 16, half * 8, ctb, l);
    __syncthreads();  // SQ reused next half
  }

  // ---- epilogues ----
#pragma unroll
  for (int m = 0; m < 4; ++m) {
    int c = (ctb + 4 * m) * 16 + (l & 15);
    int rbase = rt * 16 + ((l >> 4) << 2);
#pragma unroll
    for (int ri = 0; ri < 4; ++ri) {
      int r = rbase + ri;
      float o = acc2[m][ri] + EF[r * 256 + c];
      atomicAdd(&out_edge[((size_t)n * K_NB + r) * H_DIM + c], gate * o);
    }
  }
  if (t < 256) {   // 8c: node FFN out (fp32)
    float o = nfv + c2n[t];
    for (int i = 0; i < FFH; ++i) o += Mh1[i] * w2n[(size_t)i * H_DIM + t];
    atomicAdd(&out_node[n * H_DIM + t], gate * o);
  }
}

// ---------------------------------------------------------------- launch
extern "C" void kernel_launch(void* const* d_in, const int* in_sizes, int n_in,
                              void* d_out, int out_size, void* d_ws, size_t ws_size,
                              hipStream_t stream) {
  const float* node_features = (const float*)d_in[0];
  const float* edge_features = (const float*)d_in[1];
  const float* edge_raw      = (const float*)d_in[2];
  const int*   neighbor_list = (const int*)d_in[3];
  const float* neighbor_mask = (const float*)d_in[4];
  const float* w_gate        = (const float*)d_in[6];
  const float* W_edge = (const float*)d_in[7];
  const float* b_edge = (const float*)d_in[8];
  const float* W_node = (const float*)d_in[9];
  const float* b_node = (const float*)d_in[10];
  const float* W_msg  = (const float*)d_in[11];
  const float* b_msg  = (const float*)d_in[12];
  const float* W_qkv  = (const float*)d_in[13];
  const float* b_qkv  = (const float*)d_in[14];
  const float* W_out  = (const float*)d_in[15];
  const float* b_out  = (const float*)d_in[16];
  const float* ln_attn_g = (const float*)d_in[17];
  const float* ln_attn_b = (const float*)d_in[18];
  const float* ln_ffn_g  = (const float*)d_in[19];
  const float* ln_ffn_b  = (const float*)d_in[20];
  const float* W1n = (const float*)d_in[21];
  const float* b1n = (const float*)d_in[22];
  const float* W2n = (const float*)d_in[23];
  const float* b2n = (const float*)d_in[24];
  const float* W1e = (const float*)d_in[25];
  const float* b1e = (const float*)d_in[26];
  const float* W2e = (const float*)d_in[27];
  const float* b2e = (const float*)d_in[28];

  unsigned short* nh16 = (unsigned short*)d_ws;           // 2097152 bf16
  unsigned short* fbp  = nh16 + NH_ELEMS;                 // 6029312 bf16
  int*   sel_ne  = (int*)(fbp + (size_t)N_EXP * EXP_STRIDE);
  float* sel_g   = (float*)(sel_ne + 2048);
  int*   work_ne = (int*)(sel_g + 2048);
  float* work_g  = (float*)(work_ne + 2048);

  float* out_node = (float*)d_out;
  float* out_edge = out_node + N_NODES * H_DIM;

  hipMemsetAsync(d_out, 0, (size_t)out_size * sizeof(float), stream);

  gate_kernel<<<N_NODES, 64, 0, stream>>>(node_features, w_gate, sel_ne, sel_g);
  sort_kernel<<<1, 256, 0, stream>>>(sel_ne, sel_g, work_ne, work_g);
  nh_kernel<<<dim3(N_NODES, N_EXP), 256, 0, stream>>>(node_features, ln_attn_g, ln_attn_b, nh16);
  wconv<<<dim3(1472, N_EXP), 64, 0, stream>>>(W_node, W_msg, W_edge, W_qkv, W_out, W1e, W2e, fbp);

  size_t smem = 81408;   // 2 x 81408 = 162816 <= 163840 -> 2 blocks/CU
  hipFuncSetAttribute((const void*)moe_main, hipFuncAttributeMaxDynamicSharedMemorySize, (int)smem);
  moe_main<<<N_NODES * NTOPK, 512, smem, stream>>>(
      node_features, edge_features, edge_raw, neighbor_list, neighbor_mask,
      W_node, b_node, b_edge, b_msg, b_qkv, b_out,
      ln_ffn_g, ln_ffn_b, W1n, b1n, W2n, b2n, b1e, b2e,
      nh16, fbp, work_ne, work_g, out_node, out_edge);
}

// Round 7
// 702.988 us; speedup vs baseline: 2.6796x; 1.0901x over previous
//
#include <hip/hip_runtime.h>
#include <math.h>

#define N_NODES 1024
#define K_NB    32
#define H_DIM   256
#define DE_DIM  128
#define N_EXP   8
#define NTOPK   2
#define FFH     512

typedef __attribute__((ext_vector_type(8))) short s8v;   // 8 bf16 = 4 VGPR
typedef __attribute__((ext_vector_type(4))) float f4v;   // MFMA acc

// ---- ws layout (elements) ----
#define NH_ELEMS   (N_EXP * N_NODES * H_DIM)   // 2097152 bf16
// per-expert fragment-pool offsets (bf16 elems)
#define OFF_WN   0
#define OFF_WM   65536
#define OFF_WE   196608
#define OFF_WQ   229376
#define OFF_WO   425984
#define OFF_W1E  491520
#define OFF_W2E  622592
#define EXP_STRIDE 753664

// ---------------------------------------------------------------- helpers
__device__ __forceinline__ unsigned short f2bf(float x) {
  unsigned u = __float_as_uint(x);
  unsigned r = u + 0x7FFFu + ((u >> 16) & 1u);   // RNE
  return (unsigned short)(r >> 16);
}
__device__ __forceinline__ float bf2f(unsigned short h) {
  return __uint_as_float((unsigned)h << 16);
}
__device__ __forceinline__ float gelu_f(float x) {
  float u = 0.7978845608028654f * (x + 0.044715f * x * x * x);
  float ex = __expf(2.f * u);
  float th = 1.f - 2.f / (ex + 1.f);
  return 0.5f * x * (1.f + th);
}

// A-fragment read from row-major bf16 LDS tile with XOR swizzle.
// lane l: row = rt*16+(l&15), contract elems = kt*32 + (l>>4)*8 + j
__device__ __forceinline__ s8v lda(const char* base, int SBv, int rt, int kt, int l) {
  int r = rt * 16 + (l & 15);
  int byte = r * SBv + kt * 64 + ((l >> 4) << 4);
  return *(const s8v*)(base + (byte ^ ((r & 7) << 4)));
}
__device__ __forceinline__ void stb16(char* base, int SBv, int r, int c, float v) {
  *(unsigned short*)(base + ((r * SBv + c * 2) ^ ((r & 7) << 4))) = f2bf(v);
}

// K-loop: NA output tiles (ct = ctb0 + CSTR*m), NKT k-steps.
template<int NA, int NKT, int CSTR>
__device__ __forceinline__ void kloop(f4v acc[NA], const char* Ab, int ASB, int rt,
                                      const unsigned short* __restrict__ fb, int NCT,
                                      int ktb0, int ctb0, int l) {
  __builtin_amdgcn_s_setprio(1);
  for (int kt = 0; kt < NKT; ++kt) {
    s8v av = lda(Ab, ASB, rt, kt, l);
#pragma unroll
    for (int m = 0; m < NA; ++m) {
      s8v bv = *(const s8v*)(fb + (((size_t)(ktb0 + kt) * NCT + (ctb0 + CSTR * m)) * 64 + l) * 8);
      acc[m] = __builtin_amdgcn_mfma_f32_16x16x32_bf16(av, bv, acc[m], 0, 0, 0);
    }
  }
  __builtin_amdgcn_s_setprio(0);
}

// ---------------------------------------------------------------- gating
__global__ __launch_bounds__(64)
void gate_kernel(const float* __restrict__ nf, const float* __restrict__ wg,
                 int* __restrict__ sel_ne, float* __restrict__ sel_g) {
  int n = blockIdx.x, t = threadIdx.x;
  float p[8] = {0, 0, 0, 0, 0, 0, 0, 0};
  for (int j = 0; j < 4; ++j) {
    float x = nf[n * H_DIM + t + 64 * j];
#pragma unroll
    for (int e = 0; e < 8; ++e) p[e] += x * wg[(t + 64 * j) * 8 + e];
  }
#pragma unroll
  for (int e = 0; e < 8; ++e)
    for (int m = 32; m >= 1; m >>= 1) p[e] += __shfl_xor(p[e], m, 64);
  if (t == 0) {
    int i0 = 0; float v0 = p[0];
    for (int e = 1; e < 8; ++e) if (p[e] > v0) { v0 = p[e]; i0 = e; }
    int i1 = -1; float v1 = -3.4e38f;
    for (int e = 0; e < 8; ++e) if (e != i0 && p[e] > v1) { v1 = p[e]; i1 = e; }
    float g1 = __expf(v1 - v0);
    float inv = 1.f / (1.f + g1);
    sel_ne[n * 2 + 0] = (n << 3) | i0; sel_g[n * 2 + 0] = inv;
    sel_ne[n * 2 + 1] = (n << 3) | i1; sel_g[n * 2 + 1] = g1 * inv;
  }
}

__global__ __launch_bounds__(256)
void sort_kernel(const int* __restrict__ sel_ne, const float* __restrict__ sel_g,
                 int* __restrict__ work_ne, float* __restrict__ work_g) {
  __shared__ int cnt[8], off[8], cur[8];
  int t = threadIdx.x;
  if (t < 8) { cnt[t] = 0; cur[t] = 0; }
  __syncthreads();
  for (int i = t; i < N_NODES * NTOPK; i += 256) atomicAdd(&cnt[sel_ne[i] & 7], 1);
  __syncthreads();
  if (t == 0) { int s = 0; for (int e = 0; e < 8; ++e) { off[e] = s; s += cnt[e]; } }
  __syncthreads();
  for (int i = t; i < N_NODES * NTOPK; i += 256) {
    int pe = sel_ne[i]; int e = pe & 7;
    int pos = off[e] + atomicAdd(&cur[e], 1);
    work_ne[pos] = pe; work_g[pos] = sel_g[i];
  }
}

// per-expert LayerNorm of all nodes -> bf16
__global__ __launch_bounds__(256)
void nh_kernel(const float* __restrict__ nf, const float* __restrict__ lag,
               const float* __restrict__ lab, unsigned short* __restrict__ nh16) {
  __shared__ float red[8];
  int n = blockIdx.x, e = blockIdx.y, t = threadIdx.x;
  float x = nf[n * H_DIM + t];
  float sv = x, sq = x * x;
  for (int m = 32; m >= 1; m >>= 1) { sv += __shfl_xor(sv, m, 64); sq += __shfl_xor(sq, m, 64); }
  if ((t & 63) == 0) { red[t >> 6] = sv; red[4 + (t >> 6)] = sq; }
  __syncthreads();
  float sum = red[0] + red[1] + red[2] + red[3];
  float ssum = red[4] + red[5] + red[6] + red[7];
  float mu = sum * (1.f / 256.f);
  float var = ssum * (1.f / 256.f) - mu * mu;
  float rstd = rsqrtf(var + 1e-5f);
  nh16[((size_t)e * N_NODES + n) * H_DIM + t] =
      f2bf((x - mu) * rstd * lag[e * H_DIM + t] + lab[e * H_DIM + t]);
}

// ------------------------------------------------ weight -> bf16 fragments
__global__ __launch_bounds__(64)
void wconv(const float* __restrict__ W_node, const float* __restrict__ W_msg,
           const float* __restrict__ W_edge, const float* __restrict__ W_qkv,
           const float* __restrict__ W_out, const float* __restrict__ W1e,
           const float* __restrict__ W2e, unsigned short* __restrict__ fb) {
  int f = blockIdx.x, e = blockIdx.y, l = threadIdx.x;
  const float* src; int C, nct, fl; size_t off;
  if (f < 128)       { src = W_node + (size_t)e * 131072; C = 256; nct = 16; fl = f;        off = OFF_WN;  }
  else if (f < 384)  { src = W_msg  + (size_t)e * 131072; C = 256; nct = 16; fl = f - 128;  off = OFF_WM;  }
  else if (f < 448)  { src = W_edge + (size_t)e * 32768;  C = 256; nct = 16; fl = f - 384;  off = OFF_WE;  }
  else if (f < 832)  { src = W_qkv  + (size_t)e * 196608; C = 768; nct = 48; fl = f - 448;  off = OFF_WQ;  }
  else if (f < 960)  { src = W_out  + (size_t)e * 65536;  C = 256; nct = 16; fl = f - 832;  off = OFF_WO;  }
  else if (f < 1216) { src = W1e    + (size_t)e * 131072; C = 512; nct = 32; fl = f - 960;  off = OFF_W1E; }
  else               { src = W2e    + (size_t)e * 131072; C = 256; nct = 16; fl = f - 1216; off = OFF_W2E; }
  int kt = fl / nct, ct = fl - kt * nct;
  int k0 = kt * 32 + ((l >> 4) << 3), c = ct * 16 + (l & 15);
  unsigned pk[4];
#pragma unroll
  for (int jj = 0; jj < 4; ++jj) {
    unsigned short a = f2bf(src[(size_t)(k0 + 2 * jj) * C + c]);
    unsigned short b = f2bf(src[(size_t)(k0 + 2 * jj + 1) * C + c]);
    pk[jj] = (unsigned)a | ((unsigned)b << 16);
  }
  unsigned short* dst = fb + (size_t)e * EXP_STRIDE + off + ((size_t)fl * 64 + l) * 8;
  *(uint4*)dst = make_uint4(pk[0], pk[1], pk[2], pk[3]);
}

// ---------------------------------------------------------------- main
// 512 threads (8 waves), __launch_bounds__(512,4): 2 blocks/CU, 128 regs.
// Attention is now MFMA: wave w = head w; S^T = K@Q^T (4 mfma), softmax in
// D-layout regs, P->SQp (overwrites dead q, wave-private), ctx = P@V (4 mfma).
__global__ __launch_bounds__(512, 4)
void moe_main(const float* __restrict__ node_features,
              const float* __restrict__ edge_features,
              const float* __restrict__ edge_raw,
              const int* __restrict__ neighbor_list,
              const float* __restrict__ neighbor_mask,
              const float* __restrict__ W_node_f32, const float* __restrict__ bn,
              const float* __restrict__ be, const float* __restrict__ bm,
              const float* __restrict__ bq, const float* __restrict__ bo,
              const float* __restrict__ ln_ffn_g, const float* __restrict__ ln_ffn_b,
              const float* __restrict__ W1n, const float* __restrict__ b1n,
              const float* __restrict__ W2n, const float* __restrict__ b2n,
              const float* __restrict__ b1e, const float* __restrict__ b2e,
              const unsigned short* __restrict__ nh16,
              const unsigned short* __restrict__ fb,
              const int* __restrict__ work_ne, const float* __restrict__ work_g,
              float* __restrict__ out_node, float* __restrict__ out_edge) {
  extern __shared__ char sm[];
  char* SAp = sm;                      // 16K: sender -> msg -> ctx -> eh2
  char* SBp = sm + 16384;              // 16K: nodeh -> k
  char* SCp = sm + 32768;              // 16K: eh -> v
  float* EF = (float*)(sm + 16384);    // 32K f32 [32][256] (overlays SB+SC)
  char* SDp = sm + 49152;              // 8K : edge_raw bf16
  char* SQp = sm + 57344;              // 16K: q bf16 -> P bf16 -> h1e half
  float* MF = (float*)(sm + 73728);
  float* Mrecv = MF;            // 256
  float* Mrv2  = MF + 256;      // 512
  float* Mnp   = MF + 768;      // 256
  float* Mnh2  = MF + 1024;     // 256
  float* Mh1   = MF + 1280;     // 512
  float* Mred  = MF + 1792;     // 8
  float* Mmask = MF + 1800;     // 32
  float* Mmu   = MF + 1832;     // 32
  float* Mrstd = MF + 1864;     // 32

  const int t = threadIdx.x;
  const int pe = work_ne[blockIdx.x];
  const int n = pe >> 3, e = pe & 7;
  const float gate = work_g[blockIdx.x];

  const unsigned short* fbE   = fb + (size_t)e * EXP_STRIDE;
  const unsigned short* fbWn  = fbE + OFF_WN;
  const unsigned short* fbWm  = fbE + OFF_WM;
  const unsigned short* fbWe  = fbE + OFF_WE;
  const unsigned short* fbWq  = fbE + OFF_WQ;
  const unsigned short* fbWo  = fbE + OFF_WO;
  const unsigned short* fbW1e = fbE + OFF_W1E;
  const unsigned short* fbW2e = fbE + OFF_W2E;

  const float* Wn2  = W_node_f32 + (size_t)e * 131072;
  const float* bnE  = bn + e * H_DIM;
  const float* beE  = be + e * H_DIM;
  const float* bmE  = bm + e * H_DIM;
  const float* bqE  = bq + e * 3 * H_DIM;
  const float* boE  = bo + e * H_DIM;
  const float* lfg  = ln_ffn_g + e * H_DIM;
  const float* lfb  = ln_ffn_b + e * H_DIM;
  const float* w1n  = W1n + (size_t)e * H_DIM * FFH;
  const float* c1n  = b1n + e * FFH;
  const float* w2n  = W2n + (size_t)e * FFH * H_DIM;
  const float* c2n  = b2n + e * H_DIM;
  const float* c1e  = b1e + e * FFH;
  const float* c2e  = b2e + e * H_DIM;

  const int w = t >> 6, l = t & 63;
  const int rt = w & 1, ctb = w >> 1;   // ctb in 0..3

  // ---- stage ----
  const unsigned short* nh_e = nh16 + (size_t)e * N_NODES * H_DIM;
#pragma unroll
  for (int rr2 = 0; rr2 < 2; ++rr2) {
    int r = (t >> 5) + 16 * rr2, j = t & 31;
    int nbr = neighbor_list[n * K_NB + r];
    uint4 val = ((const uint4*)(nh_e + (size_t)nbr * H_DIM))[j];
    *(uint4*)(SAp + ((r * 512 + j * 16) ^ ((r & 7) << 4))) = val;
  }
  if (t < 256) Mrecv[t] = bf2f(nh_e[(size_t)n * H_DIM + t]);
#pragma unroll
  for (int rr2 = 0; rr2 < 2; ++rr2) {
    int r = (t >> 5) + 16 * rr2, c = (t & 31) * 4;
    float4 v = *(const float4*)(edge_raw + ((size_t)n * K_NB + r) * DE_DIM + c);
    unsigned p0 = (unsigned)f2bf(v.x) | ((unsigned)f2bf(v.y) << 16);
    unsigned p1 = (unsigned)f2bf(v.z) | ((unsigned)f2bf(v.w) << 16);
    *(uint2*)(SDp + ((r * 256 + c * 2) ^ ((r & 7) << 4))) = make_uint2(p0, p1);
  }
  if (t < 32) Mmask[t] = neighbor_mask[n * K_NB + t];
  if (t < 256) Mnp[t] = 0.f;
  __syncthreads();

  // ---- recv rank-1: Mrv[c] = sum_i recv[i]*Wn[256+i][c] + bn[c] (fp32) ----
  {
    int c = t & 255, part = t >> 8;   // part in 0..1
    float s = 0.f;
    for (int i = 0; i < 128; ++i)
      s += Mrecv[part * 128 + i] * Wn2[(size_t)(256 + part * 128 + i) * 256 + c];
    Mrv2[part * 256 + c] = s;
  }
  __syncthreads();
  if (t < 256) Mrecv[t] = Mrv2[t] + Mrv2[256 + t] + bnE[t];
  __syncthreads();

  // ---- phase 1: nodeh = gelu(sender@Wn1 + Mrv) -> SB ----
  {
    f4v acc[4];
#pragma unroll
    for (int m = 0; m < 4; ++m) {
      float iv = Mrecv[(ctb + 4 * m) * 16 + (l & 15)];
      acc[m][0] = iv; acc[m][1] = iv; acc[m][2] = iv; acc[m][3] = iv;
    }
    kloop<4, 8, 4>(acc, SAp, 512, rt, fbWn, 16, 0, ctb, l);
#pragma unroll
    for (int m = 0; m < 4; ++m) {
      int c = (ctb + 4 * m) * 16 + (l & 15);
#pragma unroll
      for (int ri = 0; ri < 4; ++ri)
        stb16(SBp, 512, rt * 16 + ((l >> 4) << 2) + ri, c, gelu_f(acc[m][ri]));
    }
  }
  // ---- phase 3: eh = gelu(edge_raw@We + be) -> SC ----
  {
    f4v acc[4];
#pragma unroll
    for (int m = 0; m < 4; ++m) {
      float iv = beE[(ctb + 4 * m) * 16 + (l & 15)];
      acc[m][0] = iv; acc[m][1] = iv; acc[m][2] = iv; acc[m][3] = iv;
    }
    kloop<4, 4, 4>(acc, SDp, 256, rt, fbWe, 16, 0, ctb, l);
#pragma unroll
    for (int m = 0; m < 4; ++m) {
      int c = (ctb + 4 * m) * 16 + (l & 15);
#pragma unroll
      for (int ri = 0; ri < 4; ++ri)
        stb16(SCp, 512, rt * 16 + ((l >> 4) << 2) + ri, c, gelu_f(acc[m][ri]));
    }
  }
  __syncthreads();

  // ---- phase 2+4: msg = gelu([eh|nodeh]@Wm + bm) -> SA ----
  {
    f4v acc[4];
#pragma unroll
    for (int m = 0; m < 4; ++m) {
      float iv = bmE[(ctb + 4 * m) * 16 + (l & 15)];
      acc[m][0] = iv; acc[m][1] = iv; acc[m][2] = iv; acc[m][3] = iv;
    }
    kloop<4, 8, 4>(acc, SCp, 512, rt, fbWm, 16, 0, ctb, l);   // eh    (rows 0..255)
    kloop<4, 8, 4>(acc, SBp, 512, rt, fbWm, 16, 8, ctb, l);   // nodeh (rows 256..511)
#pragma unroll
    for (int m = 0; m < 4; ++m) {
      int c = (ctb + 4 * m) * 16 + (l & 15);
#pragma unroll
      for (int ri = 0; ri < 4; ++ri)
        stb16(SAp, 512, rt * 16 + ((l >> 4) << 2) + ri, c, gelu_f(acc[m][ri]));
    }
  }
  __syncthreads();

  // ---- phase 5: qkv = msg@Wq + bq (two NA=6 passes); q->SQ, k->SB, v->SC ----
#pragma unroll
  for (int p = 0; p < 2; ++p) {
    f4v acc[6];
#pragma unroll
    for (int m = 0; m < 6; ++m) {
      float iv = bqE[(ctb + 24 * p + 4 * m) * 16 + (l & 15)];
      acc[m][0] = iv; acc[m][1] = iv; acc[m][2] = iv; acc[m][3] = iv;
    }
    kloop<6, 8, 4>(acc, SAp, 512, rt, fbWq, 48, 0, ctb + 24 * p, l);
#pragma unroll
    for (int m = 0; m < 6; ++m) {
      int cg = (ctb + 24 * p + 4 * m) * 16 + (l & 15);
      int rbase = rt * 16 + ((l >> 4) << 2);
      char* dst = (cg < 256) ? SQp : ((cg < 512) ? SBp : SCp);
      int cl = cg & 255;
#pragma unroll
      for (int ri = 0; ri < 4; ++ri) stb16(dst, 512, rbase + ri, cl, acc[m][ri]);
    }
  }
  __syncthreads();

  // ---- phase 6: MFMA attention; wave w = head h (all data wave-private) ----
  {
    const int h = w, l15 = l & 15, lg = l >> 4;
    // S^T = K @ Q^T : D[k-slot][q] per head, 2x2 16x16 tiles, k-dim = 32 dims
    f4v st[2][2];
    {
      s8v ka0 = lda(SBp, 512, 0, h, l);   // A: k rows 0..15, dims of head h
      s8v ka1 = lda(SBp, 512, 1, h, l);   // A: k rows 16..31
      s8v qb0 = lda(SQp, 512, 0, h, l);   // B = Q^T cols 0..15 (A-pattern read)
      s8v qb1 = lda(SQp, 512, 1, h, l);   // B = Q^T cols 16..31
      f4v z = {0.f, 0.f, 0.f, 0.f};
      st[0][0] = __builtin_amdgcn_mfma_f32_16x16x32_bf16(ka0, qb0, z, 0, 0, 0);
      st[0][1] = __builtin_amdgcn_mfma_f32_16x16x32_bf16(ka0, qb1, z, 0, 0, 0);
      st[1][0] = __builtin_amdgcn_mfma_f32_16x16x32_bf16(ka1, qb0, z, 0, 0, 0);
      st[1][1] = __builtin_amdgcn_mfma_f32_16x16x32_bf16(ka1, qb1, z, 0, 0, 0);
    }
    const float scale = 0.17677669529663687f;  // 1/sqrt(32)
    float madd[2][4];
#pragma unroll
    for (int rt2 = 0; rt2 < 2; ++rt2)
#pragma unroll
      for (int ri = 0; ri < 4; ++ri)
        madd[rt2][ri] = (Mmask[rt2 * 16 + 4 * lg + ri] > 0.f) ? 0.f : -1e9f;
    // per-q-column softmax (column = lane&15 within ct tile; rows spread over
    // ri in-lane and lane>>4 groups -> 8 in-lane vals + shfl_xor(16,32))
#pragma unroll
    for (int ct2 = 0; ct2 < 2; ++ct2) {
      float m_ = -3.4e38f;
#pragma unroll
      for (int rt2 = 0; rt2 < 2; ++rt2)
#pragma unroll
        for (int ri = 0; ri < 4; ++ri) {
          float sv = st[rt2][ct2][ri] * scale + madd[rt2][ri];
          st[rt2][ct2][ri] = sv;
          m_ = fmaxf(m_, sv);
        }
      m_ = fmaxf(m_, __shfl_xor(m_, 16, 64));
      m_ = fmaxf(m_, __shfl_xor(m_, 32, 64));
      float s_ = 0.f;
#pragma unroll
      for (int rt2 = 0; rt2 < 2; ++rt2)
#pragma unroll
        for (int ri = 0; ri < 4; ++ri) {
          float ev = __expf(st[rt2][ct2][ri] - m_);
          st[rt2][ct2][ri] = ev;
          s_ += ev;
        }
      s_ += __shfl_xor(s_, 16, 64);
      s_ += __shfl_xor(s_, 32, 64);
      float inv = 1.f / s_;
      // P[q][k] transposed store into SQp head-h bytes (q now dead, wave-private)
#pragma unroll
      for (int rt2 = 0; rt2 < 2; ++rt2)
#pragma unroll
        for (int ri = 0; ri < 4; ++ri)
          stb16(SQp, 512, ct2 * 16 + l15, h * 32 + rt2 * 16 + 4 * lg + ri,
                st[rt2][ct2][ri] * inv);
    }
    // ctx = P @ V : A = P rows (lda, kt=h), B = V natural [k][d] (8 u16/lane)
    s8v pa0 = lda(SQp, 512, 0, h, l);
    s8v pa1 = lda(SQp, 512, 1, h, l);
#pragma unroll
    for (int dt = 0; dt < 2; ++dt) {
      s8v vb;
#pragma unroll
      for (int j = 0; j < 8; ++j) {
        int rj = lg * 8 + j;
        vb[j] = *(const short*)(SCp +
                 ((rj * 512 + h * 64 + dt * 32 + l15 * 2) ^ ((rj & 7) << 4)));
      }
      f4v z = {0.f, 0.f, 0.f, 0.f};
      f4v c0 = __builtin_amdgcn_mfma_f32_16x16x32_bf16(pa0, vb, z, 0, 0, 0);
      f4v c1 = __builtin_amdgcn_mfma_f32_16x16x32_bf16(pa1, vb, z, 0, 0, 0);
#pragma unroll
      for (int ri = 0; ri < 4; ++ri) {
        stb16(SAp, 512, 4 * lg + ri,      h * 32 + dt * 16 + l15, c0[ri]);
        stb16(SAp, 512, 16 + 4 * lg + ri, h * 32 + dt * 16 + l15, c1[ri]);
      }
    }
  }
  __syncthreads();

  // ---- phase 7: edge_out = ctx@Wo + bo; np partials; ef -> EF (over k/v) ----
  {
    f4v acc[4];
#pragma unroll
    for (int m = 0; m < 4; ++m) {
      float iv = boE[(ctb + 4 * m) * 16 + (l & 15)];
      acc[m][0] = iv; acc[m][1] = iv; acc[m][2] = iv; acc[m][3] = iv;
    }
    kloop<4, 8, 4>(acc, SAp, 512, rt, fbWo, 16, 0, ctb, l);
#pragma unroll
    for (int m = 0; m < 4; ++m) {
      int c = (ctb + 4 * m) * 16 + (l & 15);
      int rbase = rt * 16 + ((l >> 4) << 2);
      float np = 0.f;
#pragma unroll
      for (int ri = 0; ri < 4; ++ri) {
        int r = rbase + ri;
        float eo = acc[m][ri];
        np += eo * Mmask[r];
        EF[r * 256 + c] = eo + edge_features[((size_t)n * K_NB + r) * H_DIM + c];
      }
      atomicAdd(&Mnp[c], np);
    }
  }
  __syncthreads();

  // ---- phase 9a: LN stats of ef; 8a: nfv + node-LN partials ----
  {
    int rr = t >> 4, j = t & 15;
    float s1 = 0.f, s2 = 0.f;
#pragma unroll
    for (int m2 = 0; m2 < 16; ++m2) {
      float xv = EF[rr * 256 + j + 16 * m2];
      s1 += xv; s2 += xv * xv;
    }
    s1 += __shfl_xor(s1, 8, 64); s2 += __shfl_xor(s2, 8, 64);
    s1 += __shfl_xor(s1, 4, 64); s2 += __shfl_xor(s2, 4, 64);
    s1 += __shfl_xor(s1, 2, 64); s2 += __shfl_xor(s2, 2, 64);
    s1 += __shfl_xor(s1, 1, 64); s2 += __shfl_xor(s2, 1, 64);
    if (j == 0) {
      float mu2 = s1 * (1.f / 256.f);
      float v2 = s2 * (1.f / 256.f) - mu2 * mu2;
      Mmu[rr] = mu2; Mrstd[rr] = rsqrtf(v2 + 1e-5f);
    }
  }
  float cntv = 1e-5f;
#pragma unroll
  for (int kk = 0; kk < 32; ++kk) cntv += Mmask[kk];
  float nfv = 0.f;
  if (t < 256) {
    nfv = Mnp[t] / cntv + node_features[n * H_DIM + t];
    float sv = nfv, sq = nfv * nfv;
    for (int m = 32; m >= 1; m >>= 1) { sv += __shfl_xor(sv, m, 64); sq += __shfl_xor(sq, m, 64); }
    if ((t & 63) == 0) { Mred[t >> 6] = sv; Mred[4 + (t >> 6)] = sq; }
  }
  __syncthreads();

  // ---- 9c: node LN -> Mnh2 ; 9d: eh2 = LN(ef) -> SA bf16 ----
  if (t < 256) {
    float sum = Mred[0] + Mred[1] + Mred[2] + Mred[3];
    float ssum = Mred[4] + Mred[5] + Mred[6] + Mred[7];
    float mu = sum * (1.f / 256.f);
    float var = ssum * (1.f / 256.f) - mu * mu;
    float rstd = rsqrtf(var + 1e-5f);
    Mnh2[t] = (nfv - mu) * rstd * lfg[t] + lfb[t];
  }
  {
    int col = t & 255, rgp = t >> 8;
    float g2 = lfg[col], b2v = lfb[col];
#pragma unroll
    for (int r8 = 0; r8 < 16; ++r8) {
      int row = rgp * 16 + r8;
      float xv = (EF[row * 256 + col] - Mmu[row]) * Mrstd[row] * g2 + b2v;
      stb16(SAp, 512, row, col, xv);
    }
  }
  __syncthreads();

  // ---- phases 10+11 (k-split halves, h1e half-buffer in SQ) + node FFN ----
  f4v acc2[4];
#pragma unroll
  for (int m = 0; m < 4; ++m) {
    float iv = c2e[(ctb + 4 * m) * 16 + (l & 15)];
    acc2[m][0] = iv; acc2[m][1] = iv; acc2[m][2] = iv; acc2[m][3] = iv;
  }
#pragma unroll
  for (int half = 0; half < 2; ++half) {
    // phase 10 half: h1e[:, half*256 : +256] = gelu(eh2 @ w1e_half + c1e_half)
    {
      f4v acc[4];
#pragma unroll
      for (int m = 0; m < 4; ++m) {
        float iv = c1e[(half * 16 + ctb + 4 * m) * 16 + (l & 15)];
        acc[m][0] = iv; acc[m][1] = iv; acc[m][2] = iv; acc[m][3] = iv;
      }
      kloop<4, 8, 4>(acc, SAp, 512, rt, fbW1e, 32, 0, half * 16 + ctb, l);
#pragma unroll
      for (int m = 0; m < 4; ++m) {
        int c = (ctb + 4 * m) * 16 + (l & 15);
#pragma unroll
        for (int ri = 0; ri < 4; ++ri)
          stb16(SQp, 512, rt * 16 + ((l >> 4) << 2) + ri, c, gelu_f(acc[m][ri]));
      }
    }
    if (half == 0) {     // 8b: node FFN hidden (fp32), all 512 threads
      float a = c1n[t];
      for (int i = 0; i < H_DIM; ++i) a += Mnh2[i] * w1n[(size_t)i * FFH + t];
      Mh1[t] = gelu_f(a);
    }
    __syncthreads();
    // phase 11 half: acc2 += h1e_half @ w2e[half*256 : , :]
    kloop<4, 8, 4>(acc2, SQp, 512, rt, fbW2e, 16, half * 8, ctb, l);
    __syncthreads();  // SQ reused next half
  }

  // ---- epilogues ----
#pragma unroll
  for (int m = 0; m < 4; ++m) {
    int c = (ctb + 4 * m) * 16 + (l & 15);
    int rbase = rt * 16 + ((l >> 4) << 2);
#pragma unroll
    for (int ri = 0; ri < 4; ++ri) {
      int r = rbase + ri;
      float o = acc2[m][ri] + EF[r * 256 + c];
      atomicAdd(&out_edge[((size_t)n * K_NB + r) * H_DIM + c], gate * o);
    }
  }
  if (t < 256) {   // 8c: node FFN out (fp32)
    float o = nfv + c2n[t];
    for (int i = 0; i < FFH; ++i) o += Mh1[i] * w2n[(size_t)i * H_DIM + t];
    atomicAdd(&out_node[n * H_DIM + t], gate * o);
  }
}

// ---------------------------------------------------------------- launch
extern "C" void kernel_launch(void* const* d_in, const int* in_sizes, int n_in,
                              void* d_out, int out_size, void* d_ws, size_t ws_size,
                              hipStream_t stream) {
  const float* node_features = (const float*)d_in[0];
  const float* edge_features = (const float*)d_in[1];
  const float* edge_raw      = (const float*)d_in[2];
  const int*   neighbor_list = (const int*)d_in[3];
  const float* neighbor_mask = (const float*)d_in[4];
  const float* w_gate        = (const float*)d_in[6];
  const float* W_edge = (const float*)d_in[7];
  const float* b_edge = (const float*)d_in[8];
  const float* W_node = (const float*)d_in[9];
  const float* b_node = (const float*)d_in[10];
  const float* W_msg  = (const float*)d_in[11];
  const float* b_msg  = (const float*)d_in[12];
  const float* W_qkv  = (const float*)d_in[13];
  const float* b_qkv  = (const float*)d_in[14];
  const float* W_out  = (const float*)d_in[15];
  const float* b_out  = (const float*)d_in[16];
  const float* ln_attn_g = (const float*)d_in[17];
  const float* ln_attn_b = (const float*)d_in[18];
  const float* ln_ffn_g  = (const float*)d_in[19];
  const float* ln_ffn_b  = (const float*)d_in[20];
  const float* W1n = (const float*)d_in[21];
  const float* b1n = (const float*)d_in[22];
  const float* W2n = (const float*)d_in[23];
  const float* b2n = (const float*)d_in[24];
  const float* W1e = (const float*)d_in[25];
  const float* b1e = (const float*)d_in[26];
  const float* W2e = (const float*)d_in[27];
  const float* b2e = (const float*)d_in[28];

  unsigned short* nh16 = (unsigned short*)d_ws;           // 2097152 bf16
  unsigned short* fbp  = nh16 + NH_ELEMS;                 // 6029312 bf16
  int*   sel_ne  = (int*)(fbp + (size_t)N_EXP * EXP_STRIDE);
  float* sel_g   = (float*)(sel_ne + 2048);
  int*   work_ne = (int*)(sel_g + 2048);
  float* work_g  = (float*)(work_ne + 2048);

  float* out_node = (float*)d_out;
  float* out_edge = out_node + N_NODES * H_DIM;

  hipMemsetAsync(d_out, 0, (size_t)out_size * sizeof(float), stream);

  gate_kernel<<<N_NODES, 64, 0, stream>>>(node_features, w_gate, sel_ne, sel_g);
  sort_kernel<<<1, 256, 0, stream>>>(sel_ne, sel_g, work_ne, work_g);
  nh_kernel<<<dim3(N_NODES, N_EXP), 256, 0, stream>>>(node_features, ln_attn_g, ln_attn_b, nh16);
  wconv<<<dim3(1472, N_EXP), 64, 0, stream>>>(W_node, W_msg, W_edge, W_qkv, W_out, W1e, W2e, fbp);

  size_t smem = 81408;   // 2 x 81408 = 162816 <= 163840 -> 2 blocks/CU
  hipFuncSetAttribute((const void*)moe_main, hipFuncAttributeMaxDynamicSharedMemorySize, (int)smem);
  moe_main<<<N_NODES * NTOPK, 512, smem, stream>>>(
      node_features, edge_features, edge_raw, neighbor_list, neighbor_mask,
      W_node, b_node, b_edge, b_msg, b_qkv, b_out,
      ln_ffn_g, ln_ffn_b, W1n, b1n, W2n, b2n, b1e, b2e,
      nh16, fbp, work_ne, work_g, out_node, out_edge);
}

// Round 8
// 632.768 us; speedup vs baseline: 2.9770x; 1.1110x over previous
//
#include <hip/hip_runtime.h>
#include <math.h>

#define N_NODES 1024
#define K_NB    32
#define H_DIM   256
#define DE_DIM  128
#define N_EXP   8
#define NTOPK   2
#define FFH     512

typedef __attribute__((ext_vector_type(8))) short s8v;   // 8 bf16 = 4 VGPR
typedef __attribute__((ext_vector_type(4))) float f4v;   // MFMA acc

// ---- ws layout (elements) ----
#define NH_ELEMS   (N_EXP * N_NODES * H_DIM)   // 2097152 bf16
// per-expert fragment-pool offsets (bf16 elems)
#define OFF_WN   0
#define OFF_WM   65536
#define OFF_WE   196608
#define OFF_WQ   229376
#define OFF_WO   425984
#define OFF_W1E  491520
#define OFF_W2E  622592
#define EXP_STRIDE 753664

// ---------------------------------------------------------------- helpers
__device__ __forceinline__ unsigned short f2bf(float x) {
  unsigned u = __float_as_uint(x);
  unsigned r = u + 0x7FFFu + ((u >> 16) & 1u);   // RNE
  return (unsigned short)(r >> 16);
}
__device__ __forceinline__ float bf2f(unsigned short h) {
  return __uint_as_float((unsigned)h << 16);
}
__device__ __forceinline__ float gelu_f(float x) {
  float u = 0.7978845608028654f * (x + 0.044715f * x * x * x);
  float ex = __expf(2.f * u);
  float th = 1.f - 2.f / (ex + 1.f);
  return 0.5f * x * (1.f + th);
}

// A-fragment read from row-major bf16 LDS tile with XOR swizzle.
// lane l: row = rt*16+(l&15), contract elems = kt*32 + (l>>4)*8 + j
__device__ __forceinline__ s8v lda(const char* base, int SBv, int rt, int kt, int l) {
  int r = rt * 16 + (l & 15);
  int byte = r * SBv + kt * 64 + ((l >> 4) << 4);
  return *(const s8v*)(base + (byte ^ ((r & 7) << 4)));
}
__device__ __forceinline__ void stb16(char* base, int SBv, int r, int c, float v) {
  *(unsigned short*)(base + ((r * SBv + c * 2) ^ ((r & 7) << 4))) = f2bf(v);
}

// K-loop, BOTH row-tiles per wave: each B-fragment (global/L2, ~250cy) is
// loaded ONCE and feeds 2 MFMAs (rt=0,1) -> halves the L2 B-frag stream
// that R7's counters implicated as the dominant stall (60% idle cycles).
// acc[rt][m], col-tile ct = ctb0 + CSTR*m.
template<int NA, int NKT, int CSTR>
__device__ __forceinline__ void kloop2(f4v acc[2][NA], const char* Ab, int ASB,
                                       const unsigned short* __restrict__ fb, int NCT,
                                       int ktb0, int ctb0, int l) {
  __builtin_amdgcn_s_setprio(1);
  for (int kt = 0; kt < NKT; ++kt) {
    s8v a0 = lda(Ab, ASB, 0, kt, l);
    s8v a1 = lda(Ab, ASB, 1, kt, l);
#pragma unroll
    for (int m = 0; m < NA; ++m) {
      s8v bv = *(const s8v*)(fb + (((size_t)(ktb0 + kt) * NCT + (ctb0 + CSTR * m)) * 64 + l) * 8);
      acc[0][m] = __builtin_amdgcn_mfma_f32_16x16x32_bf16(a0, bv, acc[0][m], 0, 0, 0);
      acc[1][m] = __builtin_amdgcn_mfma_f32_16x16x32_bf16(a1, bv, acc[1][m], 0, 0, 0);
    }
  }
  __builtin_amdgcn_s_setprio(0);
}

// ---------------------------------------------------------------- gating
__global__ __launch_bounds__(64)
void gate_kernel(const float* __restrict__ nf, const float* __restrict__ wg,
                 int* __restrict__ sel_ne, float* __restrict__ sel_g) {
  int n = blockIdx.x, t = threadIdx.x;
  float p[8] = {0, 0, 0, 0, 0, 0, 0, 0};
  for (int j = 0; j < 4; ++j) {
    float x = nf[n * H_DIM + t + 64 * j];
#pragma unroll
    for (int e = 0; e < 8; ++e) p[e] += x * wg[(t + 64 * j) * 8 + e];
  }
#pragma unroll
  for (int e = 0; e < 8; ++e)
    for (int m = 32; m >= 1; m >>= 1) p[e] += __shfl_xor(p[e], m, 64);
  if (t == 0) {
    int i0 = 0; float v0 = p[0];
    for (int e = 1; e < 8; ++e) if (p[e] > v0) { v0 = p[e]; i0 = e; }
    int i1 = -1; float v1 = -3.4e38f;
    for (int e = 0; e < 8; ++e) if (e != i0 && p[e] > v1) { v1 = p[e]; i1 = e; }
    float g1 = __expf(v1 - v0);
    float inv = 1.f / (1.f + g1);
    sel_ne[n * 2 + 0] = (n << 3) | i0; sel_g[n * 2 + 0] = inv;
    sel_ne[n * 2 + 1] = (n << 3) | i1; sel_g[n * 2 + 1] = g1 * inv;
  }
}

__global__ __launch_bounds__(256)
void sort_kernel(const int* __restrict__ sel_ne, const float* __restrict__ sel_g,
                 int* __restrict__ work_ne, float* __restrict__ work_g) {
  __shared__ int cnt[8], off[8], cur[8];
  int t = threadIdx.x;
  if (t < 8) { cnt[t] = 0; cur[t] = 0; }
  __syncthreads();
  for (int i = t; i < N_NODES * NTOPK; i += 256) atomicAdd(&cnt[sel_ne[i] & 7], 1);
  __syncthreads();
  if (t == 0) { int s = 0; for (int e = 0; e < 8; ++e) { off[e] = s; s += cnt[e]; } }
  __syncthreads();
  for (int i = t; i < N_NODES * NTOPK; i += 256) {
    int pe = sel_ne[i]; int e = pe & 7;
    int pos = off[e] + atomicAdd(&cur[e], 1);
    work_ne[pos] = pe; work_g[pos] = sel_g[i];
  }
}

// per-expert LayerNorm of all nodes -> bf16
__global__ __launch_bounds__(256)
void nh_kernel(const float* __restrict__ nf, const float* __restrict__ lag,
               const float* __restrict__ lab, unsigned short* __restrict__ nh16) {
  __shared__ float red[8];
  int n = blockIdx.x, e = blockIdx.y, t = threadIdx.x;
  float x = nf[n * H_DIM + t];
  float sv = x, sq = x * x;
  for (int m = 32; m >= 1; m >>= 1) { sv += __shfl_xor(sv, m, 64); sq += __shfl_xor(sq, m, 64); }
  if ((t & 63) == 0) { red[t >> 6] = sv; red[4 + (t >> 6)] = sq; }
  __syncthreads();
  float sum = red[0] + red[1] + red[2] + red[3];
  float ssum = red[4] + red[5] + red[6] + red[7];
  float mu = sum * (1.f / 256.f);
  float var = ssum * (1.f / 256.f) - mu * mu;
  float rstd = rsqrtf(var + 1e-5f);
  nh16[((size_t)e * N_NODES + n) * H_DIM + t] =
      f2bf((x - mu) * rstd * lag[e * H_DIM + t] + lab[e * H_DIM + t]);
}

// ------------------------------------------------ weight -> bf16 fragments
__global__ __launch_bounds__(64)
void wconv(const float* __restrict__ W_node, const float* __restrict__ W_msg,
           const float* __restrict__ W_edge, const float* __restrict__ W_qkv,
           const float* __restrict__ W_out, const float* __restrict__ W1e,
           const float* __restrict__ W2e, unsigned short* __restrict__ fb) {
  int f = blockIdx.x, e = blockIdx.y, l = threadIdx.x;
  const float* src; int C, nct, fl; size_t off;
  if (f < 128)       { src = W_node + (size_t)e * 131072; C = 256; nct = 16; fl = f;        off = OFF_WN;  }
  else if (f < 384)  { src = W_msg  + (size_t)e * 131072; C = 256; nct = 16; fl = f - 128;  off = OFF_WM;  }
  else if (f < 448)  { src = W_edge + (size_t)e * 32768;  C = 256; nct = 16; fl = f - 384;  off = OFF_WE;  }
  else if (f < 832)  { src = W_qkv  + (size_t)e * 196608; C = 768; nct = 48; fl = f - 448;  off = OFF_WQ;  }
  else if (f < 960)  { src = W_out  + (size_t)e * 65536;  C = 256; nct = 16; fl = f - 832;  off = OFF_WO;  }
  else if (f < 1216) { src = W1e    + (size_t)e * 131072; C = 512; nct = 32; fl = f - 960;  off = OFF_W1E; }
  else               { src = W2e    + (size_t)e * 131072; C = 256; nct = 16; fl = f - 1216; off = OFF_W2E; }
  int kt = fl / nct, ct = fl - kt * nct;
  int k0 = kt * 32 + ((l >> 4) << 3), c = ct * 16 + (l & 15);
  unsigned pk[4];
#pragma unroll
  for (int jj = 0; jj < 4; ++jj) {
    unsigned short a = f2bf(src[(size_t)(k0 + 2 * jj) * C + c]);
    unsigned short b = f2bf(src[(size_t)(k0 + 2 * jj + 1) * C + c]);
    pk[jj] = (unsigned)a | ((unsigned)b << 16);
  }
  unsigned short* dst = fb + (size_t)e * EXP_STRIDE + off + ((size_t)fl * 64 + l) * 8;
  *(uint4*)dst = make_uint4(pk[0], pk[1], pk[2], pk[3]);
}

// ---------------------------------------------------------------- main
// 512 threads (8 waves), 2 blocks/CU, 128 regs. Wave w = col-group ctb (0..7);
// each wave computes BOTH 16-row tiles (kloop2) so B-frags are loaded once.
__global__ __launch_bounds__(512, 4)
void moe_main(const float* __restrict__ node_features,
              const float* __restrict__ edge_features,
              const float* __restrict__ edge_raw,
              const int* __restrict__ neighbor_list,
              const float* __restrict__ neighbor_mask,
              const float* __restrict__ W_node_f32, const float* __restrict__ bn,
              const float* __restrict__ be, const float* __restrict__ bm,
              const float* __restrict__ bq, const float* __restrict__ bo,
              const float* __restrict__ ln_ffn_g, const float* __restrict__ ln_ffn_b,
              const float* __restrict__ W1n, const float* __restrict__ b1n,
              const float* __restrict__ W2n, const float* __restrict__ b2n,
              const float* __restrict__ b1e, const float* __restrict__ b2e,
              const unsigned short* __restrict__ nh16,
              const unsigned short* __restrict__ fb,
              const int* __restrict__ work_ne, const float* __restrict__ work_g,
              float* __restrict__ out_node, float* __restrict__ out_edge) {
  extern __shared__ char sm[];
  char* SAp = sm;                      // 16K: sender -> msg -> ctx -> eh2
  char* SBp = sm + 16384;              // 16K: nodeh -> k
  char* SCp = sm + 32768;              // 16K: eh -> v
  float* EF = (float*)(sm + 16384);    // 32K f32 [32][256] (overlays SB+SC)
  char* SDp = sm + 49152;              // 8K : edge_raw bf16
  char* SQp = sm + 57344;              // 16K: q bf16 -> P bf16 -> h1e half
  float* MF = (float*)(sm + 73728);
  float* Mrecv = MF;            // 256
  float* Mrv2  = MF + 256;      // 512
  float* Mnp   = MF + 768;      // 256
  float* Mnh2  = MF + 1024;     // 256
  float* Mh1   = MF + 1280;     // 512
  float* Mred  = MF + 1792;     // 8
  float* Mmask = MF + 1800;     // 32
  float* Mmu   = MF + 1832;     // 32
  float* Mrstd = MF + 1864;     // 32

  const int t = threadIdx.x;
  const int pe = work_ne[blockIdx.x];
  const int n = pe >> 3, e = pe & 7;
  const float gate = work_g[blockIdx.x];

  const unsigned short* fbE   = fb + (size_t)e * EXP_STRIDE;
  const unsigned short* fbWn  = fbE + OFF_WN;
  const unsigned short* fbWm  = fbE + OFF_WM;
  const unsigned short* fbWe  = fbE + OFF_WE;
  const unsigned short* fbWq  = fbE + OFF_WQ;
  const unsigned short* fbWo  = fbE + OFF_WO;
  const unsigned short* fbW1e = fbE + OFF_W1E;
  const unsigned short* fbW2e = fbE + OFF_W2E;

  const float* Wn2  = W_node_f32 + (size_t)e * 131072;
  const float* bnE  = bn + e * H_DIM;
  const float* beE  = be + e * H_DIM;
  const float* bmE  = bm + e * H_DIM;
  const float* bqE  = bq + e * 3 * H_DIM;
  const float* boE  = bo + e * H_DIM;
  const float* lfg  = ln_ffn_g + e * H_DIM;
  const float* lfb  = ln_ffn_b + e * H_DIM;
  const float* w1n  = W1n + (size_t)e * H_DIM * FFH;
  const float* c1n  = b1n + e * FFH;
  const float* w2n  = W2n + (size_t)e * FFH * H_DIM;
  const float* c2n  = b2n + e * H_DIM;
  const float* c1e  = b1e + e * FFH;
  const float* c2e  = b2e + e * H_DIM;

  const int w = t >> 6, l = t & 63;
  const int ctb = w;                 // col-group 0..7
  const int l15 = l & 15, lg = l >> 4;
  const int rbase0 = (lg << 2);      // rows 4*lg .. +4 (rt adds 16)

  // ---- stage ----
  const unsigned short* nh_e = nh16 + (size_t)e * N_NODES * H_DIM;
#pragma unroll
  for (int rr2 = 0; rr2 < 2; ++rr2) {
    int r = (t >> 5) + 16 * rr2, j = t & 31;
    int nbr = neighbor_list[n * K_NB + r];
    uint4 val = ((const uint4*)(nh_e + (size_t)nbr * H_DIM))[j];
    *(uint4*)(SAp + ((r * 512 + j * 16) ^ ((r & 7) << 4))) = val;
  }
  if (t < 256) Mrecv[t] = bf2f(nh_e[(size_t)n * H_DIM + t]);
#pragma unroll
  for (int rr2 = 0; rr2 < 2; ++rr2) {
    int r = (t >> 5) + 16 * rr2, c = (t & 31) * 4;
    float4 v = *(const float4*)(edge_raw + ((size_t)n * K_NB + r) * DE_DIM + c);
    unsigned p0 = (unsigned)f2bf(v.x) | ((unsigned)f2bf(v.y) << 16);
    unsigned p1 = (unsigned)f2bf(v.z) | ((unsigned)f2bf(v.w) << 16);
    *(uint2*)(SDp + ((r * 256 + c * 2) ^ ((r & 7) << 4))) = make_uint2(p0, p1);
  }
  if (t < 32) Mmask[t] = neighbor_mask[n * K_NB + t];
  if (t < 256) Mnp[t] = 0.f;
  __syncthreads();

  // ---- recv rank-1: Mrv[c] = sum_i recv[i]*Wn[256+i][c] + bn[c] (fp32) ----
  {
    int c = t & 255, part = t >> 8;   // part in 0..1
    float s0 = 0.f, s1 = 0.f;
    for (int i = 0; i < 64; ++i) {    // 2-way split chain for ILP
      s0 += Mrecv[part * 128 + i] * Wn2[(size_t)(256 + part * 128 + i) * 256 + c];
      s1 += Mrecv[part * 128 + 64 + i] * Wn2[(size_t)(256 + part * 128 + 64 + i) * 256 + c];
    }
    Mrv2[part * 256 + c] = s0 + s1;
  }
  __syncthreads();
  if (t < 256) Mrecv[t] = Mrv2[t] + Mrv2[256 + t] + bnE[t];
  __syncthreads();

  // ---- phase 1: nodeh = gelu(sender@Wn1 + Mrv) -> SB ----
  {
    f4v acc[2][2];
#pragma unroll
    for (int m = 0; m < 2; ++m) {
      float iv = Mrecv[(ctb + 8 * m) * 16 + l15];
#pragma unroll
      for (int rt2 = 0; rt2 < 2; ++rt2) {
        acc[rt2][m][0] = iv; acc[rt2][m][1] = iv; acc[rt2][m][2] = iv; acc[rt2][m][3] = iv;
      }
    }
    kloop2<2, 8, 8>(acc, SAp, 512, fbWn, 16, 0, ctb, l);
#pragma unroll
    for (int m = 0; m < 2; ++m) {
      int c = (ctb + 8 * m) * 16 + l15;
#pragma unroll
      for (int rt2 = 0; rt2 < 2; ++rt2)
#pragma unroll
        for (int ri = 0; ri < 4; ++ri)
          stb16(SBp, 512, rt2 * 16 + rbase0 + ri, c, gelu_f(acc[rt2][m][ri]));
    }
  }
  // ---- phase 3: eh = gelu(edge_raw@We + be) -> SC ----
  {
    f4v acc[2][2];
#pragma unroll
    for (int m = 0; m < 2; ++m) {
      float iv = beE[(ctb + 8 * m) * 16 + l15];
#pragma unroll
      for (int rt2 = 0; rt2 < 2; ++rt2) {
        acc[rt2][m][0] = iv; acc[rt2][m][1] = iv; acc[rt2][m][2] = iv; acc[rt2][m][3] = iv;
      }
    }
    kloop2<2, 4, 8>(acc, SDp, 256, fbWe, 16, 0, ctb, l);
#pragma unroll
    for (int m = 0; m < 2; ++m) {
      int c = (ctb + 8 * m) * 16 + l15;
#pragma unroll
      for (int rt2 = 0; rt2 < 2; ++rt2)
#pragma unroll
        for (int ri = 0; ri < 4; ++ri)
          stb16(SCp, 512, rt2 * 16 + rbase0 + ri, c, gelu_f(acc[rt2][m][ri]));
    }
  }
  __syncthreads();

  // ---- phase 2+4: msg = gelu([eh|nodeh]@Wm + bm) -> SA ----
  {
    f4v acc[2][2];
#pragma unroll
    for (int m = 0; m < 2; ++m) {
      float iv = bmE[(ctb + 8 * m) * 16 + l15];
#pragma unroll
      for (int rt2 = 0; rt2 < 2; ++rt2) {
        acc[rt2][m][0] = iv; acc[rt2][m][1] = iv; acc[rt2][m][2] = iv; acc[rt2][m][3] = iv;
      }
    }
    kloop2<2, 8, 8>(acc, SCp, 512, fbWm, 16, 0, ctb, l);   // eh    (rows 0..255)
    kloop2<2, 8, 8>(acc, SBp, 512, fbWm, 16, 8, ctb, l);   // nodeh (rows 256..511)
#pragma unroll
    for (int m = 0; m < 2; ++m) {
      int c = (ctb + 8 * m) * 16 + l15;
#pragma unroll
      for (int rt2 = 0; rt2 < 2; ++rt2)
#pragma unroll
        for (int ri = 0; ri < 4; ++ri)
          stb16(SAp, 512, rt2 * 16 + rbase0 + ri, c, gelu_f(acc[rt2][m][ri]));
    }
  }
  __syncthreads();

  // ---- phase 5: qkv = msg@Wq + bq (3 passes of 16 tiles); q->SQ, k->SB, v->SC ----
#pragma unroll
  for (int p = 0; p < 3; ++p) {
    f4v acc[2][2];
#pragma unroll
    for (int m = 0; m < 2; ++m) {
      float iv = bqE[(p * 16 + ctb + 8 * m) * 16 + l15];
#pragma unroll
      for (int rt2 = 0; rt2 < 2; ++rt2) {
        acc[rt2][m][0] = iv; acc[rt2][m][1] = iv; acc[rt2][m][2] = iv; acc[rt2][m][3] = iv;
      }
    }
    kloop2<2, 8, 8>(acc, SAp, 512, fbWq, 48, 0, p * 16 + ctb, l);
#pragma unroll
    for (int m = 0; m < 2; ++m) {
      int cg = (p * 16 + ctb + 8 * m) * 16 + l15;
      char* dst = (cg < 256) ? SQp : ((cg < 512) ? SBp : SCp);
      int cl = cg & 255;
#pragma unroll
      for (int rt2 = 0; rt2 < 2; ++rt2)
#pragma unroll
        for (int ri = 0; ri < 4; ++ri)
          stb16(dst, 512, rt2 * 16 + rbase0 + ri, cl, acc[rt2][m][ri]);
    }
  }
  __syncthreads();

  // ---- phase 6: MFMA attention; wave w = head h (all data wave-private) ----
  {
    const int h = w;
    // S^T = K @ Q^T : D[k-slot][q] per head, 2x2 16x16 tiles, contract = 32 dims
    f4v st[2][2];
    {
      s8v ka0 = lda(SBp, 512, 0, h, l);   // A: k rows 0..15, dims of head h
      s8v ka1 = lda(SBp, 512, 1, h, l);   // A: k rows 16..31
      s8v qb0 = lda(SQp, 512, 0, h, l);   // B = Q^T cols 0..15 (A-pattern read)
      s8v qb1 = lda(SQp, 512, 1, h, l);   // B = Q^T cols 16..31
      f4v z = {0.f, 0.f, 0.f, 0.f};
      st[0][0] = __builtin_amdgcn_mfma_f32_16x16x32_bf16(ka0, qb0, z, 0, 0, 0);
      st[0][1] = __builtin_amdgcn_mfma_f32_16x16x32_bf16(ka0, qb1, z, 0, 0, 0);
      st[1][0] = __builtin_amdgcn_mfma_f32_16x16x32_bf16(ka1, qb0, z, 0, 0, 0);
      st[1][1] = __builtin_amdgcn_mfma_f32_16x16x32_bf16(ka1, qb1, z, 0, 0, 0);
    }
    const float scale = 0.17677669529663687f;  // 1/sqrt(32)
    float madd[2][4];
#pragma unroll
    for (int rt2 = 0; rt2 < 2; ++rt2)
#pragma unroll
      for (int ri = 0; ri < 4; ++ri)
        madd[rt2][ri] = (Mmask[rt2 * 16 + 4 * lg + ri] > 0.f) ? 0.f : -1e9f;
#pragma unroll
    for (int ct2 = 0; ct2 < 2; ++ct2) {
      float m_ = -3.4e38f;
#pragma unroll
      for (int rt2 = 0; rt2 < 2; ++rt2)
#pragma unroll
        for (int ri = 0; ri < 4; ++ri) {
          float sv = st[rt2][ct2][ri] * scale + madd[rt2][ri];
          st[rt2][ct2][ri] = sv;
          m_ = fmaxf(m_, sv);
        }
      m_ = fmaxf(m_, __shfl_xor(m_, 16, 64));
      m_ = fmaxf(m_, __shfl_xor(m_, 32, 64));
      float s_ = 0.f;
#pragma unroll
      for (int rt2 = 0; rt2 < 2; ++rt2)
#pragma unroll
        for (int ri = 0; ri < 4; ++ri) {
          float ev = __expf(st[rt2][ct2][ri] - m_);
          st[rt2][ct2][ri] = ev;
          s_ += ev;
        }
      s_ += __shfl_xor(s_, 16, 64);
      s_ += __shfl_xor(s_, 32, 64);
      float inv = 1.f / s_;
      // P[q][k] transposed store into SQp head-h bytes (q dead, wave-private)
#pragma unroll
      for (int rt2 = 0; rt2 < 2; ++rt2)
#pragma unroll
        for (int ri = 0; ri < 4; ++ri)
          stb16(SQp, 512, ct2 * 16 + l15, h * 32 + rt2 * 16 + 4 * lg + ri,
                st[rt2][ct2][ri] * inv);
    }
    // ctx = P @ V : A = P rows (lda, kt=h), B = V natural [k][d] (8 u16/lane)
    s8v pa0 = lda(SQp, 512, 0, h, l);
    s8v pa1 = lda(SQp, 512, 1, h, l);
#pragma unroll
    for (int dt = 0; dt < 2; ++dt) {
      s8v vb;
#pragma unroll
      for (int j = 0; j < 8; ++j) {
        int rj = lg * 8 + j;
        vb[j] = *(const short*)(SCp +
                 ((rj * 512 + h * 64 + dt * 32 + l15 * 2) ^ ((rj & 7) << 4)));
      }
      f4v z = {0.f, 0.f, 0.f, 0.f};
      f4v c0 = __builtin_amdgcn_mfma_f32_16x16x32_bf16(pa0, vb, z, 0, 0, 0);
      f4v c1 = __builtin_amdgcn_mfma_f32_16x16x32_bf16(pa1, vb, z, 0, 0, 0);
#pragma unroll
      for (int ri = 0; ri < 4; ++ri) {
        stb16(SAp, 512, 4 * lg + ri,      h * 32 + dt * 16 + l15, c0[ri]);
        stb16(SAp, 512, 16 + 4 * lg + ri, h * 32 + dt * 16 + l15, c1[ri]);
      }
    }
  }
  __syncthreads();

  // ---- phase 7: edge_out = ctx@Wo + bo; np partials; ef -> EF (over k/v) ----
  {
    f4v acc[2][2];
#pragma unroll
    for (int m = 0; m < 2; ++m) {
      float iv = boE[(ctb + 8 * m) * 16 + l15];
#pragma unroll
      for (int rt2 = 0; rt2 < 2; ++rt2) {
        acc[rt2][m][0] = iv; acc[rt2][m][1] = iv; acc[rt2][m][2] = iv; acc[rt2][m][3] = iv;
      }
    }
    kloop2<2, 8, 8>(acc, SAp, 512, fbWo, 16, 0, ctb, l);
#pragma unroll
    for (int m = 0; m < 2; ++m) {
      int c = (ctb + 8 * m) * 16 + l15;
      float np = 0.f;
#pragma unroll
      for (int rt2 = 0; rt2 < 2; ++rt2)
#pragma unroll
        for (int ri = 0; ri < 4; ++ri) {
          int r = rt2 * 16 + rbase0 + ri;
          float eo = acc[rt2][m][ri];
          np += eo * Mmask[r];
          EF[r * 256 + c] = eo + edge_features[((size_t)n * K_NB + r) * H_DIM + c];
        }
      atomicAdd(&Mnp[c], np);
    }
  }
  __syncthreads();

  // ---- phase 9a: LN stats of ef; 8a: nfv + node-LN partials ----
  {
    int rr = t >> 4, j = t & 15;
    float s1 = 0.f, s2 = 0.f;
#pragma unroll
    for (int m2 = 0; m2 < 16; ++m2) {
      float xv = EF[rr * 256 + j + 16 * m2];
      s1 += xv; s2 += xv * xv;
    }
    s1 += __shfl_xor(s1, 8, 64); s2 += __shfl_xor(s2, 8, 64);
    s1 += __shfl_xor(s1, 4, 64); s2 += __shfl_xor(s2, 4, 64);
    s1 += __shfl_xor(s1, 2, 64); s2 += __shfl_xor(s2, 2, 64);
    s1 += __shfl_xor(s1, 1, 64); s2 += __shfl_xor(s2, 1, 64);
    if (j == 0) {
      float mu2 = s1 * (1.f / 256.f);
      float v2 = s2 * (1.f / 256.f) - mu2 * mu2;
      Mmu[rr] = mu2; Mrstd[rr] = rsqrtf(v2 + 1e-5f);
    }
  }
  float cntv = 1e-5f;
#pragma unroll
  for (int kk = 0; kk < 32; ++kk) cntv += Mmask[kk];
  float nfv = 0.f;
  if (t < 256) {
    nfv = Mnp[t] / cntv + node_features[n * H_DIM + t];
    float sv = nfv, sq = nfv * nfv;
    for (int m = 32; m >= 1; m >>= 1) { sv += __shfl_xor(sv, m, 64); sq += __shfl_xor(sq, m, 64); }
    if ((t & 63) == 0) { Mred[t >> 6] = sv; Mred[4 + (t >> 6)] = sq; }
  }
  __syncthreads();

  // ---- 9c: node LN -> Mnh2 ; 9d: eh2 = LN(ef) -> SA bf16 ----
  if (t < 256) {
    float sum = Mred[0] + Mred[1] + Mred[2] + Mred[3];
    float ssum = Mred[4] + Mred[5] + Mred[6] + Mred[7];
    float mu = sum * (1.f / 256.f);
    float var = ssum * (1.f / 256.f) - mu * mu;
    float rstd = rsqrtf(var + 1e-5f);
    Mnh2[t] = (nfv - mu) * rstd * lfg[t] + lfb[t];
  }
  {
    int col = t & 255, rgp = t >> 8;
    float g2 = lfg[col], b2v = lfb[col];
#pragma unroll
    for (int r8 = 0; r8 < 16; ++r8) {
      int row = rgp * 16 + r8;
      float xv = (EF[row * 256 + col] - Mmu[row]) * Mrstd[row] * g2 + b2v;
      stb16(SAp, 512, row, col, xv);
    }
  }
  __syncthreads();

  // ---- phases 10+11 (k-split halves, h1e half-buffer in SQ) + node FFN ----
  f4v acc2[2][2];
#pragma unroll
  for (int m = 0; m < 2; ++m) {
    float iv = c2e[(ctb + 8 * m) * 16 + l15];
#pragma unroll
    for (int rt2 = 0; rt2 < 2; ++rt2) {
      acc2[rt2][m][0] = iv; acc2[rt2][m][1] = iv; acc2[rt2][m][2] = iv; acc2[rt2][m][3] = iv;
    }
  }
#pragma unroll
  for (int half = 0; half < 2; ++half) {
    // phase 10 half: h1e[:, half*256 : +256] = gelu(eh2 @ w1e_half + c1e_half)
    {
      f4v acc[2][2];
#pragma unroll
      for (int m = 0; m < 2; ++m) {
        float iv = c1e[(half * 16 + ctb + 8 * m) * 16 + l15];
#pragma unroll
        for (int rt2 = 0; rt2 < 2; ++rt2) {
          acc[rt2][m][0] = iv; acc[rt2][m][1] = iv; acc[rt2][m][2] = iv; acc[rt2][m][3] = iv;
        }
      }
      kloop2<2, 8, 8>(acc, SAp, 512, fbW1e, 32, 0, half * 16 + ctb, l);
#pragma unroll
      for (int m = 0; m < 2; ++m) {
        int c = (ctb + 8 * m) * 16 + l15;
#pragma unroll
        for (int rt2 = 0; rt2 < 2; ++rt2)
#pragma unroll
          for (int ri = 0; ri < 4; ++ri)
            stb16(SQp, 512, rt2 * 16 + rbase0 + ri, c, gelu_f(acc[rt2][m][ri]));
      }
    }
    if (half == 0) {     // 8b: node FFN hidden (fp32), 2-way chain split
      float a0 = 0.f, a1 = 0.f;
      for (int i = 0; i < 128; ++i) {
        a0 += Mnh2[i] * w1n[(size_t)i * FFH + t];
        a1 += Mnh2[128 + i] * w1n[(size_t)(128 + i) * FFH + t];
      }
      Mh1[t] = gelu_f(a0 + a1 + c1n[t]);
    }
    __syncthreads();
    // phase 11 half: acc2 += h1e_half @ w2e[half*256 : , :]
    kloop2<2, 8, 8>(acc2, SQp, 512, fbW2e, 16, half * 8, ctb, l);
    __syncthreads();  // SQ reused next half
  }

  // ---- epilogues ----
#pragma unroll
  for (int m = 0; m < 2; ++m) {
    int c = (ctb + 8 * m) * 16 + l15;
#pragma unroll
    for (int rt2 = 0; rt2 < 2; ++rt2)
#pragma unroll
      for (int ri = 0; ri < 4; ++ri) {
        int r = rt2 * 16 + rbase0 + ri;
        float o = acc2[rt2][m][ri] + EF[r * 256 + c];
        atomicAdd(&out_edge[((size_t)n * K_NB + r) * H_DIM + c], gate * o);
      }
  }
  if (t < 256) {   // 8c: node FFN out (fp32), 4-way chain split
    float o0 = 0.f, o1 = 0.f, o2 = 0.f, o3 = 0.f;
    for (int i = 0; i < 128; ++i) {
      o0 += Mh1[i]       * w2n[(size_t)i * H_DIM + t];
      o1 += Mh1[128 + i] * w2n[(size_t)(128 + i) * H_DIM + t];
      o2 += Mh1[256 + i] * w2n[(size_t)(256 + i) * H_DIM + t];
      o3 += Mh1[384 + i] * w2n[(size_t)(384 + i) * H_DIM + t];
    }
    float o = nfv + c2n[t] + ((o0 + o1) + (o2 + o3));
    atomicAdd(&out_node[n * H_DIM + t], gate * o);
  }
}

// ---------------------------------------------------------------- launch
extern "C" void kernel_launch(void* const* d_in, const int* in_sizes, int n_in,
                              void* d_out, int out_size, void* d_ws, size_t ws_size,
                              hipStream_t stream) {
  const float* node_features = (const float*)d_in[0];
  const float* edge_features = (const float*)d_in[1];
  const float* edge_raw      = (const float*)d_in[2];
  const int*   neighbor_list = (const int*)d_in[3];
  const float* neighbor_mask = (const float*)d_in[4];
  const float* w_gate        = (const float*)d_in[6];
  const float* W_edge = (const float*)d_in[7];
  const float* b_edge = (const float*)d_in[8];
  const float* W_node = (const float*)d_in[9];
  const float* b_node = (const float*)d_in[10];
  const float* W_msg  = (const float*)d_in[11];
  const float* b_msg  = (const float*)d_in[12];
  const float* W_qkv  = (const float*)d_in[13];
  const float* b_qkv  = (const float*)d_in[14];
  const float* W_out  = (const float*)d_in[15];
  const float* b_out  = (const float*)d_in[16];
  const float* ln_attn_g = (const float*)d_in[17];
  const float* ln_attn_b = (const float*)d_in[18];
  const float* ln_ffn_g  = (const float*)d_in[19];
  const float* ln_ffn_b  = (const float*)d_in[20];
  const float* W1n = (const float*)d_in[21];
  const float* b1n = (const float*)d_in[22];
  const float* W2n = (const float*)d_in[23];
  const float* b2n = (const float*)d_in[24];
  const float* W1e = (const float*)d_in[25];
  const float* b1e = (const float*)d_in[26];
  const float* W2e = (const float*)d_in[27];
  const float* b2e = (const float*)d_in[28];

  unsigned short* nh16 = (unsigned short*)d_ws;           // 2097152 bf16
  unsigned short* fbp  = nh16 + NH_ELEMS;                 // 6029312 bf16
  int*   sel_ne  = (int*)(fbp + (size_t)N_EXP * EXP_STRIDE);
  float* sel_g   = (float*)(sel_ne + 2048);
  int*   work_ne = (int*)(sel_g + 2048);
  float* work_g  = (float*)(work_ne + 2048);

  float* out_node = (float*)d_out;
  float* out_edge = out_node + N_NODES * H_DIM;

  hipMemsetAsync(d_out, 0, (size_t)out_size * sizeof(float), stream);

  gate_kernel<<<N_NODES, 64, 0, stream>>>(node_features, w_gate, sel_ne, sel_g);
  sort_kernel<<<1, 256, 0, stream>>>(sel_ne, sel_g, work_ne, work_g);
  nh_kernel<<<dim3(N_NODES, N_EXP), 256, 0, stream>>>(node_features, ln_attn_g, ln_attn_b, nh16);
  wconv<<<dim3(1472, N_EXP), 64, 0, stream>>>(W_node, W_msg, W_edge, W_qkv, W_out, W1e, W2e, fbp);

  size_t smem = 81408;   // 2 x 81408 = 162816 <= 163840 -> 2 blocks/CU
  hipFuncSetAttribute((const void*)moe_main, hipFuncAttributeMaxDynamicSharedMemorySize, (int)smem);
  moe_main<<<N_NODES * NTOPK, 512, smem, stream>>>(
      node_features, edge_features, edge_raw, neighbor_list, neighbor_mask,
      W_node, b_node, b_edge, b_msg, b_qkv, b_out,
      ln_ffn_g, ln_ffn_b, W1n, b1n, W2n, b2n, b1e, b2e,
      nh16, fbp, work_ne, work_g, out_node, out_edge);
}

// Round 9
// 512.209 us; speedup vs baseline: 3.6777x; 1.2354x over previous
//
#include <hip/hip_runtime.h>
#include <math.h>

#define N_NODES 1024
#define K_NB    32
#define H_DIM   256
#define DE_DIM  128
#define N_EXP   8
#define NTOPK   2
#define FFH     512

#define NP_PAD  2176   // per-expert 16-padded worklist cap (2048 + 8*15 <= 2168)
#define NP_BLK  136    // NP_PAD/16

typedef __attribute__((ext_vector_type(8))) short s8v;   // 8 bf16 = 4 VGPR
typedef __attribute__((ext_vector_type(4))) float f4v;   // MFMA acc

// ---- ws layout (elements) ----
#define NH_ELEMS   (N_EXP * N_NODES * H_DIM)   // 2097152 bf16
// per-expert fragment-pool offsets (bf16 elems)
#define OFF_WN   0
#define OFF_WM   65536
#define OFF_WE   196608
#define OFF_WQ   229376
#define OFF_WO   425984
#define OFF_W1E  491520
#define OFF_W2E  622592
#define OFF_W1N  753664
#define OFF_W2N  884736
#define EXP_STRIDE 1015808

// ---------------------------------------------------------------- helpers
__device__ __forceinline__ unsigned short f2bf(float x) {
  unsigned u = __float_as_uint(x);
  unsigned r = u + 0x7FFFu + ((u >> 16) & 1u);   // RNE
  return (unsigned short)(r >> 16);
}
__device__ __forceinline__ float bf2f(unsigned short h) {
  return __uint_as_float((unsigned)h << 16);
}
__device__ __forceinline__ float gelu_f(float x) {
  float u = 0.7978845608028654f * (x + 0.044715f * x * x * x);
  float ex = __expf(2.f * u);
  float th = 1.f - 2.f / (ex + 1.f);
  return 0.5f * x * (1.f + th);
}

// A-fragment read from row-major bf16 LDS tile with XOR swizzle.
// lane l: row = rt*16+(l&15), contract elems = kt*32 + (l>>4)*8 + j
__device__ __forceinline__ s8v lda(const char* base, int SBv, int rt, int kt, int l) {
  int r = rt * 16 + (l & 15);
  int byte = r * SBv + kt * 64 + ((l >> 4) << 4);
  return *(const s8v*)(base + (byte ^ ((r & 7) << 4)));
}
__device__ __forceinline__ void stb16(char* base, int SBv, int r, int c, float v) {
  *(unsigned short*)(base + ((r * SBv + c * 2) ^ ((r & 7) << 4))) = f2bf(v);
}

// K-loop, BOTH row-tiles per wave: each B-fragment is loaded once and feeds
// 2 MFMAs (rt=0,1) -> halves the L2 B-frag stream (R8-verified win).
template<int NA, int NKT, int CSTR>
__device__ __forceinline__ void kloop2(f4v acc[2][NA], const char* Ab, int ASB,
                                       const unsigned short* __restrict__ fb, int NCT,
                                       int ktb0, int ctb0, int l) {
  __builtin_amdgcn_s_setprio(1);
  for (int kt = 0; kt < NKT; ++kt) {
    s8v a0 = lda(Ab, ASB, 0, kt, l);
    s8v a1 = lda(Ab, ASB, 1, kt, l);
#pragma unroll
    for (int m = 0; m < NA; ++m) {
      s8v bv = *(const s8v*)(fb + (((size_t)(ktb0 + kt) * NCT + (ctb0 + CSTR * m)) * 64 + l) * 8);
      acc[0][m] = __builtin_amdgcn_mfma_f32_16x16x32_bf16(a0, bv, acc[0][m], 0, 0, 0);
      acc[1][m] = __builtin_amdgcn_mfma_f32_16x16x32_bf16(a1, bv, acc[1][m], 0, 0, 0);
    }
  }
  __builtin_amdgcn_s_setprio(0);
}

// ---------------------------------------------------------------- gating
__global__ __launch_bounds__(64)
void gate_kernel(const float* __restrict__ nf, const float* __restrict__ wg,
                 int* __restrict__ sel_ne, float* __restrict__ sel_g) {
  int n = blockIdx.x, t = threadIdx.x;
  float p[8] = {0, 0, 0, 0, 0, 0, 0, 0};
  for (int j = 0; j < 4; ++j) {
    float x = nf[n * H_DIM + t + 64 * j];
#pragma unroll
    for (int e = 0; e < 8; ++e) p[e] += x * wg[(t + 64 * j) * 8 + e];
  }
#pragma unroll
  for (int e = 0; e < 8; ++e)
    for (int m = 32; m >= 1; m >>= 1) p[e] += __shfl_xor(p[e], m, 64);
  if (t == 0) {
    int i0 = 0; float v0 = p[0];
    for (int e = 1; e < 8; ++e) if (p[e] > v0) { v0 = p[e]; i0 = e; }
    int i1 = -1; float v1 = -3.4e38f;
    for (int e = 0; e < 8; ++e) if (e != i0 && p[e] > v1) { v1 = p[e]; i1 = e; }
    float g1 = __expf(v1 - v0);
    float inv = 1.f / (1.f + g1);
    sel_ne[n * 2 + 0] = (n << 3) | i0; sel_g[n * 2 + 0] = inv;
    sel_ne[n * 2 + 1] = (n << 3) | i1; sel_g[n * 2 + 1] = g1 * inv;
  }
}

// worklist + per-expert 16-padded index list (pwork -> index into work, -1 pad)
__global__ __launch_bounds__(256)
void sort_kernel(const int* __restrict__ sel_ne, const float* __restrict__ sel_g,
                 int* __restrict__ work_ne, float* __restrict__ work_g,
                 int* __restrict__ pwork) {
  __shared__ int cnt[8], off[8], poff[8], cur[8];
  int t = threadIdx.x;
  if (t < 8) { cnt[t] = 0; cur[t] = 0; }
  for (int i = t; i < NP_PAD; i += 256) pwork[i] = -1;
  __syncthreads();
  for (int i = t; i < N_NODES * NTOPK; i += 256) atomicAdd(&cnt[sel_ne[i] & 7], 1);
  __syncthreads();
  if (t == 0) {
    int s = 0, ps = 0;
    for (int e = 0; e < 8; ++e) {
      off[e] = s; s += cnt[e];
      poff[e] = ps; ps += (cnt[e] + 15) & ~15;
    }
  }
  __syncthreads();
  for (int i = t; i < N_NODES * NTOPK; i += 256) {
    int pe = sel_ne[i]; int e = pe & 7;
    int ci = atomicAdd(&cur[e], 1);
    int pos = off[e] + ci;
    work_ne[pos] = pe; work_g[pos] = sel_g[i];
    pwork[poff[e] + ci] = pos;
  }
}

// per-expert LayerNorm of all nodes -> bf16
__global__ __launch_bounds__(256)
void nh_kernel(const float* __restrict__ nf, const float* __restrict__ lag,
               const float* __restrict__ lab, unsigned short* __restrict__ nh16) {
  __shared__ float red[8];
  int n = blockIdx.x, e = blockIdx.y, t = threadIdx.x;
  float x = nf[n * H_DIM + t];
  float sv = x, sq = x * x;
  for (int m = 32; m >= 1; m >>= 1) { sv += __shfl_xor(sv, m, 64); sq += __shfl_xor(sq, m, 64); }
  if ((t & 63) == 0) { red[t >> 6] = sv; red[4 + (t >> 6)] = sq; }
  __syncthreads();
  float sum = red[0] + red[1] + red[2] + red[3];
  float ssum = red[4] + red[5] + red[6] + red[7];
  float mu = sum * (1.f / 256.f);
  float var = ssum * (1.f / 256.f) - mu * mu;
  float rstd = rsqrtf(var + 1e-5f);
  nh16[((size_t)e * N_NODES + n) * H_DIM + t] =
      f2bf((x - mu) * rstd * lag[e * H_DIM + t] + lab[e * H_DIM + t]);
}

// ------------------------------------------------ weight -> bf16 fragments
__global__ __launch_bounds__(64)
void wconv(const float* __restrict__ W_node, const float* __restrict__ W_msg,
           const float* __restrict__ W_edge, const float* __restrict__ W_qkv,
           const float* __restrict__ W_out, const float* __restrict__ W1e,
           const float* __restrict__ W2e, const float* __restrict__ W1n,
           const float* __restrict__ W2n, unsigned short* __restrict__ fb) {
  int f = blockIdx.x, e = blockIdx.y, l = threadIdx.x;
  const float* src; int C, nct, fl; size_t off;
  if (f < 128)       { src = W_node + (size_t)e * 131072; C = 256; nct = 16; fl = f;        off = OFF_WN;  }
  else if (f < 384)  { src = W_msg  + (size_t)e * 131072; C = 256; nct = 16; fl = f - 128;  off = OFF_WM;  }
  else if (f < 448)  { src = W_edge + (size_t)e * 32768;  C = 256; nct = 16; fl = f - 384;  off = OFF_WE;  }
  else if (f < 832)  { src = W_qkv  + (size_t)e * 196608; C = 768; nct = 48; fl = f - 448;  off = OFF_WQ;  }
  else if (f < 960)  { src = W_out  + (size_t)e * 65536;  C = 256; nct = 16; fl = f - 832;  off = OFF_WO;  }
  else if (f < 1216) { src = W1e    + (size_t)e * 131072; C = 512; nct = 32; fl = f - 960;  off = OFF_W1E; }
  else if (f < 1472) { src = W2e    + (size_t)e * 131072; C = 256; nct = 16; fl = f - 1216; off = OFF_W2E; }
  else if (f < 1728) { src = W1n    + (size_t)e * 131072; C = 512; nct = 32; fl = f - 1472; off = OFF_W1N; }
  else               { src = W2n    + (size_t)e * 131072; C = 256; nct = 16; fl = f - 1728; off = OFF_W2N; }
  int kt = fl / nct, ct = fl - kt * nct;
  int k0 = kt * 32 + ((l >> 4) << 3), c = ct * 16 + (l & 15);
  unsigned pk[4];
#pragma unroll
  for (int jj = 0; jj < 4; ++jj) {
    unsigned short a = f2bf(src[(size_t)(k0 + 2 * jj) * C + c]);
    unsigned short b = f2bf(src[(size_t)(k0 + 2 * jj + 1) * C + c]);
    pk[jj] = (unsigned)a | ((unsigned)b << 16);
  }
  unsigned short* dst = fb + (size_t)e * EXP_STRIDE + off + ((size_t)fl * 64 + l) * 8;
  *(uint4*)dst = make_uint4(pk[0], pk[1], pk[2], pk[3]);
}

// ------------------------------------- node FFN epilogue (MFMA, 16 rows/blk)
__global__ __launch_bounds__(512)
void node_ffn(const int* __restrict__ work_ne, const float* __restrict__ work_g,
              const int* __restrict__ pwork, const float* __restrict__ nfv_ws,
              const unsigned short* __restrict__ fb,
              const float* __restrict__ b1n, const float* __restrict__ b2n,
              const float* __restrict__ ln_ffn_g, const float* __restrict__ ln_ffn_b,
              float* __restrict__ out_node) {
  __shared__ char LNb[8192];      // bf16 [16][512B] swz
  __shared__ char H1b[16384];     // bf16 [16][1024B] swz
  __shared__ float NF[16 * 256];  // nfv rows f32
  __shared__ int Sidx[16]; __shared__ float Sg[16]; __shared__ int Sn[16];
  __shared__ int Se;
  const int t = threadIdx.x, b = blockIdx.x;
  if (t < 16) {
    int idx = pwork[b * 16 + t];
    Sidx[t] = idx;
    Sg[t] = (idx >= 0) ? work_g[idx] : 0.f;
    Sn[t] = (idx >= 0) ? (work_ne[idx] >> 3) : 0;
  }
  if (t == 0) {
    int e = 0;
    for (int i = 0; i < 16; ++i) {
      int ix = pwork[b * 16 + i];
      if (ix >= 0) { e = work_ne[ix] & 7; break; }
    }
    Se = e;
  }
  __syncthreads();
  const int e = Se;
  const unsigned short* fb1 = fb + (size_t)e * EXP_STRIDE + OFF_W1N;
  const unsigned short* fb2 = fb + (size_t)e * EXP_STRIDE + OFF_W2N;
  const float* lfg = ln_ffn_g + e * H_DIM;
  const float* lfb = ln_ffn_b + e * H_DIM;
  const float* c1n = b1n + e * FFH;
  const float* c2n = b2n + e * H_DIM;
  // load nfv rows + per-row LN -> LNb bf16
  {
    int r = t >> 5, j = t & 31;
    int idx = Sidx[r];
    float x[8]; float s1 = 0.f, s2 = 0.f;
#pragma unroll
    for (int z = 0; z < 8; ++z) {
      int c = j + 32 * z;
      float v = (idx >= 0) ? nfv_ws[(size_t)idx * 256 + c] : 0.f;
      NF[r * 256 + c] = v; x[z] = v; s1 += v; s2 += v * v;
    }
    s1 += __shfl_xor(s1, 16, 32); s2 += __shfl_xor(s2, 16, 32);
    s1 += __shfl_xor(s1, 8, 32);  s2 += __shfl_xor(s2, 8, 32);
    s1 += __shfl_xor(s1, 4, 32);  s2 += __shfl_xor(s2, 4, 32);
    s1 += __shfl_xor(s1, 2, 32);  s2 += __shfl_xor(s2, 2, 32);
    s1 += __shfl_xor(s1, 1, 32);  s2 += __shfl_xor(s2, 1, 32);
    float mu = s1 * (1.f / 256.f);
    float var = s2 * (1.f / 256.f) - mu * mu;
    float rstd = rsqrtf(var + 1e-5f);
#pragma unroll
    for (int z = 0; z < 8; ++z) {
      int c = j + 32 * z;
      stb16(LNb, 512, r, c, (x[z] - mu) * rstd * lfg[c] + lfb[c]);
    }
  }
  __syncthreads();
  const int w = t >> 6, l = t & 63, l15 = l & 15, lg = l >> 4;
  // h1 = gelu(LN @ W1n + c1n) -> H1b  (single 16-row tile)
  {
    f4v acc[4];
#pragma unroll
    for (int m = 0; m < 4; ++m) {
      float iv = c1n[(w + 8 * m) * 16 + l15];
      acc[m][0] = iv; acc[m][1] = iv; acc[m][2] = iv; acc[m][3] = iv;
    }
    for (int kt = 0; kt < 8; ++kt) {
      s8v a = lda(LNb, 512, 0, kt, l);
#pragma unroll
      for (int m = 0; m < 4; ++m) {
        s8v bv = *(const s8v*)(fb1 + (((size_t)kt * 32 + (w + 8 * m)) * 64 + l) * 8);
        acc[m] = __builtin_amdgcn_mfma_f32_16x16x32_bf16(a, bv, acc[m], 0, 0, 0);
      }
    }
#pragma unroll
    for (int m = 0; m < 4; ++m) {
      int c = (w + 8 * m) * 16 + l15;
#pragma unroll
      for (int ri = 0; ri < 4; ++ri)
        stb16(H1b, 1024, 4 * lg + ri, c, gelu_f(acc[m][ri]));
    }
  }
  __syncthreads();
  // out = nfv + h1 @ W2n + c2n  -> atomic (gate-weighted)
  {
    f4v acc[2];
#pragma unroll
    for (int m = 0; m < 2; ++m) {
      float iv = c2n[(w + 8 * m) * 16 + l15];
      acc[m][0] = iv; acc[m][1] = iv; acc[m][2] = iv; acc[m][3] = iv;
    }
    for (int kt = 0; kt < 16; ++kt) {
      s8v a = lda(H1b, 1024, 0, kt, l);
#pragma unroll
      for (int m = 0; m < 2; ++m) {
        s8v bv = *(const s8v*)(fb2 + (((size_t)kt * 16 + (w + 8 * m)) * 64 + l) * 8);
        acc[m] = __builtin_amdgcn_mfma_f32_16x16x32_bf16(a, bv, acc[m], 0, 0, 0);
      }
    }
#pragma unroll
    for (int m = 0; m < 2; ++m) {
      int c = (w + 8 * m) * 16 + l15;
#pragma unroll
      for (int ri = 0; ri < 4; ++ri) {
        int r = 4 * lg + ri;
        float o = NF[r * 256 + c] + acc[m][ri];
        atomicAdd(&out_node[(size_t)Sn[r] * H_DIM + c], Sg[r] * o);
      }
    }
  }
}

// ---------------------------------------------------------------- main
// 512 threads (8 waves), 2 blocks/CU, 128 regs. Node FFN extracted to
// node_ffn (R9): moe_main now only writes nfv to ws.
__global__ __launch_bounds__(512, 4)
void moe_main(const float* __restrict__ node_features,
              const float* __restrict__ edge_features,
              const float* __restrict__ edge_raw,
              const int* __restrict__ neighbor_list,
              const float* __restrict__ neighbor_mask,
              const float* __restrict__ W_node_f32, const float* __restrict__ bn,
              const float* __restrict__ be, const float* __restrict__ bm,
              const float* __restrict__ bq, const float* __restrict__ bo,
              const float* __restrict__ ln_ffn_g, const float* __restrict__ ln_ffn_b,
              const float* __restrict__ b1e, const float* __restrict__ b2e,
              const unsigned short* __restrict__ nh16,
              const unsigned short* __restrict__ fb,
              const int* __restrict__ work_ne, const float* __restrict__ work_g,
              float* __restrict__ nfv_ws, float* __restrict__ out_edge) {
  extern __shared__ char sm[];
  char* SAp = sm;                      // 16K: sender -> msg -> ctx -> eh2
  char* SBp = sm + 16384;              // 16K: nodeh -> k
  char* SCp = sm + 32768;              // 16K: eh -> v
  float* EF = (float*)(sm + 16384);    // 32K f32 [32][256] (overlays SB+SC)
  char* SDp = sm + 49152;              // 8K : edge_raw bf16
  char* SQp = sm + 57344;              // 16K: q bf16 -> P bf16 -> h1e half
  float* MF = (float*)(sm + 73728);
  float* Mrecv = MF;            // 256
  float* Mrv2  = MF + 256;      // 512
  float* Mnp   = MF + 768;      // 256
  float* Mmask = MF + 1024;     // 32
  float* Mmu   = MF + 1056;     // 32
  float* Mrstd = MF + 1088;     // 32

  const int t = threadIdx.x;
  const int pe = work_ne[blockIdx.x];
  const int n = pe >> 3, e = pe & 7;
  const float gate = work_g[blockIdx.x];

  const unsigned short* fbE   = fb + (size_t)e * EXP_STRIDE;
  const unsigned short* fbWn  = fbE + OFF_WN;
  const unsigned short* fbWm  = fbE + OFF_WM;
  const unsigned short* fbWe  = fbE + OFF_WE;
  const unsigned short* fbWq  = fbE + OFF_WQ;
  const unsigned short* fbWo  = fbE + OFF_WO;
  const unsigned short* fbW1e = fbE + OFF_W1E;
  const unsigned short* fbW2e = fbE + OFF_W2E;

  const float* Wn2  = W_node_f32 + (size_t)e * 131072;
  const float* bnE  = bn + e * H_DIM;
  const float* beE  = be + e * H_DIM;
  const float* bmE  = bm + e * H_DIM;
  const float* bqE  = bq + e * 3 * H_DIM;
  const float* boE  = bo + e * H_DIM;
  const float* lfg  = ln_ffn_g + e * H_DIM;
  const float* lfb  = ln_ffn_b + e * H_DIM;
  const float* c1e  = b1e + e * FFH;
  const float* c2e  = b2e + e * H_DIM;

  const int w = t >> 6, l = t & 63;
  const int ctb = w;                 // col-group 0..7
  const int l15 = l & 15, lg = l >> 4;
  const int rbase0 = (lg << 2);

  // ---- stage ----
  const unsigned short* nh_e = nh16 + (size_t)e * N_NODES * H_DIM;
#pragma unroll
  for (int rr2 = 0; rr2 < 2; ++rr2) {
    int r = (t >> 5) + 16 * rr2, j = t & 31;
    int nbr = neighbor_list[n * K_NB + r];
    uint4 val = ((const uint4*)(nh_e + (size_t)nbr * H_DIM))[j];
    *(uint4*)(SAp + ((r * 512 + j * 16) ^ ((r & 7) << 4))) = val;
  }
  if (t < 256) Mrecv[t] = bf2f(nh_e[(size_t)n * H_DIM + t]);
#pragma unroll
  for (int rr2 = 0; rr2 < 2; ++rr2) {
    int r = (t >> 5) + 16 * rr2, c = (t & 31) * 4;
    float4 v = *(const float4*)(edge_raw + ((size_t)n * K_NB + r) * DE_DIM + c);
    unsigned p0 = (unsigned)f2bf(v.x) | ((unsigned)f2bf(v.y) << 16);
    unsigned p1 = (unsigned)f2bf(v.z) | ((unsigned)f2bf(v.w) << 16);
    *(uint2*)(SDp + ((r * 256 + c * 2) ^ ((r & 7) << 4))) = make_uint2(p0, p1);
  }
  if (t < 32) Mmask[t] = neighbor_mask[n * K_NB + t];
  if (t < 256) Mnp[t] = 0.f;
  __syncthreads();

  // ---- recv rank-1: Mrv[c] = sum_i recv[i]*Wn[256+i][c] + bn[c] (fp32) ----
  {
    int c = t & 255, part = t >> 8;
    float s0 = 0.f, s1 = 0.f;
    for (int i = 0; i < 64; ++i) {
      s0 += Mrecv[part * 128 + i] * Wn2[(size_t)(256 + part * 128 + i) * 256 + c];
      s1 += Mrecv[part * 128 + 64 + i] * Wn2[(size_t)(256 + part * 128 + 64 + i) * 256 + c];
    }
    Mrv2[part * 256 + c] = s0 + s1;
  }
  __syncthreads();
  if (t < 256) Mrecv[t] = Mrv2[t] + Mrv2[256 + t] + bnE[t];
  __syncthreads();

  // ---- phase 1: nodeh = gelu(sender@Wn1 + Mrv) -> SB ----
  {
    f4v acc[2][2];
#pragma unroll
    for (int m = 0; m < 2; ++m) {
      float iv = Mrecv[(ctb + 8 * m) * 16 + l15];
#pragma unroll
      for (int rt2 = 0; rt2 < 2; ++rt2) {
        acc[rt2][m][0] = iv; acc[rt2][m][1] = iv; acc[rt2][m][2] = iv; acc[rt2][m][3] = iv;
      }
    }
    kloop2<2, 8, 8>(acc, SAp, 512, fbWn, 16, 0, ctb, l);
#pragma unroll
    for (int m = 0; m < 2; ++m) {
      int c = (ctb + 8 * m) * 16 + l15;
#pragma unroll
      for (int rt2 = 0; rt2 < 2; ++rt2)
#pragma unroll
        for (int ri = 0; ri < 4; ++ri)
          stb16(SBp, 512, rt2 * 16 + rbase0 + ri, c, gelu_f(acc[rt2][m][ri]));
    }
  }
  // ---- phase 3: eh = gelu(edge_raw@We + be) -> SC ----
  {
    f4v acc[2][2];
#pragma unroll
    for (int m = 0; m < 2; ++m) {
      float iv = beE[(ctb + 8 * m) * 16 + l15];
#pragma unroll
      for (int rt2 = 0; rt2 < 2; ++rt2) {
        acc[rt2][m][0] = iv; acc[rt2][m][1] = iv; acc[rt2][m][2] = iv; acc[rt2][m][3] = iv;
      }
    }
    kloop2<2, 4, 8>(acc, SDp, 256, fbWe, 16, 0, ctb, l);
#pragma unroll
    for (int m = 0; m < 2; ++m) {
      int c = (ctb + 8 * m) * 16 + l15;
#pragma unroll
      for (int rt2 = 0; rt2 < 2; ++rt2)
#pragma unroll
        for (int ri = 0; ri < 4; ++ri)
          stb16(SCp, 512, rt2 * 16 + rbase0 + ri, c, gelu_f(acc[rt2][m][ri]));
    }
  }
  __syncthreads();

  // ---- phase 2+4: msg = gelu([eh|nodeh]@Wm + bm) -> SA ----
  {
    f4v acc[2][2];
#pragma unroll
    for (int m = 0; m < 2; ++m) {
      float iv = bmE[(ctb + 8 * m) * 16 + l15];
#pragma unroll
      for (int rt2 = 0; rt2 < 2; ++rt2) {
        acc[rt2][m][0] = iv; acc[rt2][m][1] = iv; acc[rt2][m][2] = iv; acc[rt2][m][3] = iv;
      }
    }
    kloop2<2, 8, 8>(acc, SCp, 512, fbWm, 16, 0, ctb, l);   // eh    (rows 0..255)
    kloop2<2, 8, 8>(acc, SBp, 512, fbWm, 16, 8, ctb, l);   // nodeh (rows 256..511)
#pragma unroll
    for (int m = 0; m < 2; ++m) {
      int c = (ctb + 8 * m) * 16 + l15;
#pragma unroll
      for (int rt2 = 0; rt2 < 2; ++rt2)
#pragma unroll
        for (int ri = 0; ri < 4; ++ri)
          stb16(SAp, 512, rt2 * 16 + rbase0 + ri, c, gelu_f(acc[rt2][m][ri]));
    }
  }
  __syncthreads();

  // ---- phase 5: qkv = msg@Wq + bq (3 passes); q->SQ, k->SB, v->SC ----
#pragma unroll
  for (int p = 0; p < 3; ++p) {
    f4v acc[2][2];
#pragma unroll
    for (int m = 0; m < 2; ++m) {
      float iv = bqE[(p * 16 + ctb + 8 * m) * 16 + l15];
#pragma unroll
      for (int rt2 = 0; rt2 < 2; ++rt2) {
        acc[rt2][m][0] = iv; acc[rt2][m][1] = iv; acc[rt2][m][2] = iv; acc[rt2][m][3] = iv;
      }
    }
    kloop2<2, 8, 8>(acc, SAp, 512, fbWq, 48, 0, p * 16 + ctb, l);
#pragma unroll
    for (int m = 0; m < 2; ++m) {
      int cg = (p * 16 + ctb + 8 * m) * 16 + l15;
      char* dst = (cg < 256) ? SQp : ((cg < 512) ? SBp : SCp);
      int cl = cg & 255;
#pragma unroll
      for (int rt2 = 0; rt2 < 2; ++rt2)
#pragma unroll
        for (int ri = 0; ri < 4; ++ri)
          stb16(dst, 512, rt2 * 16 + rbase0 + ri, cl, acc[rt2][m][ri]);
    }
  }
  __syncthreads();

  // ---- phase 6: MFMA attention; wave w = head h (all data wave-private) ----
  {
    const int h = w;
    f4v st[2][2];
    {
      s8v ka0 = lda(SBp, 512, 0, h, l);
      s8v ka1 = lda(SBp, 512, 1, h, l);
      s8v qb0 = lda(SQp, 512, 0, h, l);
      s8v qb1 = lda(SQp, 512, 1, h, l);
      f4v z = {0.f, 0.f, 0.f, 0.f};
      st[0][0] = __builtin_amdgcn_mfma_f32_16x16x32_bf16(ka0, qb0, z, 0, 0, 0);
      st[0][1] = __builtin_amdgcn_mfma_f32_16x16x32_bf16(ka0, qb1, z, 0, 0, 0);
      st[1][0] = __builtin_amdgcn_mfma_f32_16x16x32_bf16(ka1, qb0, z, 0, 0, 0);
      st[1][1] = __builtin_amdgcn_mfma_f32_16x16x32_bf16(ka1, qb1, z, 0, 0, 0);
    }
    const float scale = 0.17677669529663687f;
    float madd[2][4];
#pragma unroll
    for (int rt2 = 0; rt2 < 2; ++rt2)
#pragma unroll
      for (int ri = 0; ri < 4; ++ri)
        madd[rt2][ri] = (Mmask[rt2 * 16 + 4 * lg + ri] > 0.f) ? 0.f : -1e9f;
#pragma unroll
    for (int ct2 = 0; ct2 < 2; ++ct2) {
      float m_ = -3.4e38f;
#pragma unroll
      for (int rt2 = 0; rt2 < 2; ++rt2)
#pragma unroll
        for (int ri = 0; ri < 4; ++ri) {
          float sv = st[rt2][ct2][ri] * scale + madd[rt2][ri];
          st[rt2][ct2][ri] = sv;
          m_ = fmaxf(m_, sv);
        }
      m_ = fmaxf(m_, __shfl_xor(m_, 16, 64));
      m_ = fmaxf(m_, __shfl_xor(m_, 32, 64));
      float s_ = 0.f;
#pragma unroll
      for (int rt2 = 0; rt2 < 2; ++rt2)
#pragma unroll
        for (int ri = 0; ri < 4; ++ri) {
          float ev = __expf(st[rt2][ct2][ri] - m_);
          st[rt2][ct2][ri] = ev;
          s_ += ev;
        }
      s_ += __shfl_xor(s_, 16, 64);
      s_ += __shfl_xor(s_, 32, 64);
      float inv = 1.f / s_;
#pragma unroll
      for (int rt2 = 0; rt2 < 2; ++rt2)
#pragma unroll
        for (int ri = 0; ri < 4; ++ri)
          stb16(SQp, 512, ct2 * 16 + l15, h * 32 + rt2 * 16 + 4 * lg + ri,
                st[rt2][ct2][ri] * inv);
    }
    s8v pa0 = lda(SQp, 512, 0, h, l);
    s8v pa1 = lda(SQp, 512, 1, h, l);
#pragma unroll
    for (int dt = 0; dt < 2; ++dt) {
      s8v vb;
#pragma unroll
      for (int j = 0; j < 8; ++j) {
        int rj = lg * 8 + j;
        vb[j] = *(const short*)(SCp +
                 ((rj * 512 + h * 64 + dt * 32 + l15 * 2) ^ ((rj & 7) << 4)));
      }
      f4v z = {0.f, 0.f, 0.f, 0.f};
      f4v c0 = __builtin_amdgcn_mfma_f32_16x16x32_bf16(pa0, vb, z, 0, 0, 0);
      f4v c1 = __builtin_amdgcn_mfma_f32_16x16x32_bf16(pa1, vb, z, 0, 0, 0);
#pragma unroll
      for (int ri = 0; ri < 4; ++ri) {
        stb16(SAp, 512, 4 * lg + ri,      h * 32 + dt * 16 + l15, c0[ri]);
        stb16(SAp, 512, 16 + 4 * lg + ri, h * 32 + dt * 16 + l15, c1[ri]);
      }
    }
  }
  __syncthreads();

  // ---- phase 7: edge_out = ctx@Wo + bo; np partials; ef -> EF ----
  {
    f4v acc[2][2];
#pragma unroll
    for (int m = 0; m < 2; ++m) {
      float iv = boE[(ctb + 8 * m) * 16 + l15];
#pragma unroll
      for (int rt2 = 0; rt2 < 2; ++rt2) {
        acc[rt2][m][0] = iv; acc[rt2][m][1] = iv; acc[rt2][m][2] = iv; acc[rt2][m][3] = iv;
      }
    }
    kloop2<2, 8, 8>(acc, SAp, 512, fbWo, 16, 0, ctb, l);
#pragma unroll
    for (int m = 0; m < 2; ++m) {
      int c = (ctb + 8 * m) * 16 + l15;
      float np = 0.f;
#pragma unroll
      for (int rt2 = 0; rt2 < 2; ++rt2)
#pragma unroll
        for (int ri = 0; ri < 4; ++ri) {
          int r = rt2 * 16 + rbase0 + ri;
          float eo = acc[rt2][m][ri];
          np += eo * Mmask[r];
          EF[r * 256 + c] = eo + edge_features[((size_t)n * K_NB + r) * H_DIM + c];
        }
      atomicAdd(&Mnp[c], np);
    }
  }
  __syncthreads();

  // ---- phase 9a: LN stats of ef; 8a: nfv -> ws ----
  {
    int rr = t >> 4, j = t & 15;
    float s1 = 0.f, s2 = 0.f;
#pragma unroll
    for (int m2 = 0; m2 < 16; ++m2) {
      float xv = EF[rr * 256 + j + 16 * m2];
      s1 += xv; s2 += xv * xv;
    }
    s1 += __shfl_xor(s1, 8, 64); s2 += __shfl_xor(s2, 8, 64);
    s1 += __shfl_xor(s1, 4, 64); s2 += __shfl_xor(s2, 4, 64);
    s1 += __shfl_xor(s1, 2, 64); s2 += __shfl_xor(s2, 2, 64);
    s1 += __shfl_xor(s1, 1, 64); s2 += __shfl_xor(s2, 1, 64);
    if (j == 0) {
      float mu2 = s1 * (1.f / 256.f);
      float v2 = s2 * (1.f / 256.f) - mu2 * mu2;
      Mmu[rr] = mu2; Mrstd[rr] = rsqrtf(v2 + 1e-5f);
    }
  }
  float cntv = 1e-5f;
#pragma unroll
  for (int kk = 0; kk < 32; ++kk) cntv += Mmask[kk];
  if (t < 256) {
    float nfv = Mnp[t] / cntv + node_features[n * H_DIM + t];
    nfv_ws[(size_t)blockIdx.x * H_DIM + t] = nfv;   // node_ffn picks this up
  }
  __syncthreads();

  // ---- 9d: eh2 = LN(ef) -> SA bf16 ----
  {
    int col = t & 255, rgp = t >> 8;
    float g2 = lfg[col], b2v = lfb[col];
#pragma unroll
    for (int r8 = 0; r8 < 16; ++r8) {
      int row = rgp * 16 + r8;
      float xv = (EF[row * 256 + col] - Mmu[row]) * Mrstd[row] * g2 + b2v;
      stb16(SAp, 512, row, col, xv);
    }
  }
  __syncthreads();

  // ---- phases 10+11 (k-split halves, h1e half-buffer in SQ) ----
  f4v acc2[2][2];
#pragma unroll
  for (int m = 0; m < 2; ++m) {
    float iv = c2e[(ctb + 8 * m) * 16 + l15];
#pragma unroll
    for (int rt2 = 0; rt2 < 2; ++rt2) {
      acc2[rt2][m][0] = iv; acc2[rt2][m][1] = iv; acc2[rt2][m][2] = iv; acc2[rt2][m][3] = iv;
    }
  }
#pragma unroll
  for (int half = 0; half < 2; ++half) {
    {
      f4v acc[2][2];
#pragma unroll
      for (int m = 0; m < 2; ++m) {
        float iv = c1e[(half * 16 + ctb + 8 * m) * 16 + l15];
#pragma unroll
        for (int rt2 = 0; rt2 < 2; ++rt2) {
          acc[rt2][m][0] = iv; acc[rt2][m][1] = iv; acc[rt2][m][2] = iv; acc[rt2][m][3] = iv;
        }
      }
      kloop2<2, 8, 8>(acc, SAp, 512, fbW1e, 32, 0, half * 16 + ctb, l);
#pragma unroll
      for (int m = 0; m < 2; ++m) {
        int c = (ctb + 8 * m) * 16 + l15;
#pragma unroll
        for (int rt2 = 0; rt2 < 2; ++rt2)
#pragma unroll
          for (int ri = 0; ri < 4; ++ri)
            stb16(SQp, 512, rt2 * 16 + rbase0 + ri, c, gelu_f(acc[rt2][m][ri]));
      }
    }
    __syncthreads();
    kloop2<2, 8, 8>(acc2, SQp, 512, fbW2e, 16, half * 8, ctb, l);
    __syncthreads();
  }

  // ---- epilogue: out_edge ----
#pragma unroll
  for (int m = 0; m < 2; ++m) {
    int c = (ctb + 8 * m) * 16 + l15;
#pragma unroll
    for (int rt2 = 0; rt2 < 2; ++rt2)
#pragma unroll
      for (int ri = 0; ri < 4; ++ri) {
        int r = rt2 * 16 + rbase0 + ri;
        float o = acc2[rt2][m][ri] + EF[r * 256 + c];
        atomicAdd(&out_edge[((size_t)n * K_NB + r) * H_DIM + c], gate * o);
      }
  }
}

// ---------------------------------------------------------------- launch
extern "C" void kernel_launch(void* const* d_in, const int* in_sizes, int n_in,
                              void* d_out, int out_size, void* d_ws, size_t ws_size,
                              hipStream_t stream) {
  const float* node_features = (const float*)d_in[0];
  const float* edge_features = (const float*)d_in[1];
  const float* edge_raw      = (const float*)d_in[2];
  const int*   neighbor_list = (const int*)d_in[3];
  const float* neighbor_mask = (const float*)d_in[4];
  const float* w_gate        = (const float*)d_in[6];
  const float* W_edge = (const float*)d_in[7];
  const float* b_edge = (const float*)d_in[8];
  const float* W_node = (const float*)d_in[9];
  const float* b_node = (const float*)d_in[10];
  const float* W_msg  = (const float*)d_in[11];
  const float* b_msg  = (const float*)d_in[12];
  const float* W_qkv  = (const float*)d_in[13];
  const float* b_qkv  = (const float*)d_in[14];
  const float* W_out  = (const float*)d_in[15];
  const float* b_out  = (const float*)d_in[16];
  const float* ln_attn_g = (const float*)d_in[17];
  const float* ln_attn_b = (const float*)d_in[18];
  const float* ln_ffn_g  = (const float*)d_in[19];
  const float* ln_ffn_b  = (const float*)d_in[20];
  const float* W1n = (const float*)d_in[21];
  const float* b1n = (const float*)d_in[22];
  const float* W2n = (const float*)d_in[23];
  const float* b2n = (const float*)d_in[24];
  const float* W1e = (const float*)d_in[25];
  const float* b1e = (const float*)d_in[26];
  const float* W2e = (const float*)d_in[27];
  const float* b2e = (const float*)d_in[28];

  unsigned short* nh16 = (unsigned short*)d_ws;           // 2,097,152 bf16
  unsigned short* fbp  = nh16 + NH_ELEMS;                 // 8,126,464 bf16
  unsigned short* endfb = fbp + (size_t)N_EXP * EXP_STRIDE;
  int*   sel_ne  = (int*)endfb;
  float* sel_g   = (float*)(sel_ne + 2048);
  int*   work_ne = (int*)(sel_g + 2048);
  float* work_g  = (float*)(work_ne + 2048);
  int*   pwork   = (int*)(work_g + 2048);
  float* nfv_ws  = (float*)(pwork + NP_PAD);              // 2048*256 f32

  float* out_node = (float*)d_out;
  float* out_edge = out_node + N_NODES * H_DIM;

  hipMemsetAsync(d_out, 0, (size_t)out_size * sizeof(float), stream);

  gate_kernel<<<N_NODES, 64, 0, stream>>>(node_features, w_gate, sel_ne, sel_g);
  sort_kernel<<<1, 256, 0, stream>>>(sel_ne, sel_g, work_ne, work_g, pwork);
  nh_kernel<<<dim3(N_NODES, N_EXP), 256, 0, stream>>>(node_features, ln_attn_g, ln_attn_b, nh16);
  wconv<<<dim3(1984, N_EXP), 64, 0, stream>>>(W_node, W_msg, W_edge, W_qkv, W_out,
                                              W1e, W2e, W1n, W2n, fbp);

  size_t smem = 81408;   // 2 x 81408 <= 163840 -> 2 blocks/CU
  hipFuncSetAttribute((const void*)moe_main, hipFuncAttributeMaxDynamicSharedMemorySize, (int)smem);
  moe_main<<<N_NODES * NTOPK, 512, smem, stream>>>(
      node_features, edge_features, edge_raw, neighbor_list, neighbor_mask,
      W_node, b_node, b_edge, b_msg, b_qkv, b_out,
      ln_ffn_g, ln_ffn_b, b1e, b2e,
      nh16, fbp, work_ne, work_g, nfv_ws, out_edge);

  node_ffn<<<NP_BLK, 512, 0, stream>>>(work_ne, work_g, pwork, nfv_ws, fbp,
                                       b1n, b2n, ln_ffn_g, ln_ffn_b, out_node);
}